// Round 8
// baseline (1574.374 us; speedup 1.0000x reference)
//
#include <hip/hip_runtime.h>
#include <hip/hip_bf16.h>
#include <math.h>

#define B_ 4
#define N_ 8192
#define C_ 128
#define K_ 683
#define KP_ 768
#define KT_ 704   // 11*64 padded K for moments

// ---- workspace layout (float offsets) ----
#define WS_ET      0          // 128*768        = 98304
#define WS_ANCH    98304      // 4*768*4        = 12288
#define WS_EXT     110592     // 4*8192*16      = 524288
#define WS_PART    634880     // 8*4*704*168    = 3784704
#define WS_SUMA    4419584    // 4*704          = 2816
#define WS_NORM    4422400    // 4*704          = 2816
// -- new (MFMA) path --
#define WS_LOSSP2  4425216    // 128 floats (84 tile partials)
#define WS_AT      4425344    // bf16 At[4][768][8192] = 12582912 floats worth
#define WS_NEW_END 17008256   // floats -> 68,033,024 bytes
// -- old (fallback) path --
#define WS_GPART   4425216    // 2*4*768*768    = 4718592
#define WS_LOSSP   9143808    // 512

// ---- output layout (float offsets) ----
#define OUT_A      0
#define OUT_SC     22380544ULL
#define OUT_MUC    22730240ULL
#define OUT_SGC    22738436ULL
#define OUT_TOT    22763024ULL

typedef __attribute__((ext_vector_type(8))) short bf16x8s;
typedef __attribute__((ext_vector_type(4))) float f32x4;

static __device__ __forceinline__ unsigned short f2bf_rne(float f) {
  unsigned int u = __builtin_bit_cast(unsigned int, f);
  unsigned int r = (u + 0x7fffu + ((u >> 16) & 1u)) >> 16;
  return (unsigned short)r;
}

// monotone float -> u32 (order-preserving incl. negatives; no NaNs here)
static __device__ __forceinline__ unsigned int f2ord(float f) {
  unsigned int u = __builtin_bit_cast(unsigned int, f);
  return (u & 0x80000000u) ? ~u : (u | 0x80000000u);
}

static __device__ __forceinline__ unsigned long long umax64(unsigned long long a,
                                                           unsigned long long b) {
  return a > b ? a : b;
}

// =====================================================================
// E[k,c] = sum_d slot_embed[k,d] * W_proj[d,c], stored as ET[c][k]
__global__ __launch_bounds__(256) void build_ET_k(const float* __restrict__ Wp,
                                                  const float* __restrict__ se,
                                                  float* __restrict__ ET) {
  int idx = blockIdx.x * 256 + threadIdx.x;
  if (idx >= C_ * KP_) return;
  int c = idx / KP_;
  int k = idx % KP_;
  float acc = 0.f;
  if (k < K_) {
    for (int d = 0; d < C_; d++) acc = fmaf(se[k * C_ + d], Wp[d * C_ + c], acc);
  }
  ET[idx] = acc;
}

// =====================================================================
// FUSED kernel, 512 threads/block:
//   blocks 0..3      : FPS (one per batch) -> anchors
//   blocks 4..1027   : semantic GEMM, 32 rows each -> Lsem into A region
//   blocks 1028..1091: build ext features
// FPS: exact spatially-pruned rescan. Points counting-sorted by 9-bit grid
// cell (one-time); each thread owns 16 CONSECUTIVE sorted points -> tight
// bbox. Per iteration a thread skips its update+scan entirely when
// d2min(anchor,bbox) >= its current max md (exact no-op; conservative
// 0.99998 margin vs float rounding). Whole waves skip via execz. The
// reduce (u64 key butterfly + LDS hop + tree + muL broadcast) and all
// selection arithmetic are bit-identical to the passing R7 version.
__global__ __launch_bounds__(512, 1) void fused_k(const float* __restrict__ s,
    const float* __restrict__ mu, const float* __restrict__ Sigma,
    const float* __restrict__ mask, const float* __restrict__ ET,
    float* __restrict__ anchors, float* __restrict__ ext,
    float* __restrict__ A) {
  const int bid = blockIdx.x;
  const int tid = threadIdx.x;

  // one arena shared by the fps branch (muL 96K + sIdx 32K + hist 2K) and
  // the gemm branch (s_lds 16.5K + et_lds 24K)
  __shared__ __align__(16) char arena[133120];
  __shared__ double redd[8][4];
  __shared__ unsigned long long redk[2][8];
  __shared__ float an_s[4];
  __shared__ unsigned int wtot[8];

  if (bid >= 1028) {
    int idx = (bid - 1028) * 512 + tid;
    if (idx < B_ * N_) {
      float x = mu[(size_t)idx * 3 + 0];
      float y = mu[(size_t)idx * 3 + 1];
      float z = mu[(size_t)idx * 3 + 2];
      const float* S = Sigma + (size_t)idx * 9;
      float* e = ext + (size_t)idx * 16;
      e[0] = x; e[1] = y; e[2] = z;
      e[3] = x * x; e[4] = x * y; e[5] = x * z;
      e[6] = y * y; e[7] = y * z; e[8] = z * z;
      e[9] = S[0]; e[10] = S[1]; e[11] = S[2]; e[12] = S[4]; e[13] = S[5]; e[14] = S[8];
      e[15] = 1.f;
    }
    return;
  }

  if (bid >= 4) {
    float (*s_lds)[132] = (float (*)[132])arena;
    float (*et_lds)[KP_] = (float (*)[KP_])(arena + 16896);
    const int gb = bid - 4;
    const int b = gb >> 8;
    const int n0 = (gb & 255) * 32;
    const int nt = tid >> 6;
    const int kt = tid & 63;
    {
      const float* sb = s + ((size_t)(b * N_ + n0)) * C_;
      int r = tid >> 4;
      int cb = (tid & 15) * 8;
#pragma unroll
      for (int q = 0; q < 2; q++) {
        float4 v = *(const float4*)(sb + (size_t)r * C_ + cb + q * 4);
        *(float4*)(&s_lds[r][cb + q * 4]) = v;
      }
    }
    float acc[4][12];
#pragma unroll
    for (int i = 0; i < 4; i++)
#pragma unroll
      for (int j = 0; j < 12; j++) acc[i][j] = 0.f;

    for (int cc = 0; cc < 16; cc++) {
      __syncthreads();
#pragma unroll
      for (int q = 0; q < 3; q++) {
        int fid = q * 512 + tid;
        int cl = fid / 192;
        int o4 = fid % 192;
        *(float4*)(&et_lds[cl][o4 * 4]) = *(const float4*)(ET + (size_t)(cc * 8 + cl) * KP_ + o4 * 4);
      }
      __syncthreads();
#pragma unroll
      for (int c8 = 0; c8 < 8; c8++) {
        int c = cc * 8 + c8;
        float sv0 = s_lds[nt * 4 + 0][c];
        float sv1 = s_lds[nt * 4 + 1][c];
        float sv2 = s_lds[nt * 4 + 2][c];
        float sv3 = s_lds[nt * 4 + 3][c];
#pragma unroll
        for (int j = 0; j < 12; j++) {
          float ev = et_lds[c8][kt + 64 * j];
          acc[0][j] = fmaf(sv0, ev, acc[0][j]);
          acc[1][j] = fmaf(sv1, ev, acc[1][j]);
          acc[2][j] = fmaf(sv2, ev, acc[2][j]);
          acc[3][j] = fmaf(sv3, ev, acc[3][j]);
        }
      }
    }
#pragma unroll
    for (int i = 0; i < 4; i++) {
      float* Arow = A + ((size_t)(b * N_ + n0 + nt * 4 + i)) * K_;
#pragma unroll
      for (int j = 0; j < 12; j++) {
        int k = kt + 64 * j;
        if (k < K_) Arow[k] = acc[i][j];
      }
    }
    return;
  }

  // ---------------- FPS ----------------
  const int b = bid;
  const int t = tid;
  const int wv = t >> 6;
  const float* mub = mu + (size_t)b * N_ * 3;
  const float* mkb = mask + (size_t)b * N_;

  float* muL = (float*)arena;                                   // [N*3] by ORIGINAL idx
  unsigned int* sIdx = (unsigned int*)(arena + 98304);          // [N] sorted -> origIdx
  unsigned int* histo = (unsigned int*)(arena + 98304 + 32768); // [512]

  histo[t] = 0;
  __syncthreads();

  // load (original layout), stage muL, histogram, masked mean (bit-identical
  // f64 order to R7)
  int pcell[16];
  unsigned int vbits = 0;
  double sx = 0, sy = 0, sz = 0, sc = 0;
#pragma unroll
  for (int i = 0; i < 16; i++) {
    int p = i * 512 + t;
    float x = mub[p * 3 + 0], y = mub[p * 3 + 1], z = mub[p * 3 + 2];
    muL[p * 3 + 0] = x; muL[p * 3 + 1] = y; muL[p * 3 + 2] = z;
    float mk = mkb[p];
    bool valid = (mk > 0.5f);
    if (valid) { vbits |= (1u << i); sx += x; sy += y; sz += z; sc += 1.0; }
    int cx = (int)fminf(fmaxf((x + 6.f) * (2.f / 3.f), 0.f), 7.f);
    int cy = (int)fminf(fmaxf((y + 6.f) * (2.f / 3.f), 0.f), 7.f);
    int cz = (int)fminf(fmaxf((z + 6.f) * (2.f / 3.f), 0.f), 7.f);
    pcell[i] = (cx << 6) | (cy << 3) | cz;
    atomicAdd(&histo[pcell[i]], 1u);
  }
  for (int off = 32; off; off >>= 1) {
    sx += __shfl_xor(sx, off);
    sy += __shfl_xor(sy, off);
    sz += __shfl_xor(sz, off);
    sc += __shfl_xor(sc, off);
  }
  if ((t & 63) == 0) { redd[wv][0] = sx; redd[wv][1] = sy; redd[wv][2] = sz; redd[wv][3] = sc; }
  __syncthreads();
  if (t == 0) {
    double ax0 = 0, ay0 = 0, az0 = 0, ac = 0;
    for (int w = 0; w < 8; w++) { ax0 += redd[w][0]; ay0 += redd[w][1]; az0 += redd[w][2]; ac += redd[w][3]; }
    if (ac < 1.0) ac = 1.0;
    an_s[0] = (float)(ax0 / ac); an_s[1] = (float)(ay0 / ac); an_s[2] = (float)(az0 / ac);
  }
  __syncthreads();

  // exclusive prefix over 512 cells (each thread owns exactly histo[t])
  {
    unsigned int h = histo[t];
    unsigned int sscan = h;
#pragma unroll
    for (int off = 1; off < 64; off <<= 1) {
      unsigned int o = __shfl_up(sscan, off);
      if ((t & 63) >= off) sscan += o;
    }
    if ((t & 63) == 63) wtot[wv] = sscan;
    __syncthreads();
    unsigned int base = 0;
#pragma unroll
    for (int w2 = 0; w2 < 8; w2++) base += (w2 < wv) ? wtot[w2] : 0u;
    histo[t] = base + sscan - h;   // exclusive offset (reused as cursor)
    __syncthreads();
  }

  // scatter: sorted slot -> origIdx (high bit = masked)
#pragma unroll
  for (int i = 0; i < 16; i++) {
    int p = i * 512 + t;
    unsigned int pos = atomicAdd(&histo[pcell[i]], 1u);
    sIdx[pos] = (unsigned int)p | (((vbits >> i) & 1u) ? 0u : 0x80000000u);
  }
  __syncthreads();

  // gather 16 consecutive sorted points; bbox over them
  float px[16], py[16], pz[16], md[16];
  int oi[16];
  float bnx = 3.4e38f, bny = 3.4e38f, bnz = 3.4e38f;
  float bxx = -3.4e38f, bxy = -3.4e38f, bxz = -3.4e38f;
  bool anyvalid = false;
  int minoi = 0x7fffffff;
#pragma unroll
  for (int j = 0; j < 16; j++) {
    unsigned int v = sIdx[t * 16 + j];
    int p = (int)(v & 0x7fffffffu);
    oi[j] = p;
    float x = muL[p * 3 + 0], y = muL[p * 3 + 1], z = muL[p * 3 + 2];
    px[j] = x; py[j] = y; pz[j] = z;
    bool msk = (v & 0x80000000u) != 0u;
    md[j] = msk ? -1.f : 3.4e38f;
    anyvalid |= !msk;
    minoi = min(minoi, p);
    bnx = fminf(bnx, x); bny = fminf(bny, y); bnz = fminf(bnz, z);
    bxx = fmaxf(bxx, x); bxy = fmaxf(bxy, y); bxz = fmaxf(bxz, z);
  }

  float ax, ay, az;
  // -------- first anchor: argmax of masked d2-from-mean --------
  {
    float cx = an_s[0], cy = an_s[1], cz = an_s[2];
    float bv = -2.f, bv2 = -2.f;
    int bi = 0x7fffffff, bi2 = 0x7fffffff;
#pragma unroll
    for (int j = 0; j < 16; j++) {
      float dx = px[j] - cx, dy = py[j] - cy, dz = pz[j] - cz;
      float d2 = __fadd_rn(__fadd_rn(__fmul_rn(dx, dx), __fmul_rn(dy, dy)), __fmul_rn(dz, dz));
      float v = (md[j] < 0.f) ? -1.f : d2;
      int p = oi[j];
      if (j & 1) { if (v > bv2 || (v == bv2 && p < bi2)) { bv2 = v; bi2 = p; } }
      else       { if (v > bv  || (v == bv  && p < bi )) { bv = v;  bi = p; } }
    }
    if (bv2 > bv || (bv2 == bv && bi2 < bi)) { bv = bv2; bi = bi2; }
    unsigned long long k0 = ((unsigned long long)f2ord(bv) << 32) | (unsigned int)(~bi);
    for (int off = 32; off; off >>= 1) {
      unsigned long long ok = __shfl_xor(k0, off);
      if (ok > k0) k0 = ok;
    }
    if ((t & 63) == 0) redk[0][wv] = k0;
    __syncthreads();
    unsigned long long a0 = redk[0][0], a1 = redk[0][1], a2 = redk[0][2], a3 = redk[0][3];
    unsigned long long a4 = redk[0][4], a5 = redk[0][5], a6 = redk[0][6], a7 = redk[0][7];
    unsigned long long bk = umax64(umax64(umax64(a0, a1), umax64(a2, a3)),
                                  umax64(umax64(a4, a5), umax64(a6, a7)));
    int besti = (int)(~(unsigned int)bk);
    ax = muL[besti * 3 + 0]; ay = muL[besti * 3 + 1]; az = muL[besti * 3 + 2];
    if (t == 0) {
      float aa = ax * ax + ay * ay + az * az;
      float4 st = {ax, ay, az, aa};
      *(float4*)(anchors + ((size_t)b * KP_ + 0) * 4) = st;
    }
  }

  // per-thread pruning state
  float ubv;
  unsigned long long kk;
  if (anyvalid) {
    ubv = 3.4e38f;                         // forces update at k=1
    kk = ((unsigned long long)f2ord(-1.f) << 32) | (unsigned int)(~minoi);
  } else {
    ubv = -1.f;                            // skips forever
    kk = ((unsigned long long)f2ord(-1.f) << 32) | (unsigned int)(~minoi);
  }

  // -------- main loop: one barrier per iteration --------
  for (int k = 1; k < K_; k++) {
    const int par = k & 1;
    // exact skip test: d2min(anchor,bbox) vs current max md (conservative)
    float gx = fmaxf(fmaxf(bnx - ax, ax - bxx), 0.f);
    float gy = fmaxf(fmaxf(bny - ay, ay - bxy), 0.f);
    float gz = fmaxf(fmaxf(bnz - az, az - bxz), 0.f);
    float d2box = gx * gx + gy * gy + gz * gz;
    if (d2box * 0.99998f < ubv) {
      float bv = -2.f, bv2 = -2.f;
      int bi = 0x7fffffff, bi2 = 0x7fffffff;
#pragma unroll
      for (int j = 0; j < 16; j++) {
        float dx = px[j] - ax, dy = py[j] - ay, dz = pz[j] - az;
        float d2 = __fadd_rn(__fadd_rn(__fmul_rn(dx, dx), __fmul_rn(dy, dy)), __fmul_rn(dz, dz));
        float m = fminf(md[j], d2);
        md[j] = m;
        int p = oi[j];
        if (j & 1) { if (m > bv2 || (m == bv2 && p < bi2)) { bv2 = m; bi2 = p; } }
        else       { if (m > bv  || (m == bv  && p < bi )) { bv = m;  bi = p; } }
      }
      if (bv2 > bv || (bv2 == bv && bi2 < bi)) { bv = bv2; bi = bi2; }
      ubv = bv;
      kk = ((unsigned long long)f2ord(bv) << 32) | (unsigned int)(~bi);
    }
    unsigned long long kr = kk;
    for (int off = 32; off; off >>= 1) {
      unsigned long long ok = __shfl_xor(kr, off);
      if (ok > kr) kr = ok;
    }
    if ((t & 63) == 0) redk[par][wv] = kr;
    __syncthreads();
    unsigned long long a0 = redk[par][0], a1 = redk[par][1], a2 = redk[par][2], a3 = redk[par][3];
    unsigned long long a4 = redk[par][4], a5 = redk[par][5], a6 = redk[par][6], a7 = redk[par][7];
    unsigned long long bk = umax64(umax64(umax64(a0, a1), umax64(a2, a3)),
                                  umax64(umax64(a4, a5), umax64(a6, a7)));
    int besti = (int)(~(unsigned int)bk);
    ax = muL[besti * 3 + 0]; ay = muL[besti * 3 + 1]; az = muL[besti * 3 + 2];
    if (t == 0) {
      float aa = ax * ax + ay * ay + az * az;
      float4 st = {ax, ay, az, aa};
      *(float4*)(anchors + ((size_t)b * KP_ + k) * 4) = st;
    }
  }
  for (int k = K_ + t; k < KP_; k += 512) {
    float4 z4 = {0.f, 0.f, 0.f, 0.f};
    *(float4*)(anchors + ((size_t)b * KP_ + k) * 4) = z4;
  }
}

// =====================================================================
// spatial logits + mask + softmax, in place over A (holds Lsem).
__global__ __launch_bounds__(256) void spatial_softmax_k(
    const float* __restrict__ mu, const float* __restrict__ mask,
    const float* __restrict__ anchors, const float* __restrict__ lsm_p,
    const float* __restrict__ wsem_p, const float* __restrict__ wmu_p,
    float* __restrict__ A) {
  const int bid = blockIdx.x;
  const int b = bid >> 11;
  const int n0 = (bid & 2047) * 4;
  const int tid = threadIdx.x;
  const int wv = tid >> 6;
  const int lane = tid & 63;
  __shared__ __align__(16) float anch_lds[KP_][4];
  for (int q = tid; q < KP_; q += 256)
    *(float4*)(&anch_lds[q][0]) = *(const float4*)(anchors + ((size_t)b * KP_ + q) * 4);
  __syncthreads();

  const float sg = fmaxf(expf(lsm_p[0]), 1e-4f);
  const float inv2s2 = 0.5f / (sg * sg);
  const float wsem = wsem_p[0];
  const float wmu = wmu_p[0];

  const size_t gr = (size_t)b * N_ + n0 + wv;
  const float* mp = mu + gr * 3;
  float x = mp[0], y = mp[1], z = mp[2];
  float mq = x * x + y * y + z * z;
  float mk = mask[gr];
  float* Arow = A + gr * K_;

  float v[11];
  float m = -3e38f;
#pragma unroll
  for (int j = 0; j < 11; j++) {
    int k = lane + 64 * j;
    if (k < K_) {
      float lsem = Arow[k];
      float4 a4 = *(const float4*)(&anch_lds[k][0]);
      float tdot = x * a4.x + y * a4.y + z * a4.z;
      float d2 = mq - 2.f * tdot + a4.w;
      float l = wsem * lsem - wmu * d2 * inv2s2;
      if (mk < 0.5f) l = -1e9f;
      v[j] = l;
    } else v[j] = -1e30f;
    m = fmaxf(m, v[j]);
  }
  for (int off = 32; off; off >>= 1) m = fmaxf(m, __shfl_xor(m, off));
  float sum = 0.f;
#pragma unroll
  for (int j = 0; j < 11; j++) { float e = expf(v[j] - m); v[j] = e; sum += e; }
  for (int off = 32; off; off >>= 1) sum += __shfl_xor(sum, off);
  float r = mk / sum;
#pragma unroll
  for (int j = 0; j < 11; j++) {
    int k = lane + 64 * j;
    if (k < K_) Arow[k] = v[j] * r;
  }
}

// =====================================================================
// Transpose A fp32 [b][n][683] -> At bf16 [b][768][8192] (pad rows zero)
__global__ __launch_bounds__(256) void transpose_at_k(const float* __restrict__ A,
    unsigned short* __restrict__ At) {
  const int bid = blockIdx.x;          // b(4) * ktile(12) * ntile(128)
  const int ntile = bid % 128;
  const int rem = bid / 128;
  const int kt = rem % 12;
  const int b = rem / 12;
  const int k0 = kt * 64, n0 = ntile * 64;
  const int tid = threadIdx.x;
  __shared__ __align__(16) unsigned short T[64][72];

  {
    const int n_loc = tid >> 4;        // 0..15
    const int k4 = (tid & 15) * 4;
#pragma unroll
    for (int nn = 0; nn < 4; nn++) {
      int n = n_loc + 16 * nn;
      const float* ar = A + ((size_t)(b * N_ + n0 + n)) * K_;
#pragma unroll
      for (int q = 0; q < 4; q++) {
        int kk = k0 + k4 + q;
        float f = (kk < K_) ? ar[kk] : 0.f;
        T[k4 + q][n] = f2bf_rne(f);
      }
    }
  }
  __syncthreads();
  {
    const int k_loc = tid >> 2;        // 0..63
    const int c = tid & 3;             // 16-ushort chunk
    uint4 v0 = *(const uint4*)(&T[k_loc][c * 16]);
    uint4 v1 = *(const uint4*)(&T[k_loc][c * 16 + 8]);
    unsigned short* dst = At + ((size_t)(b * KP_ + k0 + k_loc)) * N_ + n0 + c * 16;
    *(uint4*)dst = v0;
    *(uint4*)(dst + 8) = v1;
  }
}

// =====================================================================
// MFMA gram + fused collapse-loss tile partial.
// 84 blocks = 4 b x 21 symmetric 128x128 tiles; full N reduction per block.
__global__ __launch_bounds__(256) void gram_mfma_k(const unsigned short* __restrict__ At,
    const float* __restrict__ norm_ws, float* __restrict__ lossp) {
  const int bid = blockIdx.x;
  const int b = bid / 21;
  int p = bid % 21;
  int tk = 0, tl = 0;
  { int pp = p; for (int r0 = 0; r0 < 6; r0++) { int cnt = 6 - r0; if (pp < cnt) { tk = r0; tl = r0 + pp; break; } pp -= cnt; } }
  const int k0 = tk * 128, l0 = tl * 128;
  const int tid = threadIdx.x;
  const int l = tid & 63;
  const int w = tid >> 6;
  const int wr = w >> 1, wc = w & 1;

  __shared__ __align__(16) unsigned short Ak_lds[128 * 72];
  __shared__ __align__(16) unsigned short Al_lds[128 * 72];
  __shared__ float nk_s[128], nl_s[128], red_s[4];

  if (tid < 128) {
    int kk = k0 + tid;
    nk_s[tid] = (kk < K_) ? fmaxf(norm_ws[b * KT_ + kk], 1e-8f) : 1.f;
  } else {
    int ll2 = l0 + tid - 128;
    nl_s[tid - 128] = (ll2 < K_) ? fmaxf(norm_ws[b * KT_ + ll2], 1e-8f) : 1.f;
  }

  f32x4 acc[4][4];
#pragma unroll
  for (int i = 0; i < 4; i++)
#pragma unroll
    for (int j = 0; j < 4; j++) acc[i][j] = (f32x4){0.f, 0.f, 0.f, 0.f};

  const unsigned short* gk = At + ((size_t)(b * KP_ + k0)) * N_;
  const unsigned short* gl = At + ((size_t)(b * KP_ + l0)) * N_;

  for (int ch = 0; ch < 128; ch++) {
    const int n0 = ch * 64;
    __syncthreads();
#pragma unroll
    for (int q = 0; q < 4; q++) {
      int chunk = tid + 256 * q;
      int row = chunk >> 3, slot = chunk & 7;
      uint4 v = *(const uint4*)(gk + (size_t)row * N_ + n0 + slot * 8);
      *(uint4*)(Ak_lds + row * 72 + slot * 8) = v;
      uint4 v2 = *(const uint4*)(gl + (size_t)row * N_ + n0 + slot * 8);
      *(uint4*)(Al_lds + row * 72 + slot * 8) = v2;
    }
    __syncthreads();
#pragma unroll
    for (int ks = 0; ks < 2; ks++) {
      const int noff = (l >> 4) * 8 + ks * 32;
      bf16x8s af[4], bfr[4];
#pragma unroll
      for (int f = 0; f < 4; f++) {
        af[f]  = *(const bf16x8s*)(Ak_lds + (wr * 64 + f * 16 + (l & 15)) * 72 + noff);
        bfr[f] = *(const bf16x8s*)(Al_lds + (wc * 64 + f * 16 + (l & 15)) * 72 + noff);
      }
#pragma unroll
      for (int i = 0; i < 4; i++)
#pragma unroll
        for (int j = 0; j < 4; j++)
          acc[i][j] = __builtin_amdgcn_mfma_f32_16x16x32_bf16(af[i], bfr[j], acc[i][j], 0, 0, 0);
    }
  }

  // epilogue: loss partial for this tile
  float local = 0.f;
  const float wgt = (tk == tl) ? 1.f : 2.f;
#pragma unroll
  for (int i = 0; i < 4; i++) {
#pragma unroll
    for (int j = 0; j < 4; j++) {
#pragma unroll
      for (int r = 0; r < 4; r++) {
        int ki = wr * 64 + i * 16 + (l >> 4) * 4 + r;   // local row
        int li = wc * 64 + j * 16 + (l & 15);           // local col
        int gkk = k0 + ki, gll = l0 + li;
        if (gkk < K_ && gll < K_ && gkk != gll) {
          float g = acc[i][j][r];
          float x = g / (nk_s[ki] * nl_s[li]);
          local = fmaf(wgt * x, x, local);
        }
      }
    }
  }
  for (int off = 32; off; off >>= 1) local += __shfl_xor(local, off);
  if ((tid & 63) == 0) red_s[w] = local;
  __syncthreads();
  if (tid == 0) lossp[bid] = red_s[0] + red_s[1] + red_s[2] + red_s[3];
}

// =====================================================================
// GEMM2: moments = A^T x F, F = [s(128) | ext(16) | pad(16)], plus sum(A^2).
__global__ __launch_bounds__(256) void gemm2_k(const float* __restrict__ A,
    const float* __restrict__ s, const float* __restrict__ ext,
    float* __restrict__ part) {
  const int bid = blockIdx.x;
  const int np = bid / 44;
  const int rem = bid % 44;
  const int b = rem / 11;
  const int k0 = (rem % 11) * 64;
  const int n0 = np * 1024;
  const int tid = threadIdx.x;
  const int kt = tid & 15;
  const int ft = tid >> 4;
  __shared__ __align__(16) float A_lds[32][64];
  __shared__ __align__(16) float F_lds[32][160];
  float acc[4][10];
#pragma unroll
  for (int c = 0; c < 4; c++)
#pragma unroll
    for (int f = 0; f < 10; f++) acc[c][f] = 0.f;
  float asq[4] = {0.f, 0.f, 0.f, 0.f};

  for (int ch = 0; ch < 32; ch++) {
    int nb = n0 + ch * 32;
    __syncthreads();
#pragma unroll
    for (int p = 0; p < 8; p++) {
      int q = tid + 256 * p; int r = q >> 6; int c = q & 63; int k = k0 + c;
      A_lds[r][c] = (k < K_) ? A[((size_t)(b * N_ + nb + r)) * K_ + k] : 0.f;
    }
#pragma unroll
    for (int p = 0; p < 16; p++) {
      int q = tid + 256 * p; int r = q >> 7; int c = q & 127;
      F_lds[r][c] = s[((size_t)(b * N_ + nb + r)) * C_ + c];
    }
#pragma unroll
    for (int p = 0; p < 2; p++) {
      int q = tid + 256 * p; int r = q >> 4; int e = q & 15;
      F_lds[r][128 + e] = ext[((size_t)(b * N_ + nb + r)) * 16 + e];
      F_lds[r][144 + e] = 0.f;
    }
    __syncthreads();
#pragma unroll
    for (int i = 0; i < 32; i++) {
      float a0 = A_lds[i][kt * 4 + 0];
      float a1 = A_lds[i][kt * 4 + 1];
      float a2 = A_lds[i][kt * 4 + 2];
      float a3 = A_lds[i][kt * 4 + 3];
      if (ft == 0) {
        asq[0] = fmaf(a0, a0, asq[0]); asq[1] = fmaf(a1, a1, asq[1]);
        asq[2] = fmaf(a2, a2, asq[2]); asq[3] = fmaf(a3, a3, asq[3]);
      }
#pragma unroll
      for (int f = 0; f < 10; f++) {
        float fv = F_lds[i][ft * 10 + f];
        acc[0][f] = fmaf(a0, fv, acc[0][f]);
        acc[1][f] = fmaf(a1, fv, acc[1][f]);
        acc[2][f] = fmaf(a2, fv, acc[2][f]);
        acc[3][f] = fmaf(a3, fv, acc[3][f]);
      }
    }
  }
#pragma unroll
  for (int c = 0; c < 4; c++) {
    size_t base = ((size_t)((np * 4 + b) * KT_ + k0 + kt * 4 + c)) * 168;
#pragma unroll
    for (int f = 0; f < 10; f++) part[base + ft * 10 + f] = acc[c][f];
    if (ft == 0) part[base + 160] = asq[c];
  }
}

// =====================================================================
// Postprocess: one wave per (b,k): s_c, mu_c, Sigma_c, sumA, norms.
__global__ __launch_bounds__(256) void postproc_k(const float* __restrict__ part,
    float* __restrict__ out, float* __restrict__ sumA_ws, float* __restrict__ norm_ws) {
  const int gw = blockIdx.x * 4 + (threadIdx.x >> 6);
  const int lane = threadIdx.x & 63;
  const int b = gw / K_;
  const int k = gw % K_;
  float v0 = 0.f, v1 = 0.f, v2 = 0.f, v3 = 0.f;
  for (int np = 0; np < 8; np++) {
    const float* r = part + ((size_t)((np * 4 + b) * KT_ + k)) * 168;
    v0 += r[lane];
    v1 += r[64 + lane];
    if (lane < 16) v2 += r[128 + lane];
    if (lane == 0) v3 += r[160];
  }
  float sumA = __shfl(v2, 15);
  float asq = __shfl(v3, 0);
  float denom = fmaxf(sumA, 1e-8f);
  float inv = 1.f / denom;
  out[OUT_SC + ((size_t)(b * K_ + k)) * C_ + lane] = v0 * inv;
  out[OUT_SC + ((size_t)(b * K_ + k)) * C_ + 64 + lane] = v1 * inv;
  float m0 = __shfl(v2, 0) * inv;
  float m1 = __shfl(v2, 1) * inv;
  float m2 = __shfl(v2, 2) * inv;
  if (lane < 3) out[OUT_MUC + ((size_t)(b * K_ + k)) * 3 + lane] = (lane == 0) ? m0 : ((lane == 1) ? m1 : m2);
  float W = sumA * inv;
  float fac = 2.f - W;
  float M2s[6], Sgs[6];
#pragma unroll
  for (int j = 0; j < 6; j++) { M2s[j] = __shfl(v2, 3 + j); Sgs[j] = __shfl(v2, 9 + j); }
  if (lane < 9) {
    int d = lane / 3, e = lane % 3;
    int lo = min(d, e), hi = max(d, e);
    int j = hi + 2 * lo - ((lo * (lo - 1)) >> 1);
    float mud = (d == 0) ? m0 : ((d == 1) ? m1 : m2);
    float mue = (e == 0) ? m0 : ((e == 1) ? m1 : m2);
    float M2j = (j == 0) ? M2s[0] : (j == 1) ? M2s[1] : (j == 2) ? M2s[2] : (j == 3) ? M2s[3] : (j == 4) ? M2s[4] : M2s[5];
    float Sgj = (j == 0) ? Sgs[0] : (j == 1) ? Sgs[1] : (j == 2) ? Sgs[2] : (j == 3) ? Sgs[3] : (j == 4) ? Sgs[4] : Sgs[5];
    float val = (Sgj + M2j) * inv - mud * mue * fac;
    if (d == e) val += 1e-6f;
    out[OUT_SGC + ((size_t)(b * K_ + k)) * 9 + lane] = val;
  }
  if (lane == 0) { sumA_ws[b * KT_ + k] = sumA; norm_ws[b * KT_ + k] = sqrtf(asq); }
}

// =====================================================================
// OLD fp32 gram path (fallback if ws too small for At)
__device__ __forceinline__ int swz(int f) { return f ^ (((f >> 5) & 3) << 3); }

__global__ __launch_bounds__(256) void gram_k(const float* __restrict__ A,
                                              float* __restrict__ Gpart) {
  const int bid = blockIdx.x;
  const int np = bid & 1;
  int q = bid >> 1;
  const int b = q / 21;
  int p = q % 21;
  int tk = 0, tl = 0;
  { int pp = p; for (int r0 = 0; r0 < 6; r0++) { int cnt = 6 - r0; if (pp < cnt) { tk = r0; tl = r0 + pp; break; } pp -= cnt; } }
  const int k0 = tk * 128, l0 = tl * 128;
  const int n0 = np * 4096;
  const int tid = threadIdx.x;
  const int ktid = tid & 15, ltid = tid >> 4;
  const bool diag = (tk == tl);
  __shared__ __align__(16) float Ak[32][128];
  __shared__ __align__(16) float Al[32][128];
  float acc[8][8];
#pragma unroll
  for (int i = 0; i < 8; i++)
#pragma unroll
    for (int j = 0; j < 8; j++) acc[i][j] = 0.f;

  const int kb = swz(ktid * 8);
  const int lb = swz(ltid * 8);
  for (int ch = 0; ch < 128; ch++) {
    int nb = n0 + ch * 32;
    __syncthreads();
#pragma unroll
    for (int pq = 0; pq < 16; pq++) {
      int qq = tid + 256 * pq; int r = qq >> 7; int c = qq & 127;
      int kk = k0 + c;
      Ak[r][swz(c)] = (kk < K_) ? A[((size_t)(b * N_ + nb + r)) * K_ + kk] : 0.f;
      if (!diag) {
        int ll = l0 + c;
        Al[r][swz(c)] = (ll < K_) ? A[((size_t)(b * N_ + nb + r)) * K_ + ll] : 0.f;
      }
    }
    __syncthreads();
    const float (*Alp)[128] = diag ? Ak : Al;
#pragma unroll
    for (int i = 0; i < 32; i++) {
      float4 ka = *(const float4*)(&Ak[i][kb]);
      float4 kb4 = *(const float4*)(&Ak[i][kb + 4]);
      float4 la = *(const float4*)(&Alp[i][lb]);
      float4 lb4 = *(const float4*)(&Alp[i][lb + 4]);
      float av[8] = {ka.x, ka.y, ka.z, ka.w, kb4.x, kb4.y, kb4.z, kb4.w};
      float lv[8] = {la.x, la.y, la.z, la.w, lb4.x, lb4.y, lb4.z, lb4.w};
#pragma unroll
      for (int ii = 0; ii < 8; ii++)
#pragma unroll
        for (int jj = 0; jj < 8; jj++)
          acc[ii][jj] = fmaf(av[ii], lv[jj], acc[ii][jj]);
    }
  }
#pragma unroll
  for (int ii = 0; ii < 8; ii++) {
    int kk = k0 + ktid * 8 + ii;
    float* gp = Gpart + ((size_t)((np * 4 + b) * KP_ + kk)) * KP_ + l0 + ltid * 8;
#pragma unroll
    for (int jj = 0; jj < 8; jj++) gp[jj] = acc[ii][jj];
  }
}

__global__ __launch_bounds__(256) void loss_part_k(const float* __restrict__ Gpart,
    const float* __restrict__ norm_ws, float* __restrict__ lossp) {
  const long long total = (long long)B_ * 21 * 16384;
  float local = 0.f;
  for (long long idx = (long long)blockIdx.x * 256 + threadIdx.x; idx < total; idx += (long long)512 * 256) {
    int e = (int)(idx & 16383);
    int rest = (int)(idx >> 14);
    int p = rest % 21;
    int b = rest / 21;
    int tk = 0, tl = 0;
    { int pp = p; for (int r0 = 0; r0 < 6; r0++) { int cnt = 6 - r0; if (pp < cnt) { tk = r0; tl = r0 + pp; break; } pp -= cnt; } }
    int i = e >> 7, j = e & 127;
    int k = tk * 128 + i, l = tl * 128 + j;
    if (k < K_ && l < K_ && k != l) {
      size_t i0 = ((size_t)((0 * 4 + b) * KP_ + k)) * KP_ + l;
      size_t i1 = ((size_t)((1 * 4 + b) * KP_ + k)) * KP_ + l;
      float g = Gpart[i0] + Gpart[i1];
      float nk = fmaxf(norm_ws[b * KT_ + k], 1e-8f);
      float nl2 = fmaxf(norm_ws[b * KT_ + l], 1e-8f);
      float x = g / (nk * nl2);
      float wgt = (tk == tl) ? 1.f : 2.f;
      local = fmaf(wgt * x, x, local);
    }
  }
  __shared__ float red[4];
  for (int off = 32; off; off >>= 1) local += __shfl_xor(local, off);
  if ((threadIdx.x & 63) == 0) red[threadIdx.x >> 6] = local;
  __syncthreads();
  if (threadIdx.x == 0) lossp[blockIdx.x] = red[0] + red[1] + red[2] + red[3];
}

__global__ __launch_bounds__(256) void final_k(const float* __restrict__ sumA_ws,
    const float* __restrict__ lossp, float* __restrict__ out) {
  const int lane = threadIdx.x & 63;
  const int wv = threadIdx.x >> 6;
  __shared__ float occ_s[4];
  __shared__ float col_s[4];
  float sb = 0.f;
  for (int k = lane; k < K_; k += 64) sb += sumA_ws[wv * KT_ + k];
  for (int off = 32; off; off >>= 1) sb += __shfl_xor(sb, off);
  float Sb = fmaxf(sb, 1e-8f);
  float lo = 0.f;
  const float tgt = 1.f / (float)K_;
  for (int k = lane; k < K_; k += 64) {
    float o = sumA_ws[wv * KT_ + k] / Sb - tgt;
    lo = fmaf(o, o, lo);
  }
  for (int off = 32; off; off >>= 1) lo += __shfl_xor(lo, off);
  if (lane == 0) occ_s[wv] = lo;
  float c = lossp[threadIdx.x] + lossp[threadIdx.x + 256];
  for (int off = 32; off; off >>= 1) c += __shfl_xor(c, off);
  if (lane == 0) col_s[wv] = c;
  __syncthreads();
  if (threadIdx.x == 0) {
    float loss_occ = (occ_s[0] + occ_s[1] + occ_s[2] + occ_s[3]) / (float)(B_ * K_);
    float coll = (col_s[0] + col_s[1] + col_s[2] + col_s[3]) / ((float)B_ * K_ * K_);
    out[OUT_TOT] = loss_occ + 0.1f * coll;
  }
}

// final for the MFMA path: 84 tile partials
__global__ __launch_bounds__(256) void final2_k(const float* __restrict__ sumA_ws,
    const float* __restrict__ lossp, float* __restrict__ out) {
  const int lane = threadIdx.x & 63;
  const int wv = threadIdx.x >> 6;
  __shared__ float occ_s[4];
  __shared__ float col_s[4];
  float sb = 0.f;
  for (int k = lane; k < K_; k += 64) sb += sumA_ws[wv * KT_ + k];
  for (int off = 32; off; off >>= 1) sb += __shfl_xor(sb, off);
  float Sb = fmaxf(sb, 1e-8f);
  float lo = 0.f;
  const float tgt = 1.f / (float)K_;
  for (int k = lane; k < K_; k += 64) {
    float o = sumA_ws[wv * KT_ + k] / Sb - tgt;
    lo = fmaf(o, o, lo);
  }
  for (int off = 32; off; off >>= 1) lo += __shfl_xor(lo, off);
  if (lane == 0) occ_s[wv] = lo;
  float c = 0.f;
  for (int i = threadIdx.x; i < 84; i += 256) c += lossp[i];
  for (int off = 32; off; off >>= 1) c += __shfl_xor(c, off);
  if (lane == 0) col_s[wv] = c;
  __syncthreads();
  if (threadIdx.x == 0) {
    float loss_occ = (occ_s[0] + occ_s[1] + occ_s[2] + occ_s[3]) / (float)(B_ * K_);
    float coll = (col_s[0] + col_s[1] + col_s[2] + col_s[3]) / ((float)B_ * K_ * K_);
    out[OUT_TOT] = loss_occ + 0.1f * coll;
  }
}

// =====================================================================
extern "C" void kernel_launch(void* const* d_in, const int* in_sizes, int n_in,
                              void* d_out, int out_size, void* d_ws, size_t ws_size,
                              hipStream_t stream) {
  const float* s = (const float*)d_in[0];
  const float* mu = (const float*)d_in[1];
  const float* Sigma = (const float*)d_in[2];
  const float* mask = (const float*)d_in[3];
  const float* Wp = (const float*)d_in[4];
  const float* se = (const float*)d_in[5];
  const float* lsm = (const float*)d_in[6];
  const float* wsem = (const float*)d_in[7];
  const float* wmu = (const float*)d_in[8];
  float* out = (float*)d_out;
  float* ws = (float*)d_ws;

  float* ET = ws + WS_ET;
  float* anch = ws + WS_ANCH;
  float* ext = ws + WS_EXT;
  float* part = ws + WS_PART;
  float* sumA = ws + WS_SUMA;
  float* nrm = ws + WS_NORM;

  hipLaunchKernelGGL(build_ET_k, dim3(384), dim3(256), 0, stream, Wp, se, ET);
  hipLaunchKernelGGL(fused_k, dim3(1092), dim3(512), 0, stream, s, mu, Sigma, mask, ET, anch, ext, out);
  hipLaunchKernelGGL(spatial_softmax_k, dim3(8192), dim3(256), 0, stream, mu, mask, anch, lsm, wsem, wmu, out);
  hipLaunchKernelGGL(gemm2_k, dim3(352), dim3(256), 0, stream, out, s, ext, part);
  hipLaunchKernelGGL(postproc_k, dim3(683), dim3(256), 0, stream, part, out, sumA, nrm);

  const bool use_mfma = ws_size >= (size_t)WS_NEW_END * 4;
  if (use_mfma) {
    float* lossp2 = ws + WS_LOSSP2;
    unsigned short* At = (unsigned short*)(ws + WS_AT);
    hipLaunchKernelGGL(transpose_at_k, dim3(4 * 12 * 128), dim3(256), 0, stream, out, At);
    hipLaunchKernelGGL(gram_mfma_k, dim3(84), dim3(256), 0, stream, At, nrm, lossp2);
    hipLaunchKernelGGL(final2_k, dim3(1), dim3(256), 0, stream, sumA, lossp2, out);
  } else {
    float* Gpart = ws + WS_GPART;
    float* lossp = ws + WS_LOSSP;
    hipLaunchKernelGGL(gram_k, dim3(168), dim3(256), 0, stream, out, Gpart);
    hipLaunchKernelGGL(loss_part_k, dim3(512), dim3(256), 0, stream, Gpart, nrm, lossp);
    hipLaunchKernelGGL(final_k, dim3(1), dim3(256), 0, stream, sumA, lossp, out);
  }
}

// Round 9
// 1264.289 us; speedup vs baseline: 1.2453x; 1.2453x over previous
//
#include <hip/hip_runtime.h>
#include <hip/hip_bf16.h>
#include <math.h>

#define B_ 4
#define N_ 8192
#define C_ 128
#define K_ 683
#define KP_ 768
#define KT_ 704   // 11*64 padded K for ext moments

// ---- workspace layout, MFMA path (float offsets) ----
#define WS_ET      0          // 128*768            = 98304
#define WS_ANCH    98304      // 4*768*4            = 12288
#define WS_EXT     110592     // 4*8192*16          = 524288
#define WS_EPART   634880     // 8*4*704*32         = 720896
#define WS_MPART   1355776    // 2*4*768*128        = 786432
#define WS_SUMA    2142208    // 4*704              = 2816
#define WS_NORM    2145024    // 4*704              = 2816
#define WS_LOSSP2  2147840    // 128
#define WS_ST      2147968    // bf16 4*128*8192    = 2097152 floats worth
#define WS_AT      4245120    // bf16 4*768*8192    = 12582912 floats worth
#define WS_NEW_END 16828032   // floats -> 67,312,128 bytes (<= proven 68MB)
// ---- old fallback offsets ----
#define OLD_PART   634880
#define OLD_SUMA   4419584
#define OLD_NORM   4422400
#define OLD_GPART  4425216
#define OLD_LOSSP  9143808

// ---- output layout (float offsets) ----
#define OUT_A      0
#define OUT_SC     22380544ULL
#define OUT_MUC    22730240ULL
#define OUT_SGC    22738436ULL
#define OUT_TOT    22763024ULL

typedef __attribute__((ext_vector_type(8))) short bf16x8s;
typedef __attribute__((ext_vector_type(4))) float f32x4;

static __device__ __forceinline__ unsigned short f2bf_rne(float f) {
  unsigned int u = __builtin_bit_cast(unsigned int, f);
  unsigned int r = (u + 0x7fffu + ((u >> 16) & 1u)) >> 16;
  return (unsigned short)r;
}

// monotone float -> u32 (order-preserving incl. negatives; no NaNs here)
static __device__ __forceinline__ unsigned int f2ord(float f) {
  unsigned int u = __builtin_bit_cast(unsigned int, f);
  return (u & 0x80000000u) ? ~u : (u | 0x80000000u);
}

static __device__ __forceinline__ unsigned long long umax64(unsigned long long a,
                                                           unsigned long long b) {
  return a > b ? a : b;
}

// =====================================================================
// E[k,c] = sum_d slot_embed[k,d] * W_proj[d,c], stored as ET[c][k]
__global__ __launch_bounds__(256) void build_ET_k(const float* __restrict__ Wp,
                                                  const float* __restrict__ se,
                                                  float* __restrict__ ET) {
  int idx = blockIdx.x * 256 + threadIdx.x;
  if (idx >= C_ * KP_) return;
  int c = idx / KP_;
  int k = idx % KP_;
  float acc = 0.f;
  if (k < K_) {
    for (int d = 0; d < C_; d++) acc = fmaf(se[k * C_ + d], Wp[d * C_ + c], acc);
  }
  ET[idx] = acc;
}

// =====================================================================
// FUSED kernel, 512 threads/block:
//   blocks 0..3      : FPS (one per batch) -> anchors  [R7 structure, 878us]
//   blocks 4..1027   : semantic GEMM, 32 rows each -> Lsem into A region
//   blocks 1028..1091: build ext features
//   blocks 1092..1347: sT bf16 builder: s[n][c] -> sT[b][c][n]
__global__ __launch_bounds__(512, 1) void fused_k(const float* __restrict__ s,
    const float* __restrict__ mu, const float* __restrict__ Sigma,
    const float* __restrict__ mask, const float* __restrict__ ET,
    float* __restrict__ anchors, float* __restrict__ ext,
    float* __restrict__ A, unsigned short* __restrict__ sT) {
  const int bid = blockIdx.x;
  const int tid = threadIdx.x;

  __shared__ __align__(16) float s_lds[32][132];
  __shared__ __align__(16) float et_lds[8][KP_];
  __shared__ __align__(16) float muL[N_ * 3];        // 96 KB (fps only)
  __shared__ __align__(16) float Tt[64][72];         // sT builder transpose tile
  __shared__ double redd[8][4];
  __shared__ unsigned long long redk[2][8];
  __shared__ float an_s[4];

  if (bid >= 1092) {
    // ---------------- sT builder ----------------
    const int sb = bid - 1092;      // 0..255
    const int b = sb >> 6;
    const int rest = sb & 63;
    const int chalf = rest >> 5;    // c-half 0..1
    const int ns = rest & 31;       // n-slab of 256
    const int c0 = chalf * 64, n0 = ns * 256;
#pragma unroll
    for (int t2 = 0; t2 < 4; t2++) {
      const int nb = n0 + t2 * 64;
      {
        int n_loc = tid >> 3;
        int cb = (tid & 7) * 8;
        const float* sp = s + ((size_t)(b * N_ + nb + n_loc)) * C_ + c0 + cb;
        float4 v0 = *(const float4*)(sp);
        float4 v1 = *(const float4*)(sp + 4);
        Tt[cb + 0][n_loc] = v0.x; Tt[cb + 1][n_loc] = v0.y;
        Tt[cb + 2][n_loc] = v0.z; Tt[cb + 3][n_loc] = v0.w;
        Tt[cb + 4][n_loc] = v1.x; Tt[cb + 5][n_loc] = v1.y;
        Tt[cb + 6][n_loc] = v1.z; Tt[cb + 7][n_loc] = v1.w;
      }
      __syncthreads();
      {
        int row = tid >> 3;        // c-local
        int qo = tid & 7;          // 8-value chunk
        float4 f0 = *(const float4*)(&Tt[row][qo * 8]);
        float4 f1 = *(const float4*)(&Tt[row][qo * 8 + 4]);
        unsigned short o[8];
        o[0] = f2bf_rne(f0.x); o[1] = f2bf_rne(f0.y); o[2] = f2bf_rne(f0.z); o[3] = f2bf_rne(f0.w);
        o[4] = f2bf_rne(f1.x); o[5] = f2bf_rne(f1.y); o[6] = f2bf_rne(f1.z); o[7] = f2bf_rne(f1.w);
        unsigned short* dst = sT + ((size_t)(b * C_ + c0 + row)) * N_ + nb + qo * 8;
        *(uint4*)dst = *(uint4*)o;
      }
      __syncthreads();
    }
    return;
  }

  if (bid >= 1028) {
    int idx = (bid - 1028) * 512 + tid;
    if (idx < B_ * N_) {
      float x = mu[(size_t)idx * 3 + 0];
      float y = mu[(size_t)idx * 3 + 1];
      float z = mu[(size_t)idx * 3 + 2];
      const float* S = Sigma + (size_t)idx * 9;
      float* e = ext + (size_t)idx * 16;
      e[0] = x; e[1] = y; e[2] = z;
      e[3] = x * x; e[4] = x * y; e[5] = x * z;
      e[6] = y * y; e[7] = y * z; e[8] = z * z;
      e[9] = S[0]; e[10] = S[1]; e[11] = S[2]; e[12] = S[4]; e[13] = S[5]; e[14] = S[8];
      e[15] = 1.f;
    }
    return;
  }

  if (bid >= 4) {
    const int gb = bid - 4;
    const int b = gb >> 8;
    const int n0 = (gb & 255) * 32;
    const int nt = tid >> 6;
    const int kt = tid & 63;
    {
      const float* sb = s + ((size_t)(b * N_ + n0)) * C_;
      int r = tid >> 4;
      int cb = (tid & 15) * 8;
#pragma unroll
      for (int q = 0; q < 2; q++) {
        float4 v = *(const float4*)(sb + (size_t)r * C_ + cb + q * 4);
        *(float4*)(&s_lds[r][cb + q * 4]) = v;
      }
    }
    float acc[4][12];
#pragma unroll
    for (int i = 0; i < 4; i++)
#pragma unroll
      for (int j = 0; j < 12; j++) acc[i][j] = 0.f;

    for (int cc = 0; cc < 16; cc++) {
      __syncthreads();
#pragma unroll
      for (int q = 0; q < 3; q++) {
        int fid = q * 512 + tid;
        int cl = fid / 192;
        int o4 = fid % 192;
        *(float4*)(&et_lds[cl][o4 * 4]) = *(const float4*)(ET + (size_t)(cc * 8 + cl) * KP_ + o4 * 4);
      }
      __syncthreads();
#pragma unroll
      for (int c8 = 0; c8 < 8; c8++) {
        int c = cc * 8 + c8;
        float sv0 = s_lds[nt * 4 + 0][c];
        float sv1 = s_lds[nt * 4 + 1][c];
        float sv2 = s_lds[nt * 4 + 2][c];
        float sv3 = s_lds[nt * 4 + 3][c];
#pragma unroll
        for (int j = 0; j < 12; j++) {
          float ev = et_lds[c8][kt + 64 * j];
          acc[0][j] = fmaf(sv0, ev, acc[0][j]);
          acc[1][j] = fmaf(sv1, ev, acc[1][j]);
          acc[2][j] = fmaf(sv2, ev, acc[2][j]);
          acc[3][j] = fmaf(sv3, ev, acc[3][j]);
        }
      }
    }
#pragma unroll
    for (int i = 0; i < 4; i++) {
      float* Arow = A + ((size_t)(b * N_ + n0 + nt * 4 + i)) * K_;
#pragma unroll
      for (int j = 0; j < 12; j++) {
        int k = kt + 64 * j;
        if (k < K_) Arow[k] = acc[i][j];
      }
    }
    return;
  }

  // ---------------- FPS (R7 structure, verbatim) ----------------
  const int b = bid;
  const int t = tid;
  const int wv = t >> 6;
  const float* mub = mu + (size_t)b * N_ * 3;
  const float* mkb = mask + (size_t)b * N_;
  float px[16], py[16], pz[16], md[16];

  double sx = 0, sy = 0, sz = 0, sc = 0;
#pragma unroll
  for (int i = 0; i < 16; i++) {
    int p = i * 512 + t;
    px[i] = mub[p * 3 + 0];
    py[i] = mub[p * 3 + 1];
    pz[i] = mub[p * 3 + 2];
    muL[p * 3 + 0] = px[i];
    muL[p * 3 + 1] = py[i];
    muL[p * 3 + 2] = pz[i];
    float mk = mkb[p];
    bool valid = (mk > 0.5f);
    md[i] = valid ? 3.4e38f : -1.f;
    if (valid) { sx += px[i]; sy += py[i]; sz += pz[i]; sc += 1.0; }
  }
  for (int off = 32; off; off >>= 1) {
    sx += __shfl_xor(sx, off);
    sy += __shfl_xor(sy, off);
    sz += __shfl_xor(sz, off);
    sc += __shfl_xor(sc, off);
  }
  if ((t & 63) == 0) { redd[wv][0] = sx; redd[wv][1] = sy; redd[wv][2] = sz; redd[wv][3] = sc; }
  __syncthreads();
  if (t == 0) {
    double ax0 = 0, ay0 = 0, az0 = 0, ac = 0;
    for (int w = 0; w < 8; w++) { ax0 += redd[w][0]; ay0 += redd[w][1]; az0 += redd[w][2]; ac += redd[w][3]; }
    if (ac < 1.0) ac = 1.0;
    an_s[0] = (float)(ax0 / ac); an_s[1] = (float)(ay0 / ac); an_s[2] = (float)(az0 / ac);
  }
  __syncthreads();

  float ax, ay, az;
  {
    float cx = an_s[0], cy = an_s[1], cz = an_s[2];
    float bv = -2.f, bv2 = -2.f;
    int bi = 0, bi2 = 0;
#pragma unroll
    for (int i = 0; i < 16; i++) {
      float dx = px[i] - cx, dy = py[i] - cy, dz = pz[i] - cz;
      float d2 = __fadd_rn(__fadd_rn(__fmul_rn(dx, dx), __fmul_rn(dy, dy)), __fmul_rn(dz, dz));
      float v = (md[i] < 0.f) ? -1.f : d2;
      int p = i * 512 + t;
      if (i & 1) { if (v > bv2) { bv2 = v; bi2 = p; } }
      else       { if (v > bv)  { bv = v;  bi = p; } }
    }
    if (bv2 > bv || (bv2 == bv && bi2 < bi)) { bv = bv2; bi = bi2; }
    unsigned long long k0 = ((unsigned long long)f2ord(bv) << 32) | (unsigned int)(~bi);
    for (int off = 32; off; off >>= 1) {
      unsigned long long ok = __shfl_xor(k0, off);
      if (ok > k0) k0 = ok;
    }
    if ((t & 63) == 0) redk[0][wv] = k0;
    __syncthreads();
    unsigned long long a0 = redk[0][0], a1 = redk[0][1], a2 = redk[0][2], a3 = redk[0][3];
    unsigned long long a4 = redk[0][4], a5 = redk[0][5], a6 = redk[0][6], a7 = redk[0][7];
    unsigned long long bk = umax64(umax64(umax64(a0, a1), umax64(a2, a3)),
                                  umax64(umax64(a4, a5), umax64(a6, a7)));
    int besti = (int)(~(unsigned int)bk);
    ax = muL[besti * 3 + 0]; ay = muL[besti * 3 + 1]; az = muL[besti * 3 + 2];
    if (t == 0) {
      float aa = ax * ax + ay * ay + az * az;
      float4 st = {ax, ay, az, aa};
      *(float4*)(anchors + ((size_t)b * KP_ + 0) * 4) = st;
    }
  }

  for (int k = 1; k < K_; k++) {
    const int par = k & 1;
    float bv = -2.f, bv2 = -2.f;
    int bi = 0, bi2 = 0;
#pragma unroll
    for (int i = 0; i < 16; i++) {
      float dx = px[i] - ax, dy = py[i] - ay, dz = pz[i] - az;
      float d2 = __fadd_rn(__fadd_rn(__fmul_rn(dx, dx), __fmul_rn(dy, dy)), __fmul_rn(dz, dz));
      float m = fminf(md[i], d2);
      md[i] = m;
      int p = i * 512 + t;
      if (i & 1) { if (m > bv2) { bv2 = m; bi2 = p; } }
      else       { if (m > bv)  { bv = m;  bi = p; } }
    }
    if (bv2 > bv || (bv2 == bv && bi2 < bi)) { bv = bv2; bi = bi2; }
    unsigned long long kk = ((unsigned long long)f2ord(bv) << 32) | (unsigned int)(~bi);
    for (int off = 32; off; off >>= 1) {
      unsigned long long ok = __shfl_xor(kk, off);
      if (ok > kk) kk = ok;
    }
    if ((t & 63) == 0) redk[par][wv] = kk;
    __syncthreads();
    unsigned long long a0 = redk[par][0], a1 = redk[par][1], a2 = redk[par][2], a3 = redk[par][3];
    unsigned long long a4 = redk[par][4], a5 = redk[par][5], a6 = redk[par][6], a7 = redk[par][7];
    unsigned long long bk = umax64(umax64(umax64(a0, a1), umax64(a2, a3)),
                                  umax64(umax64(a4, a5), umax64(a6, a7)));
    int besti = (int)(~(unsigned int)bk);
    ax = muL[besti * 3 + 0]; ay = muL[besti * 3 + 1]; az = muL[besti * 3 + 2];
    if (t == 0) {
      float aa = ax * ax + ay * ay + az * az;
      float4 st = {ax, ay, az, aa};
      *(float4*)(anchors + ((size_t)b * KP_ + k) * 4) = st;
    }
  }
  for (int k = K_ + t; k < KP_; k += 512) {
    float4 z4 = {0.f, 0.f, 0.f, 0.f};
    *(float4*)(anchors + ((size_t)b * KP_ + k) * 4) = z4;
  }
}

// =====================================================================
// spatial logits + mask + softmax, in place over A (holds Lsem).
__global__ __launch_bounds__(256) void spatial_softmax_k(
    const float* __restrict__ mu, const float* __restrict__ mask,
    const float* __restrict__ anchors, const float* __restrict__ lsm_p,
    const float* __restrict__ wsem_p, const float* __restrict__ wmu_p,
    float* __restrict__ A) {
  const int bid = blockIdx.x;
  const int b = bid >> 11;
  const int n0 = (bid & 2047) * 4;
  const int tid = threadIdx.x;
  const int wv = tid >> 6;
  const int lane = tid & 63;
  __shared__ __align__(16) float anch_lds[KP_][4];
  for (int q = tid; q < KP_; q += 256)
    *(float4*)(&anch_lds[q][0]) = *(const float4*)(anchors + ((size_t)b * KP_ + q) * 4);
  __syncthreads();

  const float sg = fmaxf(expf(lsm_p[0]), 1e-4f);
  const float inv2s2 = 0.5f / (sg * sg);
  const float wsem = wsem_p[0];
  const float wmu = wmu_p[0];

  const size_t gr = (size_t)b * N_ + n0 + wv;
  const float* mp = mu + gr * 3;
  float x = mp[0], y = mp[1], z = mp[2];
  float mq = x * x + y * y + z * z;
  float mk = mask[gr];
  float* Arow = A + gr * K_;

  float v[11];
  float m = -3e38f;
#pragma unroll
  for (int j = 0; j < 11; j++) {
    int k = lane + 64 * j;
    if (k < K_) {
      float lsem = Arow[k];
      float4 a4 = *(const float4*)(&anch_lds[k][0]);
      float tdot = x * a4.x + y * a4.y + z * a4.z;
      float d2 = mq - 2.f * tdot + a4.w;
      float l = wsem * lsem - wmu * d2 * inv2s2;
      if (mk < 0.5f) l = -1e9f;
      v[j] = l;
    } else v[j] = -1e30f;
    m = fmaxf(m, v[j]);
  }
  for (int off = 32; off; off >>= 1) m = fmaxf(m, __shfl_xor(m, off));
  float sum = 0.f;
#pragma unroll
  for (int j = 0; j < 11; j++) { float e = expf(v[j] - m); v[j] = e; sum += e; }
  for (int off = 32; off; off >>= 1) sum += __shfl_xor(sum, off);
  float r = mk / sum;
#pragma unroll
  for (int j = 0; j < 11; j++) {
    int k = lane + 64 * j;
    if (k < K_) Arow[k] = v[j] * r;
  }
}

// =====================================================================
// Transpose A fp32 [b][n][683] -> At bf16 [b][768][8192] (pad rows zero)
__global__ __launch_bounds__(256) void transpose_at_k(const float* __restrict__ A,
    unsigned short* __restrict__ At) {
  const int bid = blockIdx.x;          // b(4) * ktile(12) * ntile(128)
  const int ntile = bid % 128;
  const int rem = bid / 128;
  const int kt = rem % 12;
  const int b = rem / 12;
  const int k0 = kt * 64, n0 = ntile * 64;
  const int tid = threadIdx.x;
  __shared__ __align__(16) unsigned short T[64][72];

  {
    const int n_loc = tid >> 4;        // 0..15
    const int k4 = (tid & 15) * 4;
#pragma unroll
    for (int nn = 0; nn < 4; nn++) {
      int n = n_loc + 16 * nn;
      const float* ar = A + ((size_t)(b * N_ + n0 + n)) * K_;
#pragma unroll
      for (int q = 0; q < 4; q++) {
        int kk = k0 + k4 + q;
        float f = (kk < K_) ? ar[kk] : 0.f;
        T[k4 + q][n] = f2bf_rne(f);
      }
    }
  }
  __syncthreads();
  {
    const int k_loc = tid >> 2;        // 0..63
    const int c = tid & 3;             // 16-ushort chunk
    uint4 v0 = *(const uint4*)(&T[k_loc][c * 16]);
    uint4 v1 = *(const uint4*)(&T[k_loc][c * 16 + 8]);
    unsigned short* dst = At + ((size_t)(b * KP_ + k0 + k_loc)) * N_ + n0 + c * 16;
    *(uint4*)dst = v0;
    *(uint4*)(dst + 8) = v1;
  }
}

// =====================================================================
// MFMA s-moments: mpart[np][b][k][c] = sum_n At[k][n] * sT[c][n]
// 48 blocks = np(2) x b(4) x ktile(6); per block n-range 4096.
__global__ __launch_bounds__(256) void gemm2_mfma_k(const unsigned short* __restrict__ At,
    const unsigned short* __restrict__ sT, float* __restrict__ mpart) {
  const int bid = blockIdx.x;
  const int np = bid / 24;
  const int rem = bid % 24;
  const int b = rem / 6;
  const int kt2 = rem % 6;
  const int k0 = kt2 * 128;
  const int tid = threadIdx.x;
  const int l = tid & 63;
  const int w = tid >> 6;
  const int wr = w >> 1, wc = w & 1;

  __shared__ __align__(16) unsigned short Ak_lds[128 * 72];
  __shared__ __align__(16) unsigned short Bc_lds[128 * 72];

  f32x4 acc[4][4];
#pragma unroll
  for (int i = 0; i < 4; i++)
#pragma unroll
    for (int j = 0; j < 4; j++) acc[i][j] = (f32x4){0.f, 0.f, 0.f, 0.f};

  const unsigned short* gk = At + ((size_t)(b * KP_ + k0)) * N_;
  const unsigned short* gc = sT + ((size_t)(b * C_)) * N_;
  const int nbase = np * 4096;

  for (int ch = 0; ch < 64; ch++) {
    const int n0 = nbase + ch * 64;
    __syncthreads();
#pragma unroll
    for (int q = 0; q < 4; q++) {
      int chunk = tid + 256 * q;
      int row = chunk >> 3, slot = chunk & 7;
      uint4 v = *(const uint4*)(gk + (size_t)row * N_ + n0 + slot * 8);
      *(uint4*)(Ak_lds + row * 72 + slot * 8) = v;
      uint4 v2 = *(const uint4*)(gc + (size_t)row * N_ + n0 + slot * 8);
      *(uint4*)(Bc_lds + row * 72 + slot * 8) = v2;
    }
    __syncthreads();
#pragma unroll
    for (int ks = 0; ks < 2; ks++) {
      const int noff = (l >> 4) * 8 + ks * 32;
      bf16x8s af[4], bfr[4];
#pragma unroll
      for (int f = 0; f < 4; f++) {
        af[f]  = *(const bf16x8s*)(Ak_lds + (wr * 64 + f * 16 + (l & 15)) * 72 + noff);
        bfr[f] = *(const bf16x8s*)(Bc_lds + (wc * 64 + f * 16 + (l & 15)) * 72 + noff);
      }
#pragma unroll
      for (int i = 0; i < 4; i++)
#pragma unroll
        for (int j = 0; j < 4; j++)
          acc[i][j] = __builtin_amdgcn_mfma_f32_16x16x32_bf16(af[i], bfr[j], acc[i][j], 0, 0, 0);
    }
  }
  float* mp = mpart + ((size_t)((np * 4 + b) * KP_ + k0)) * C_;
#pragma unroll
  for (int i = 0; i < 4; i++) {
#pragma unroll
    for (int j = 0; j < 4; j++) {
#pragma unroll
      for (int r = 0; r < 4; r++) {
        int ki = wr * 64 + i * 16 + (l >> 4) * 4 + r;
        int ci = wc * 64 + j * 16 + (l & 15);
        mp[(size_t)ki * C_ + ci] = acc[i][j][r];
      }
    }
  }
}

// =====================================================================
// fp32 ext moments (16 features, magnitudes up to mu^2) + sum(A^2).
// epart[np][b][k][32]: slots 0..15 ext moments, 16 = asq.
__global__ __launch_bounds__(256) void gemm2_ext_k(const float* __restrict__ A,
    const float* __restrict__ ext, float* __restrict__ epart) {
  const int bid = blockIdx.x;
  const int np = bid / 44;
  const int rem = bid % 44;
  const int b = rem / 11;
  const int k0 = (rem % 11) * 64;
  const int n0 = np * 1024;
  const int tid = threadIdx.x;
  const int kt = tid & 15;
  const int ft = tid >> 4;
  __shared__ __align__(16) float A_lds[32][64];
  __shared__ __align__(16) float F_lds[32][32];
  float acc[4][2];
#pragma unroll
  for (int c = 0; c < 4; c++) { acc[c][0] = 0.f; acc[c][1] = 0.f; }
  float asq[4] = {0.f, 0.f, 0.f, 0.f};

  for (int ch = 0; ch < 32; ch++) {
    int nb = n0 + ch * 32;
    __syncthreads();
#pragma unroll
    for (int p = 0; p < 8; p++) {
      int q = tid + 256 * p; int r = q >> 6; int c = q & 63; int k = k0 + c;
      A_lds[r][c] = (k < K_) ? A[((size_t)(b * N_ + nb + r)) * K_ + k] : 0.f;
    }
#pragma unroll
    for (int p = 0; p < 2; p++) {
      int q = tid + 256 * p; int r = q >> 4; int e = q & 15;
      F_lds[r][e] = ext[((size_t)(b * N_ + nb + r)) * 16 + e];
      F_lds[r][16 + e] = 0.f;
    }
    __syncthreads();
#pragma unroll
    for (int i = 0; i < 32; i++) {
      float a0 = A_lds[i][kt * 4 + 0];
      float a1 = A_lds[i][kt * 4 + 1];
      float a2 = A_lds[i][kt * 4 + 2];
      float a3 = A_lds[i][kt * 4 + 3];
      if (ft == 0) {
        asq[0] = fmaf(a0, a0, asq[0]); asq[1] = fmaf(a1, a1, asq[1]);
        asq[2] = fmaf(a2, a2, asq[2]); asq[3] = fmaf(a3, a3, asq[3]);
      }
#pragma unroll
      for (int f = 0; f < 2; f++) {
        float fv = F_lds[i][ft * 2 + f];
        acc[0][f] = fmaf(a0, fv, acc[0][f]);
        acc[1][f] = fmaf(a1, fv, acc[1][f]);
        acc[2][f] = fmaf(a2, fv, acc[2][f]);
        acc[3][f] = fmaf(a3, fv, acc[3][f]);
      }
    }
  }
#pragma unroll
  for (int c = 0; c < 4; c++) {
    size_t base = ((size_t)((np * 4 + b) * KT_ + k0 + kt * 4 + c)) * 32;
#pragma unroll
    for (int f = 0; f < 2; f++) {
      int fidx = ft * 2 + f;
      if (fidx < 16) epart[base + fidx] = acc[c][f];
    }
    if (ft == 0) epart[base + 16] = asq[c];
  }
}

// =====================================================================
// Postprocess (MFMA path): one wave per (b,k).
__global__ __launch_bounds__(256) void postproc2_k(const float* __restrict__ mpart,
    const float* __restrict__ epart, float* __restrict__ out,
    float* __restrict__ sumA_ws, float* __restrict__ norm_ws) {
  const int gw = blockIdx.x * 4 + (threadIdx.x >> 6);
  const int lane = threadIdx.x & 63;
  const int b = gw / K_;
  const int k = gw % K_;
  float v0 = 0.f, v1 = 0.f, v2 = 0.f, v3 = 0.f;
#pragma unroll
  for (int np = 0; np < 2; np++) {
    const float* r = mpart + ((size_t)((np * 4 + b) * KP_ + k)) * C_;
    v0 += r[lane];
    v1 += r[64 + lane];
  }
#pragma unroll
  for (int np = 0; np < 8; np++) {
    const float* e = epart + ((size_t)((np * 4 + b) * KT_ + k)) * 32;
    if (lane < 16) v2 += e[lane];
    if (lane == 0) v3 += e[16];
  }
  float sumA = __shfl(v2, 15);
  float asq = __shfl(v3, 0);
  float denom = fmaxf(sumA, 1e-8f);
  float inv = 1.f / denom;
  out[OUT_SC + ((size_t)(b * K_ + k)) * C_ + lane] = v0 * inv;
  out[OUT_SC + ((size_t)(b * K_ + k)) * C_ + 64 + lane] = v1 * inv;
  float m0 = __shfl(v2, 0) * inv;
  float m1 = __shfl(v2, 1) * inv;
  float m2 = __shfl(v2, 2) * inv;
  if (lane < 3) out[OUT_MUC + ((size_t)(b * K_ + k)) * 3 + lane] = (lane == 0) ? m0 : ((lane == 1) ? m1 : m2);
  float W = sumA * inv;
  float fac = 2.f - W;
  float M2s[6], Sgs[6];
#pragma unroll
  for (int j = 0; j < 6; j++) { M2s[j] = __shfl(v2, 3 + j); Sgs[j] = __shfl(v2, 9 + j); }
  if (lane < 9) {
    int d = lane / 3, e = lane % 3;
    int lo = min(d, e), hi = max(d, e);
    int j = hi + 2 * lo - ((lo * (lo - 1)) >> 1);
    float mud = (d == 0) ? m0 : ((d == 1) ? m1 : m2);
    float mue = (e == 0) ? m0 : ((e == 1) ? m1 : m2);
    float M2j = (j == 0) ? M2s[0] : (j == 1) ? M2s[1] : (j == 2) ? M2s[2] : (j == 3) ? M2s[3] : (j == 4) ? M2s[4] : M2s[5];
    float Sgj = (j == 0) ? Sgs[0] : (j == 1) ? Sgs[1] : (j == 2) ? Sgs[2] : (j == 3) ? Sgs[3] : (j == 4) ? Sgs[4] : Sgs[5];
    float val = (Sgj + M2j) * inv - mud * mue * fac;
    if (d == e) val += 1e-6f;
    out[OUT_SGC + ((size_t)(b * K_ + k)) * 9 + lane] = val;
  }
  if (lane == 0) { sumA_ws[b * KT_ + k] = sumA; norm_ws[b * KT_ + k] = sqrtf(asq); }
}

// =====================================================================
// MFMA gram + fused collapse-loss tile partial (84 blocks).
__global__ __launch_bounds__(256) void gram_mfma_k(const unsigned short* __restrict__ At,
    const float* __restrict__ norm_ws, float* __restrict__ lossp) {
  const int bid = blockIdx.x;
  const int b = bid / 21;
  int p = bid % 21;
  int tk = 0, tl = 0;
  { int pp = p; for (int r0 = 0; r0 < 6; r0++) { int cnt = 6 - r0; if (pp < cnt) { tk = r0; tl = r0 + pp; break; } pp -= cnt; } }
  const int k0 = tk * 128, l0 = tl * 128;
  const int tid = threadIdx.x;
  const int l = tid & 63;
  const int w = tid >> 6;
  const int wr = w >> 1, wc = w & 1;

  __shared__ __align__(16) unsigned short Ak_lds[128 * 72];
  __shared__ __align__(16) unsigned short Al_lds[128 * 72];
  __shared__ float nk_s[128], nl_s[128], red_s[4];

  if (tid < 128) {
    int kk = k0 + tid;
    nk_s[tid] = (kk < K_) ? fmaxf(norm_ws[b * KT_ + kk], 1e-8f) : 1.f;
  } else {
    int ll2 = l0 + tid - 128;
    nl_s[tid - 128] = (ll2 < K_) ? fmaxf(norm_ws[b * KT_ + ll2], 1e-8f) : 1.f;
  }

  f32x4 acc[4][4];
#pragma unroll
  for (int i = 0; i < 4; i++)
#pragma unroll
    for (int j = 0; j < 4; j++) acc[i][j] = (f32x4){0.f, 0.f, 0.f, 0.f};

  const unsigned short* gk = At + ((size_t)(b * KP_ + k0)) * N_;
  const unsigned short* gl = At + ((size_t)(b * KP_ + l0)) * N_;

  for (int ch = 0; ch < 128; ch++) {
    const int n0 = ch * 64;
    __syncthreads();
#pragma unroll
    for (int q = 0; q < 4; q++) {
      int chunk = tid + 256 * q;
      int row = chunk >> 3, slot = chunk & 7;
      uint4 v = *(const uint4*)(gk + (size_t)row * N_ + n0 + slot * 8);
      *(uint4*)(Ak_lds + row * 72 + slot * 8) = v;
      uint4 v2 = *(const uint4*)(gl + (size_t)row * N_ + n0 + slot * 8);
      *(uint4*)(Al_lds + row * 72 + slot * 8) = v2;
    }
    __syncthreads();
#pragma unroll
    for (int ks = 0; ks < 2; ks++) {
      const int noff = (l >> 4) * 8 + ks * 32;
      bf16x8s af[4], bfr[4];
#pragma unroll
      for (int f = 0; f < 4; f++) {
        af[f]  = *(const bf16x8s*)(Ak_lds + (wr * 64 + f * 16 + (l & 15)) * 72 + noff);
        bfr[f] = *(const bf16x8s*)(Al_lds + (wc * 64 + f * 16 + (l & 15)) * 72 + noff);
      }
#pragma unroll
      for (int i = 0; i < 4; i++)
#pragma unroll
        for (int j = 0; j < 4; j++)
          acc[i][j] = __builtin_amdgcn_mfma_f32_16x16x32_bf16(af[i], bfr[j], acc[i][j], 0, 0, 0);
    }
  }

  float local = 0.f;
  const float wgt = (tk == tl) ? 1.f : 2.f;
#pragma unroll
  for (int i = 0; i < 4; i++) {
#pragma unroll
    for (int j = 0; j < 4; j++) {
#pragma unroll
      for (int r = 0; r < 4; r++) {
        int ki = wr * 64 + i * 16 + (l >> 4) * 4 + r;
        int li = wc * 64 + j * 16 + (l & 15);
        int gkk = k0 + ki, gll = l0 + li;
        if (gkk < K_ && gll < K_ && gkk != gll) {
          float g = acc[i][j][r];
          float x = g / (nk_s[ki] * nl_s[li]);
          local = fmaf(wgt * x, x, local);
        }
      }
    }
  }
  for (int off = 32; off; off >>= 1) local += __shfl_xor(local, off);
  if ((tid & 63) == 0) red_s[w] = local;
  __syncthreads();
  if (tid == 0) lossp[bid] = red_s[0] + red_s[1] + red_s[2] + red_s[3];
}

// final for the MFMA path: 84 tile partials
__global__ __launch_bounds__(256) void final2_k(const float* __restrict__ sumA_ws,
    const float* __restrict__ lossp, float* __restrict__ out) {
  const int lane = threadIdx.x & 63;
  const int wv = threadIdx.x >> 6;
  __shared__ float occ_s[4];
  __shared__ float col_s[4];
  float sb = 0.f;
  for (int k = lane; k < K_; k += 64) sb += sumA_ws[wv * KT_ + k];
  for (int off = 32; off; off >>= 1) sb += __shfl_xor(sb, off);
  float Sb = fmaxf(sb, 1e-8f);
  float lo = 0.f;
  const float tgt = 1.f / (float)K_;
  for (int k = lane; k < K_; k += 64) {
    float o = sumA_ws[wv * KT_ + k] / Sb - tgt;
    lo = fmaf(o, o, lo);
  }
  for (int off = 32; off; off >>= 1) lo += __shfl_xor(lo, off);
  if (lane == 0) occ_s[wv] = lo;
  float c = 0.f;
  for (int i = threadIdx.x; i < 84; i += 256) c += lossp[i];
  for (int off = 32; off; off >>= 1) c += __shfl_xor(c, off);
  if (lane == 0) col_s[wv] = c;
  __syncthreads();
  if (threadIdx.x == 0) {
    float loss_occ = (occ_s[0] + occ_s[1] + occ_s[2] + occ_s[3]) / (float)(B_ * K_);
    float coll = (col_s[0] + col_s[1] + col_s[2] + col_s[3]) / ((float)B_ * K_ * K_);
    out[OUT_TOT] = loss_occ + 0.1f * coll;
  }
}

// =====================================================================
// ---- OLD fp32 fallback path (only if ws too small; uses OLD_ offsets) ----
__global__ __launch_bounds__(256) void gemm2_k(const float* __restrict__ A,
    const float* __restrict__ s, const float* __restrict__ ext,
    float* __restrict__ part) {
  const int bid = blockIdx.x;
  const int np = bid / 44;
  const int rem = bid % 44;
  const int b = rem / 11;
  const int k0 = (rem % 11) * 64;
  const int n0 = np * 1024;
  const int tid = threadIdx.x;
  const int kt = tid & 15;
  const int ft = tid >> 4;
  __shared__ __align__(16) float A_lds[32][64];
  __shared__ __align__(16) float F_lds[32][160];
  float acc[4][10];
#pragma unroll
  for (int c = 0; c < 4; c++)
#pragma unroll
    for (int f = 0; f < 10; f++) acc[c][f] = 0.f;
  float asq[4] = {0.f, 0.f, 0.f, 0.f};
  for (int ch = 0; ch < 32; ch++) {
    int nb = n0 + ch * 32;
    __syncthreads();
#pragma unroll
    for (int p = 0; p < 8; p++) {
      int q = tid + 256 * p; int r = q >> 6; int c = q & 63; int k = k0 + c;
      A_lds[r][c] = (k < K_) ? A[((size_t)(b * N_ + nb + r)) * K_ + k] : 0.f;
    }
#pragma unroll
    for (int p = 0; p < 16; p++) {
      int q = tid + 256 * p; int r = q >> 7; int c = q & 127;
      F_lds[r][c] = s[((size_t)(b * N_ + nb + r)) * C_ + c];
    }
#pragma unroll
    for (int p = 0; p < 2; p++) {
      int q = tid + 256 * p; int r = q >> 4; int e = q & 15;
      F_lds[r][128 + e] = ext[((size_t)(b * N_ + nb + r)) * 16 + e];
      F_lds[r][144 + e] = 0.f;
    }
    __syncthreads();
#pragma unroll
    for (int i = 0; i < 32; i++) {
      float a0 = A_lds[i][kt * 4 + 0];
      float a1 = A_lds[i][kt * 4 + 1];
      float a2 = A_lds[i][kt * 4 + 2];
      float a3 = A_lds[i][kt * 4 + 3];
      if (ft == 0) {
        asq[0] = fmaf(a0, a0, asq[0]); asq[1] = fmaf(a1, a1, asq[1]);
        asq[2] = fmaf(a2, a2, asq[2]); asq[3] = fmaf(a3, a3, asq[3]);
      }
#pragma unroll
      for (int f = 0; f < 10; f++) {
        float fv = F_lds[i][ft * 10 + f];
        acc[0][f] = fmaf(a0, fv, acc[0][f]);
        acc[1][f] = fmaf(a1, fv, acc[1][f]);
        acc[2][f] = fmaf(a2, fv, acc[2][f]);
        acc[3][f] = fmaf(a3, fv, acc[3][f]);
      }
    }
  }
#pragma unroll
  for (int c = 0; c < 4; c++) {
    size_t base = ((size_t)((np * 4 + b) * KT_ + k0 + kt * 4 + c)) * 168;
#pragma unroll
    for (int f = 0; f < 10; f++) part[base + ft * 10 + f] = acc[c][f];
    if (ft == 0) part[base + 160] = asq[c];
  }
}

__global__ __launch_bounds__(256) void postproc_k(const float* __restrict__ part,
    float* __restrict__ out, float* __restrict__ sumA_ws, float* __restrict__ norm_ws) {
  const int gw = blockIdx.x * 4 + (threadIdx.x >> 6);
  const int lane = threadIdx.x & 63;
  const int b = gw / K_;
  const int k = gw % K_;
  float v0 = 0.f, v1 = 0.f, v2 = 0.f, v3 = 0.f;
  for (int np = 0; np < 8; np++) {
    const float* r = part + ((size_t)((np * 4 + b) * KT_ + k)) * 168;
    v0 += r[lane];
    v1 += r[64 + lane];
    if (lane < 16) v2 += r[128 + lane];
    if (lane == 0) v3 += r[160];
  }
  float sumA = __shfl(v2, 15);
  float asq = __shfl(v3, 0);
  float denom = fmaxf(sumA, 1e-8f);
  float inv = 1.f / denom;
  out[OUT_SC + ((size_t)(b * K_ + k)) * C_ + lane] = v0 * inv;
  out[OUT_SC + ((size_t)(b * K_ + k)) * C_ + 64 + lane] = v1 * inv;
  float m0 = __shfl(v2, 0) * inv;
  float m1 = __shfl(v2, 1) * inv;
  float m2 = __shfl(v2, 2) * inv;
  if (lane < 3) out[OUT_MUC + ((size_t)(b * K_ + k)) * 3 + lane] = (lane == 0) ? m0 : ((lane == 1) ? m1 : m2);
  float W = sumA * inv;
  float fac = 2.f - W;
  float M2s[6], Sgs[6];
#pragma unroll
  for (int j = 0; j < 6; j++) { M2s[j] = __shfl(v2, 3 + j); Sgs[j] = __shfl(v2, 9 + j); }
  if (lane < 9) {
    int d = lane / 3, e = lane % 3;
    int lo = min(d, e), hi = max(d, e);
    int j = hi + 2 * lo - ((lo * (lo - 1)) >> 1);
    float mud = (d == 0) ? m0 : ((d == 1) ? m1 : m2);
    float mue = (e == 0) ? m0 : ((e == 1) ? m1 : m2);
    float M2j = (j == 0) ? M2s[0] : (j == 1) ? M2s[1] : (j == 2) ? M2s[2] : (j == 3) ? M2s[3] : (j == 4) ? M2s[4] : M2s[5];
    float Sgj = (j == 0) ? Sgs[0] : (j == 1) ? Sgs[1] : (j == 2) ? Sgs[2] : (j == 3) ? Sgs[3] : (j == 4) ? Sgs[4] : Sgs[5];
    float val = (Sgj + M2j) * inv - mud * mue * fac;
    if (d == e) val += 1e-6f;
    out[OUT_SGC + ((size_t)(b * K_ + k)) * 9 + lane] = val;
  }
  if (lane == 0) { sumA_ws[b * KT_ + k] = sumA; norm_ws[b * KT_ + k] = sqrtf(asq); }
}

__device__ __forceinline__ int swz(int f) { return f ^ (((f >> 5) & 3) << 3); }

__global__ __launch_bounds__(256) void gram_k(const float* __restrict__ A,
                                              float* __restrict__ Gpart) {
  const int bid = blockIdx.x;
  const int np = bid & 1;
  int q = bid >> 1;
  const int b = q / 21;
  int p = q % 21;
  int tk = 0, tl = 0;
  { int pp = p; for (int r0 = 0; r0 < 6; r0++) { int cnt = 6 - r0; if (pp < cnt) { tk = r0; tl = r0 + pp; break; } pp -= cnt; } }
  const int k0 = tk * 128, l0 = tl * 128;
  const int n0 = np * 4096;
  const int tid = threadIdx.x;
  const int ktid = tid & 15, ltid = tid >> 4;
  const bool diag = (tk == tl);
  __shared__ __align__(16) float Ak[32][128];
  __shared__ __align__(16) float Al[32][128];
  float acc[8][8];
#pragma unroll
  for (int i = 0; i < 8; i++)
#pragma unroll
    for (int j = 0; j < 8; j++) acc[i][j] = 0.f;
  const int kb = swz(ktid * 8);
  const int lb = swz(ltid * 8);
  for (int ch = 0; ch < 128; ch++) {
    int nb = n0 + ch * 32;
    __syncthreads();
#pragma unroll
    for (int pq = 0; pq < 16; pq++) {
      int qq = tid + 256 * pq; int r = qq >> 7; int c = qq & 127;
      int kk = k0 + c;
      Ak[r][swz(c)] = (kk < K_) ? A[((size_t)(b * N_ + nb + r)) * K_ + kk] : 0.f;
      if (!diag) {
        int ll = l0 + c;
        Al[r][swz(c)] = (ll < K_) ? A[((size_t)(b * N_ + nb + r)) * K_ + ll] : 0.f;
      }
    }
    __syncthreads();
    const float (*Alp)[128] = diag ? Ak : Al;
#pragma unroll
    for (int i = 0; i < 32; i++) {
      float4 ka = *(const float4*)(&Ak[i][kb]);
      float4 kb4 = *(const float4*)(&Ak[i][kb + 4]);
      float4 la = *(const float4*)(&Alp[i][lb]);
      float4 lb4 = *(const float4*)(&Alp[i][lb + 4]);
      float av[8] = {ka.x, ka.y, ka.z, ka.w, kb4.x, kb4.y, kb4.z, kb4.w};
      float lv[8] = {la.x, la.y, la.z, la.w, lb4.x, lb4.y, lb4.z, lb4.w};
#pragma unroll
      for (int ii = 0; ii < 8; ii++)
#pragma unroll
        for (int jj = 0; jj < 8; jj++)
          acc[ii][jj] = fmaf(av[ii], lv[jj], acc[ii][jj]);
    }
  }
#pragma unroll
  for (int ii = 0; ii < 8; ii++) {
    int kk = k0 + ktid * 8 + ii;
    float* gp = Gpart + ((size_t)((np * 4 + b) * KP_ + kk)) * KP_ + l0 + ltid * 8;
#pragma unroll
    for (int jj = 0; jj < 8; jj++) gp[jj] = acc[ii][jj];
  }
}

__global__ __launch_bounds__(256) void loss_part_k(const float* __restrict__ Gpart,
    const float* __restrict__ norm_ws, float* __restrict__ lossp) {
  const long long total = (long long)B_ * 21 * 16384;
  float local = 0.f;
  for (long long idx = (long long)blockIdx.x * 256 + threadIdx.x; idx < total; idx += (long long)512 * 256) {
    int e = (int)(idx & 16383);
    int rest = (int)(idx >> 14);
    int p = rest % 21;
    int b = rest / 21;
    int tk = 0, tl = 0;
    { int pp = p; for (int r0 = 0; r0 < 6; r0++) { int cnt = 6 - r0; if (pp < cnt) { tk = r0; tl = r0 + pp; break; } pp -= cnt; } }
    int i = e >> 7, j = e & 127;
    int k = tk * 128 + i, l = tl * 128 + j;
    if (k < K_ && l < K_ && k != l) {
      size_t i0 = ((size_t)((0 * 4 + b) * KP_ + k)) * KP_ + l;
      size_t i1 = ((size_t)((1 * 4 + b) * KP_ + k)) * KP_ + l;
      float g = Gpart[i0] + Gpart[i1];
      float nk = fmaxf(norm_ws[b * KT_ + k], 1e-8f);
      float nl2 = fmaxf(norm_ws[b * KT_ + l], 1e-8f);
      float x = g / (nk * nl2);
      float wgt = (tk == tl) ? 1.f : 2.f;
      local = fmaf(wgt * x, x, local);
    }
  }
  __shared__ float red[4];
  for (int off = 32; off; off >>= 1) local += __shfl_xor(local, off);
  if ((threadIdx.x & 63) == 0) red[threadIdx.x >> 6] = local;
  __syncthreads();
  if (threadIdx.x == 0) lossp[blockIdx.x] = red[0] + red[1] + red[2] + red[3];
}

__global__ __launch_bounds__(256) void final_k(const float* __restrict__ sumA_ws,
    const float* __restrict__ lossp, float* __restrict__ out) {
  const int lane = threadIdx.x & 63;
  const int wv = threadIdx.x >> 6;
  __shared__ float occ_s[4];
  __shared__ float col_s[4];
  float sb = 0.f;
  for (int k = lane; k < K_; k += 64) sb += sumA_ws[wv * KT_ + k];
  for (int off = 32; off; off >>= 1) sb += __shfl_xor(sb, off);
  float Sb = fmaxf(sb, 1e-8f);
  float lo = 0.f;
  const float tgt = 1.f / (float)K_;
  for (int k = lane; k < K_; k += 64) {
    float o = sumA_ws[wv * KT_ + k] / Sb - tgt;
    lo = fmaf(o, o, lo);
  }
  for (int off = 32; off; off >>= 1) lo += __shfl_xor(lo, off);
  if (lane == 0) occ_s[wv] = lo;
  float c = lossp[threadIdx.x] + lossp[threadIdx.x + 256];
  for (int off = 32; off; off >>= 1) c += __shfl_xor(c, off);
  if (lane == 0) col_s[wv] = c;
  __syncthreads();
  if (threadIdx.x == 0) {
    float loss_occ = (occ_s[0] + occ_s[1] + occ_s[2] + occ_s[3]) / (float)(B_ * K_);
    float coll = (col_s[0] + col_s[1] + col_s[2] + col_s[3]) / ((float)B_ * K_ * K_);
    out[OUT_TOT] = loss_occ + 0.1f * coll;
  }
}

// =====================================================================
extern "C" void kernel_launch(void* const* d_in, const int* in_sizes, int n_in,
                              void* d_out, int out_size, void* d_ws, size_t ws_size,
                              hipStream_t stream) {
  const float* s = (const float*)d_in[0];
  const float* mu = (const float*)d_in[1];
  const float* Sigma = (const float*)d_in[2];
  const float* mask = (const float*)d_in[3];
  const float* Wp = (const float*)d_in[4];
  const float* se = (const float*)d_in[5];
  const float* lsm = (const float*)d_in[6];
  const float* wsem = (const float*)d_in[7];
  const float* wmu = (const float*)d_in[8];
  float* out = (float*)d_out;
  float* ws = (float*)d_ws;

  float* ET = ws + WS_ET;
  float* anch = ws + WS_ANCH;
  float* ext = ws + WS_EXT;

  const bool use_mfma = ws_size >= (size_t)WS_NEW_END * 4;

  if (use_mfma) {
    float* epart = ws + WS_EPART;
    float* mpart = ws + WS_MPART;
    float* sumA = ws + WS_SUMA;
    float* nrm = ws + WS_NORM;
    float* lossp2 = ws + WS_LOSSP2;
    unsigned short* sT = (unsigned short*)(ws + WS_ST);
    unsigned short* At = (unsigned short*)(ws + WS_AT);

    hipLaunchKernelGGL(build_ET_k, dim3(384), dim3(256), 0, stream, Wp, se, ET);
    hipLaunchKernelGGL(fused_k, dim3(1348), dim3(512), 0, stream, s, mu, Sigma, mask, ET, anch, ext, out, sT);
    hipLaunchKernelGGL(spatial_softmax_k, dim3(8192), dim3(256), 0, stream, mu, mask, anch, lsm, wsem, wmu, out);
    hipLaunchKernelGGL(transpose_at_k, dim3(4 * 12 * 128), dim3(256), 0, stream, out, At);
    hipLaunchKernelGGL(gemm2_mfma_k, dim3(48), dim3(256), 0, stream, At, sT, mpart);
    hipLaunchKernelGGL(gemm2_ext_k, dim3(352), dim3(256), 0, stream, out, ext, epart);
    hipLaunchKernelGGL(postproc2_k, dim3(683), dim3(256), 0, stream, mpart, epart, out, sumA, nrm);
    hipLaunchKernelGGL(gram_mfma_k, dim3(84), dim3(256), 0, stream, At, nrm, lossp2);
    hipLaunchKernelGGL(final2_k, dim3(1), dim3(256), 0, stream, sumA, lossp2, out);
  } else {
    float* part = ws + OLD_PART;
    float* sumA = ws + OLD_SUMA;
    float* nrm = ws + OLD_NORM;
    float* Gpart = ws + OLD_GPART;
    float* lossp = ws + OLD_LOSSP;
    unsigned short* sT = (unsigned short*)(ws + WS_ST);  // scratch, overwritten later

    hipLaunchKernelGGL(build_ET_k, dim3(384), dim3(256), 0, stream, Wp, se, ET);
    hipLaunchKernelGGL(fused_k, dim3(1348), dim3(512), 0, stream, s, mu, Sigma, mask, ET, anch, ext, out, sT);
    hipLaunchKernelGGL(spatial_softmax_k, dim3(8192), dim3(256), 0, stream, mu, mask, anch, lsm, wsem, wmu, out);
    hipLaunchKernelGGL(gemm2_k, dim3(352), dim3(256), 0, stream, out, s, ext, part);
    hipLaunchKernelGGL(postproc_k, dim3(683), dim3(256), 0, stream, part, out, sumA, nrm);
    hipLaunchKernelGGL(gram_k, dim3(168), dim3(256), 0, stream, out, Gpart);
    hipLaunchKernelGGL(loss_part_k, dim3(512), dim3(256), 0, stream, Gpart, nrm, lossp);
    hipLaunchKernelGGL(final_k, dim3(1), dim3(256), 0, stream, sumA, lossp, out);
  }
}

// Round 10
// 1252.583 us; speedup vs baseline: 1.2569x; 1.0093x over previous
//
#include <hip/hip_runtime.h>
#include <hip/hip_bf16.h>
#include <math.h>

#define B_ 4
#define N_ 8192
#define C_ 128
#define K_ 683
#define KP_ 768
#define KT_ 704   // 11*64 padded K for ext moments

// ---- workspace layout, MFMA path (float offsets) ----
#define WS_ET      0          // 128*768            = 98304
#define WS_ANCH    98304      // 4*768*4            = 12288
#define WS_EXT     110592     // 4*8192*16          = 524288
#define WS_EPART   634880     // 8*4*704*32         = 720896
#define WS_MPART   1355776    // 2*4*768*128        = 786432
#define WS_SUMA    2142208    // 4*704              = 2816
#define WS_NORM    2145024    // 4*704              = 2816
#define WS_LOSSP2  2147840    // 128
#define WS_ST      2147968    // bf16 4*128*8192    = 2097152 floats worth
#define WS_AT      4245120    // bf16 4*768*8192    = 12582912 floats worth
#define WS_NEW_END 16828032   // floats -> 67,312,128 bytes
// ---- old fallback offsets ----
#define OLD_PART   634880
#define OLD_SUMA   4419584
#define OLD_NORM   4422400
#define OLD_GPART  4425216
#define OLD_LOSSP  9143808

// ---- output layout (float offsets) ----
#define OUT_A      0
#define OUT_SC     22380544ULL
#define OUT_MUC    22730240ULL
#define OUT_SGC    22738436ULL
#define OUT_TOT    22763024ULL

typedef __attribute__((ext_vector_type(8))) short bf16x8s;
typedef __attribute__((ext_vector_type(4))) float f32x4;

static __device__ __forceinline__ unsigned short f2bf_rne(float f) {
  unsigned int u = __builtin_bit_cast(unsigned int, f);
  unsigned int r = (u + 0x7fffu + ((u >> 16) & 1u)) >> 16;
  return (unsigned short)r;
}

// monotone float -> u32 (order-preserving incl. negatives; no NaNs here)
static __device__ __forceinline__ unsigned int f2ord(float f) {
  unsigned int u = __builtin_bit_cast(unsigned int, f);
  return (u & 0x80000000u) ? ~u : (u | 0x80000000u);
}

static __device__ __forceinline__ unsigned long long umax64(unsigned long long a,
                                                           unsigned long long b) {
  return a > b ? a : b;
}

// =====================================================================
// E[k,c] = sum_d slot_embed[k,d] * W_proj[d,c], stored as ET[c][k]
__global__ __launch_bounds__(256) void build_ET_k(const float* __restrict__ Wp,
                                                  const float* __restrict__ se,
                                                  float* __restrict__ ET) {
  int idx = blockIdx.x * 256 + threadIdx.x;
  if (idx >= C_ * KP_) return;
  int c = idx / KP_;
  int k = idx % KP_;
  float acc = 0.f;
  if (k < K_) {
    for (int d = 0; d < C_; d++) acc = fmaf(se[k * C_ + d], Wp[d * C_ + c], acc);
  }
  ET[idx] = acc;
}

// =====================================================================
// FUSED kernel, 512 threads/block:
//   blocks 0..3      : FPS (one per batch) -> anchors  [R7 structure]
//   blocks 4..1027   : semantic GEMM, 32 rows each -> Lsem into A region
//   blocks 1028..1091: build ext features
//   blocks 1092..1347: sT bf16 builder: s[n][c] -> sT[b][c][n]
__global__ __launch_bounds__(512, 1) void fused_k(const float* __restrict__ s,
    const float* __restrict__ mu, const float* __restrict__ Sigma,
    const float* __restrict__ mask, const float* __restrict__ ET,
    float* __restrict__ anchors, float* __restrict__ ext,
    float* __restrict__ A, unsigned short* __restrict__ sT) {
  const int bid = blockIdx.x;
  const int tid = threadIdx.x;

  __shared__ __align__(16) float s_lds[32][132];
  __shared__ __align__(16) float et_lds[8][KP_];
  __shared__ __align__(16) float muL[N_ * 3];        // 96 KB (fps only)
  __shared__ __align__(16) float Tt[64][72];         // sT builder transpose tile
  __shared__ double redd[8][4];
  __shared__ unsigned long long redk[2][8];
  __shared__ float an_s[4];

  if (bid >= 1092) {
    // ---------------- sT builder ----------------
    const int sb = bid - 1092;      // 0..255
    const int b = sb >> 6;
    const int rest = sb & 63;
    const int chalf = rest >> 5;    // c-half 0..1
    const int ns = rest & 31;       // n-slab of 256
    const int c0 = chalf * 64, n0 = ns * 256;
#pragma unroll
    for (int t2 = 0; t2 < 4; t2++) {
      const int nb = n0 + t2 * 64;
      {
        int n_loc = tid >> 3;
        int cb = (tid & 7) * 8;
        const float* sp = s + ((size_t)(b * N_ + nb + n_loc)) * C_ + c0 + cb;
        float4 v0 = *(const float4*)(sp);
        float4 v1 = *(const float4*)(sp + 4);
        Tt[cb + 0][n_loc] = v0.x; Tt[cb + 1][n_loc] = v0.y;
        Tt[cb + 2][n_loc] = v0.z; Tt[cb + 3][n_loc] = v0.w;
        Tt[cb + 4][n_loc] = v1.x; Tt[cb + 5][n_loc] = v1.y;
        Tt[cb + 6][n_loc] = v1.z; Tt[cb + 7][n_loc] = v1.w;
      }
      __syncthreads();
      {
        int row = tid >> 3;        // c-local
        int qo = tid & 7;          // 8-value chunk
        float4 f0 = *(const float4*)(&Tt[row][qo * 8]);
        float4 f1 = *(const float4*)(&Tt[row][qo * 8 + 4]);
        unsigned short o[8];
        o[0] = f2bf_rne(f0.x); o[1] = f2bf_rne(f0.y); o[2] = f2bf_rne(f0.z); o[3] = f2bf_rne(f0.w);
        o[4] = f2bf_rne(f1.x); o[5] = f2bf_rne(f1.y); o[6] = f2bf_rne(f1.z); o[7] = f2bf_rne(f1.w);
        unsigned short* dst = sT + ((size_t)(b * C_ + c0 + row)) * N_ + nb + qo * 8;
        *(uint4*)dst = *(uint4*)o;
      }
      __syncthreads();
    }
    return;
  }

  if (bid >= 1028) {
    int idx = (bid - 1028) * 512 + tid;
    if (idx < B_ * N_) {
      float x = mu[(size_t)idx * 3 + 0];
      float y = mu[(size_t)idx * 3 + 1];
      float z = mu[(size_t)idx * 3 + 2];
      const float* S = Sigma + (size_t)idx * 9;
      float* e = ext + (size_t)idx * 16;
      e[0] = x; e[1] = y; e[2] = z;
      e[3] = x * x; e[4] = x * y; e[5] = x * z;
      e[6] = y * y; e[7] = y * z; e[8] = z * z;
      e[9] = S[0]; e[10] = S[1]; e[11] = S[2]; e[12] = S[4]; e[13] = S[5]; e[14] = S[8];
      e[15] = 1.f;
    }
    return;
  }

  if (bid >= 4) {
    const int gb = bid - 4;
    const int b = gb >> 8;
    const int n0 = (gb & 255) * 32;
    const int nt = tid >> 6;
    const int kt = tid & 63;
    {
      const float* sb = s + ((size_t)(b * N_ + n0)) * C_;
      int r = tid >> 4;
      int cb = (tid & 15) * 8;
#pragma unroll
      for (int q = 0; q < 2; q++) {
        float4 v = *(const float4*)(sb + (size_t)r * C_ + cb + q * 4);
        *(float4*)(&s_lds[r][cb + q * 4]) = v;
      }
    }
    float acc[4][12];
#pragma unroll
    for (int i = 0; i < 4; i++)
#pragma unroll
      for (int j = 0; j < 12; j++) acc[i][j] = 0.f;

    for (int cc = 0; cc < 16; cc++) {
      __syncthreads();
#pragma unroll
      for (int q = 0; q < 3; q++) {
        int fid = q * 512 + tid;
        int cl = fid / 192;
        int o4 = fid % 192;
        *(float4*)(&et_lds[cl][o4 * 4]) = *(const float4*)(ET + (size_t)(cc * 8 + cl) * KP_ + o4 * 4);
      }
      __syncthreads();
#pragma unroll
      for (int c8 = 0; c8 < 8; c8++) {
        int c = cc * 8 + c8;
        float sv0 = s_lds[nt * 4 + 0][c];
        float sv1 = s_lds[nt * 4 + 1][c];
        float sv2 = s_lds[nt * 4 + 2][c];
        float sv3 = s_lds[nt * 4 + 3][c];
#pragma unroll
        for (int j = 0; j < 12; j++) {
          float ev = et_lds[c8][kt + 64 * j];
          acc[0][j] = fmaf(sv0, ev, acc[0][j]);
          acc[1][j] = fmaf(sv1, ev, acc[1][j]);
          acc[2][j] = fmaf(sv2, ev, acc[2][j]);
          acc[3][j] = fmaf(sv3, ev, acc[3][j]);
        }
      }
    }
#pragma unroll
    for (int i = 0; i < 4; i++) {
      float* Arow = A + ((size_t)(b * N_ + n0 + nt * 4 + i)) * K_;
#pragma unroll
      for (int j = 0; j < 12; j++) {
        int k = kt + 64 * j;
        if (k < K_) Arow[k] = acc[i][j];
      }
    }
    return;
  }

  // ---------------- FPS (R7 structure, verbatim) ----------------
  const int b = bid;
  const int t = tid;
  const int wv = t >> 6;
  const float* mub = mu + (size_t)b * N_ * 3;
  const float* mkb = mask + (size_t)b * N_;
  float px[16], py[16], pz[16], md[16];

  double sx = 0, sy = 0, sz = 0, sc = 0;
#pragma unroll
  for (int i = 0; i < 16; i++) {
    int p = i * 512 + t;
    px[i] = mub[p * 3 + 0];
    py[i] = mub[p * 3 + 1];
    pz[i] = mub[p * 3 + 2];
    muL[p * 3 + 0] = px[i];
    muL[p * 3 + 1] = py[i];
    muL[p * 3 + 2] = pz[i];
    float mk = mkb[p];
    bool valid = (mk > 0.5f);
    md[i] = valid ? 3.4e38f : -1.f;
    if (valid) { sx += px[i]; sy += py[i]; sz += pz[i]; sc += 1.0; }
  }
  for (int off = 32; off; off >>= 1) {
    sx += __shfl_xor(sx, off);
    sy += __shfl_xor(sy, off);
    sz += __shfl_xor(sz, off);
    sc += __shfl_xor(sc, off);
  }
  if ((t & 63) == 0) { redd[wv][0] = sx; redd[wv][1] = sy; redd[wv][2] = sz; redd[wv][3] = sc; }
  __syncthreads();
  if (t == 0) {
    double ax0 = 0, ay0 = 0, az0 = 0, ac = 0;
    for (int w = 0; w < 8; w++) { ax0 += redd[w][0]; ay0 += redd[w][1]; az0 += redd[w][2]; ac += redd[w][3]; }
    if (ac < 1.0) ac = 1.0;
    an_s[0] = (float)(ax0 / ac); an_s[1] = (float)(ay0 / ac); an_s[2] = (float)(az0 / ac);
  }
  __syncthreads();

  float ax, ay, az;
  {
    float cx = an_s[0], cy = an_s[1], cz = an_s[2];
    float bv = -2.f, bv2 = -2.f;
    int bi = 0, bi2 = 0;
#pragma unroll
    for (int i = 0; i < 16; i++) {
      float dx = px[i] - cx, dy = py[i] - cy, dz = pz[i] - cz;
      float d2 = __fadd_rn(__fadd_rn(__fmul_rn(dx, dx), __fmul_rn(dy, dy)), __fmul_rn(dz, dz));
      float v = (md[i] < 0.f) ? -1.f : d2;
      int p = i * 512 + t;
      if (i & 1) { if (v > bv2) { bv2 = v; bi2 = p; } }
      else       { if (v > bv)  { bv = v;  bi = p; } }
    }
    if (bv2 > bv || (bv2 == bv && bi2 < bi)) { bv = bv2; bi = bi2; }
    unsigned long long k0 = ((unsigned long long)f2ord(bv) << 32) | (unsigned int)(~bi);
    for (int off = 32; off; off >>= 1) {
      unsigned long long ok = __shfl_xor(k0, off);
      if (ok > k0) k0 = ok;
    }
    if ((t & 63) == 0) redk[0][wv] = k0;
    __syncthreads();
    unsigned long long a0 = redk[0][0], a1 = redk[0][1], a2 = redk[0][2], a3 = redk[0][3];
    unsigned long long a4 = redk[0][4], a5 = redk[0][5], a6 = redk[0][6], a7 = redk[0][7];
    unsigned long long bk = umax64(umax64(umax64(a0, a1), umax64(a2, a3)),
                                  umax64(umax64(a4, a5), umax64(a6, a7)));
    int besti = (int)(~(unsigned int)bk);
    ax = muL[besti * 3 + 0]; ay = muL[besti * 3 + 1]; az = muL[besti * 3 + 2];
    if (t == 0) {
      float aa = ax * ax + ay * ay + az * az;
      float4 st = {ax, ay, az, aa};
      *(float4*)(anchors + ((size_t)b * KP_ + 0) * 4) = st;
    }
  }

  for (int k = 1; k < K_; k++) {
    const int par = k & 1;
    float bv = -2.f, bv2 = -2.f;
    int bi = 0, bi2 = 0;
#pragma unroll
    for (int i = 0; i < 16; i++) {
      float dx = px[i] - ax, dy = py[i] - ay, dz = pz[i] - az;
      float d2 = __fadd_rn(__fadd_rn(__fmul_rn(dx, dx), __fmul_rn(dy, dy)), __fmul_rn(dz, dz));
      float m = fminf(md[i], d2);
      md[i] = m;
      int p = i * 512 + t;
      if (i & 1) { if (m > bv2) { bv2 = m; bi2 = p; } }
      else       { if (m > bv)  { bv = m;  bi = p; } }
    }
    if (bv2 > bv || (bv2 == bv && bi2 < bi)) { bv = bv2; bi = bi2; }
    unsigned long long kk = ((unsigned long long)f2ord(bv) << 32) | (unsigned int)(~bi);
    for (int off = 32; off; off >>= 1) {
      unsigned long long ok = __shfl_xor(kk, off);
      if (ok > kk) kk = ok;
    }
    if ((t & 63) == 0) redk[par][wv] = kk;
    __syncthreads();
    unsigned long long a0 = redk[par][0], a1 = redk[par][1], a2 = redk[par][2], a3 = redk[par][3];
    unsigned long long a4 = redk[par][4], a5 = redk[par][5], a6 = redk[par][6], a7 = redk[par][7];
    unsigned long long bk = umax64(umax64(umax64(a0, a1), umax64(a2, a3)),
                                  umax64(umax64(a4, a5), umax64(a6, a7)));
    int besti = (int)(~(unsigned int)bk);
    ax = muL[besti * 3 + 0]; ay = muL[besti * 3 + 1]; az = muL[besti * 3 + 2];
    if (t == 0) {
      float aa = ax * ax + ay * ay + az * az;
      float4 st = {ax, ay, az, aa};
      *(float4*)(anchors + ((size_t)b * KP_ + k) * 4) = st;
    }
  }
  for (int k = K_ + t; k < KP_; k += 512) {
    float4 z4 = {0.f, 0.f, 0.f, 0.f};
    *(float4*)(anchors + ((size_t)b * KP_ + k) * 4) = z4;
  }
}

// =====================================================================
// FUSED postA: spatial logits + mask + softmax (bit-identical arithmetic
// to the previous spatial_softmax_k) + bf16 transpose to At, one pass.
// 1024 blocks = b(4) x 32-row slabs(256). 256 threads = 4 waves x 8 rows.
__global__ __launch_bounds__(256) void postA_k(
    const float* __restrict__ mu, const float* __restrict__ mask,
    const float* __restrict__ anchors, const float* __restrict__ lsm_p,
    const float* __restrict__ wsem_p, const float* __restrict__ wmu_p,
    float* __restrict__ A, unsigned short* __restrict__ At) {
  const int bid = blockIdx.x;
  const int b = bid >> 8;
  const int n0 = (bid & 255) * 32;
  const int tid = threadIdx.x;
  const int wv = tid >> 6;
  const int lane = tid & 63;
  __shared__ __align__(16) float anch_lds[KP_][4];
  __shared__ __align__(16) unsigned short T[KP_][40];  // 80B stride: b128-aligned readout

  for (int q = tid; q < KP_; q += 256)
    *(float4*)(&anch_lds[q][0]) = *(const float4*)(anchors + ((size_t)b * KP_ + q) * 4);
  __syncthreads();

  const float sg = fmaxf(expf(lsm_p[0]), 1e-4f);
  const float inv2s2 = 0.5f / (sg * sg);
  const float wsem = wsem_p[0];
  const float wmu = wmu_p[0];

#pragma unroll
  for (int g = 0; g < 2; g++) {
    const int r0 = wv * 8 + g * 4;       // column group base (mult of 4)
    unsigned short tpack[12][4];
#pragma unroll
    for (int rr = 0; rr < 4; rr++) {
      const size_t gr = (size_t)b * N_ + n0 + r0 + rr;
      const float* mp = mu + gr * 3;
      float x = mp[0], y = mp[1], z = mp[2];
      float mq = x * x + y * y + z * z;
      float mk = mask[gr];
      float* Arow = A + gr * K_;

      float v[11];
      float m = -3e38f;
#pragma unroll
      for (int j = 0; j < 11; j++) {
        int k = lane + 64 * j;
        if (k < K_) {
          float lsem = Arow[k];
          float4 a4 = *(const float4*)(&anch_lds[k][0]);
          float tdot = x * a4.x + y * a4.y + z * a4.z;
          float d2 = mq - 2.f * tdot + a4.w;
          float l = wsem * lsem - wmu * d2 * inv2s2;
          if (mk < 0.5f) l = -1e9f;
          v[j] = l;
        } else v[j] = -1e30f;
        m = fmaxf(m, v[j]);
      }
      for (int off = 32; off; off >>= 1) m = fmaxf(m, __shfl_xor(m, off));
      float sum = 0.f;
#pragma unroll
      for (int j = 0; j < 11; j++) { float e = expf(v[j] - m); v[j] = e; sum += e; }
      for (int off = 32; off; off >>= 1) sum += __shfl_xor(sum, off);
      float r = mk / sum;
#pragma unroll
      for (int j = 0; j < 11; j++) {
        int k = lane + 64 * j;
        float av = v[j] * r;
        if (k < K_) { Arow[k] = av; tpack[j][rr] = f2bf_rne(av); }
        else tpack[j][rr] = 0;
      }
      tpack[11][rr] = 0;
    }
    // 12 ds_write_b64: T[k][r0..r0+3]
#pragma unroll
    for (int j = 0; j < 12; j++) {
      int k = lane + 64 * j;
      *(unsigned long long*)(&T[k][r0]) = *(const unsigned long long*)(&tpack[j][0]);
    }
  }
  __syncthreads();
  // readout: 3 k-rows per thread, 64B each
#pragma unroll
  for (int kq = 0; kq < 3; kq++) {
    int k = tid + 256 * kq;
    const uint4* src = (const uint4*)(&T[k][0]);
    unsigned short* dst = At + ((size_t)(b * KP_ + k)) * N_ + n0;
#pragma unroll
    for (int q = 0; q < 4; q++) *(uint4*)(dst + q * 8) = src[q];
  }
}

// =====================================================================
// spatial softmax (fallback path only)
__global__ __launch_bounds__(256) void spatial_softmax_k(
    const float* __restrict__ mu, const float* __restrict__ mask,
    const float* __restrict__ anchors, const float* __restrict__ lsm_p,
    const float* __restrict__ wsem_p, const float* __restrict__ wmu_p,
    float* __restrict__ A) {
  const int bid = blockIdx.x;
  const int b = bid >> 11;
  const int n0 = (bid & 2047) * 4;
  const int tid = threadIdx.x;
  const int wv = tid >> 6;
  const int lane = tid & 63;
  __shared__ __align__(16) float anch_lds[KP_][4];
  for (int q = tid; q < KP_; q += 256)
    *(float4*)(&anch_lds[q][0]) = *(const float4*)(anchors + ((size_t)b * KP_ + q) * 4);
  __syncthreads();

  const float sg = fmaxf(expf(lsm_p[0]), 1e-4f);
  const float inv2s2 = 0.5f / (sg * sg);
  const float wsem = wsem_p[0];
  const float wmu = wmu_p[0];

  const size_t gr = (size_t)b * N_ + n0 + wv;
  const float* mp = mu + gr * 3;
  float x = mp[0], y = mp[1], z = mp[2];
  float mq = x * x + y * y + z * z;
  float mk = mask[gr];
  float* Arow = A + gr * K_;

  float v[11];
  float m = -3e38f;
#pragma unroll
  for (int j = 0; j < 11; j++) {
    int k = lane + 64 * j;
    if (k < K_) {
      float lsem = Arow[k];
      float4 a4 = *(const float4*)(&anch_lds[k][0]);
      float tdot = x * a4.x + y * a4.y + z * a4.z;
      float d2 = mq - 2.f * tdot + a4.w;
      float l = wsem * lsem - wmu * d2 * inv2s2;
      if (mk < 0.5f) l = -1e9f;
      v[j] = l;
    } else v[j] = -1e30f;
    m = fmaxf(m, v[j]);
  }
  for (int off = 32; off; off >>= 1) m = fmaxf(m, __shfl_xor(m, off));
  float sum = 0.f;
#pragma unroll
  for (int j = 0; j < 11; j++) { float e = expf(v[j] - m); v[j] = e; sum += e; }
  for (int off = 32; off; off >>= 1) sum += __shfl_xor(sum, off);
  float r = mk / sum;
#pragma unroll
  for (int j = 0; j < 11; j++) {
    int k = lane + 64 * j;
    if (k < K_) Arow[k] = v[j] * r;
  }
}

// =====================================================================
// MFMA s-moments: mpart[np][b][k][c] = sum_n At[k][n] * sT[c][n]
__global__ __launch_bounds__(256) void gemm2_mfma_k(const unsigned short* __restrict__ At,
    const unsigned short* __restrict__ sT, float* __restrict__ mpart) {
  const int bid = blockIdx.x;
  const int np = bid / 24;
  const int rem = bid % 24;
  const int b = rem / 6;
  const int kt2 = rem % 6;
  const int k0 = kt2 * 128;
  const int tid = threadIdx.x;
  const int l = tid & 63;
  const int w = tid >> 6;
  const int wr = w >> 1, wc = w & 1;

  __shared__ __align__(16) unsigned short Ak_lds[128 * 72];
  __shared__ __align__(16) unsigned short Bc_lds[128 * 72];

  f32x4 acc[4][4];
#pragma unroll
  for (int i = 0; i < 4; i++)
#pragma unroll
    for (int j = 0; j < 4; j++) acc[i][j] = (f32x4){0.f, 0.f, 0.f, 0.f};

  const unsigned short* gk = At + ((size_t)(b * KP_ + k0)) * N_;
  const unsigned short* gc = sT + ((size_t)(b * C_)) * N_;
  const int nbase = np * 4096;

  for (int ch = 0; ch < 64; ch++) {
    const int n0 = nbase + ch * 64;
    __syncthreads();
#pragma unroll
    for (int q = 0; q < 4; q++) {
      int chunk = tid + 256 * q;
      int row = chunk >> 3, slot = chunk & 7;
      uint4 v = *(const uint4*)(gk + (size_t)row * N_ + n0 + slot * 8);
      *(uint4*)(Ak_lds + row * 72 + slot * 8) = v;
      uint4 v2 = *(const uint4*)(gc + (size_t)row * N_ + n0 + slot * 8);
      *(uint4*)(Bc_lds + row * 72 + slot * 8) = v2;
    }
    __syncthreads();
#pragma unroll
    for (int ks = 0; ks < 2; ks++) {
      const int noff = (l >> 4) * 8 + ks * 32;
      bf16x8s af[4], bfr[4];
#pragma unroll
      for (int f = 0; f < 4; f++) {
        af[f]  = *(const bf16x8s*)(Ak_lds + (wr * 64 + f * 16 + (l & 15)) * 72 + noff);
        bfr[f] = *(const bf16x8s*)(Bc_lds + (wc * 64 + f * 16 + (l & 15)) * 72 + noff);
      }
#pragma unroll
      for (int i = 0; i < 4; i++)
#pragma unroll
        for (int j = 0; j < 4; j++)
          acc[i][j] = __builtin_amdgcn_mfma_f32_16x16x32_bf16(af[i], bfr[j], acc[i][j], 0, 0, 0);
    }
  }
  float* mp = mpart + ((size_t)((np * 4 + b) * KP_ + k0)) * C_;
#pragma unroll
  for (int i = 0; i < 4; i++) {
#pragma unroll
    for (int j = 0; j < 4; j++) {
#pragma unroll
      for (int r = 0; r < 4; r++) {
        int ki = wr * 64 + i * 16 + (l >> 4) * 4 + r;
        int ci = wc * 64 + j * 16 + (l & 15);
        mp[(size_t)ki * C_ + ci] = acc[i][j][r];
      }
    }
  }
}

// =====================================================================
// fp32 ext moments (16 features) + sum(A^2).
__global__ __launch_bounds__(256) void gemm2_ext_k(const float* __restrict__ A,
    const float* __restrict__ ext, float* __restrict__ epart) {
  const int bid = blockIdx.x;
  const int np = bid / 44;
  const int rem = bid % 44;
  const int b = rem / 11;
  const int k0 = (rem % 11) * 64;
  const int n0 = np * 1024;
  const int tid = threadIdx.x;
  const int kt = tid & 15;
  const int ft = tid >> 4;
  __shared__ __align__(16) float A_lds[32][64];
  __shared__ __align__(16) float F_lds[32][32];
  float acc[4][2];
#pragma unroll
  for (int c = 0; c < 4; c++) { acc[c][0] = 0.f; acc[c][1] = 0.f; }
  float asq[4] = {0.f, 0.f, 0.f, 0.f};

  for (int ch = 0; ch < 32; ch++) {
    int nb = n0 + ch * 32;
    __syncthreads();
#pragma unroll
    for (int p = 0; p < 8; p++) {
      int q = tid + 256 * p; int r = q >> 6; int c = q & 63; int k = k0 + c;
      A_lds[r][c] = (k < K_) ? A[((size_t)(b * N_ + nb + r)) * K_ + k] : 0.f;
    }
#pragma unroll
    for (int p = 0; p < 2; p++) {
      int q = tid + 256 * p; int r = q >> 4; int e = q & 15;
      F_lds[r][e] = ext[((size_t)(b * N_ + nb + r)) * 16 + e];
      F_lds[r][16 + e] = 0.f;
    }
    __syncthreads();
#pragma unroll
    for (int i = 0; i < 32; i++) {
      float a0 = A_lds[i][kt * 4 + 0];
      float a1 = A_lds[i][kt * 4 + 1];
      float a2 = A_lds[i][kt * 4 + 2];
      float a3 = A_lds[i][kt * 4 + 3];
      if (ft == 0) {
        asq[0] = fmaf(a0, a0, asq[0]); asq[1] = fmaf(a1, a1, asq[1]);
        asq[2] = fmaf(a2, a2, asq[2]); asq[3] = fmaf(a3, a3, asq[3]);
      }
#pragma unroll
      for (int f = 0; f < 2; f++) {
        float fv = F_lds[i][ft * 2 + f];
        acc[0][f] = fmaf(a0, fv, acc[0][f]);
        acc[1][f] = fmaf(a1, fv, acc[1][f]);
        acc[2][f] = fmaf(a2, fv, acc[2][f]);
        acc[3][f] = fmaf(a3, fv, acc[3][f]);
      }
    }
  }
#pragma unroll
  for (int c = 0; c < 4; c++) {
    size_t base = ((size_t)((np * 4 + b) * KT_ + k0 + kt * 4 + c)) * 32;
#pragma unroll
    for (int f = 0; f < 2; f++) {
      int fidx = ft * 2 + f;
      if (fidx < 16) epart[base + fidx] = acc[c][f];
    }
    if (ft == 0) epart[base + 16] = asq[c];
  }
}

// =====================================================================
// Postprocess (MFMA path): one wave per (b,k).
__global__ __launch_bounds__(256) void postproc2_k(const float* __restrict__ mpart,
    const float* __restrict__ epart, float* __restrict__ out,
    float* __restrict__ sumA_ws, float* __restrict__ norm_ws) {
  const int gw = blockIdx.x * 4 + (threadIdx.x >> 6);
  const int lane = threadIdx.x & 63;
  const int b = gw / K_;
  const int k = gw % K_;
  float v0 = 0.f, v1 = 0.f, v2 = 0.f, v3 = 0.f;
#pragma unroll
  for (int np = 0; np < 2; np++) {
    const float* r = mpart + ((size_t)((np * 4 + b) * KP_ + k)) * C_;
    v0 += r[lane];
    v1 += r[64 + lane];
  }
#pragma unroll
  for (int np = 0; np < 8; np++) {
    const float* e = epart + ((size_t)((np * 4 + b) * KT_ + k)) * 32;
    if (lane < 16) v2 += e[lane];
    if (lane == 0) v3 += e[16];
  }
  float sumA = __shfl(v2, 15);
  float asq = __shfl(v3, 0);
  float denom = fmaxf(sumA, 1e-8f);
  float inv = 1.f / denom;
  out[OUT_SC + ((size_t)(b * K_ + k)) * C_ + lane] = v0 * inv;
  out[OUT_SC + ((size_t)(b * K_ + k)) * C_ + 64 + lane] = v1 * inv;
  float m0 = __shfl(v2, 0) * inv;
  float m1 = __shfl(v2, 1) * inv;
  float m2 = __shfl(v2, 2) * inv;
  if (lane < 3) out[OUT_MUC + ((size_t)(b * K_ + k)) * 3 + lane] = (lane == 0) ? m0 : ((lane == 1) ? m1 : m2);
  float W = sumA * inv;
  float fac = 2.f - W;
  float M2s[6], Sgs[6];
#pragma unroll
  for (int j = 0; j < 6; j++) { M2s[j] = __shfl(v2, 3 + j); Sgs[j] = __shfl(v2, 9 + j); }
  if (lane < 9) {
    int d = lane / 3, e = lane % 3;
    int lo = min(d, e), hi = max(d, e);
    int j = hi + 2 * lo - ((lo * (lo - 1)) >> 1);
    float mud = (d == 0) ? m0 : ((d == 1) ? m1 : m2);
    float mue = (e == 0) ? m0 : ((e == 1) ? m1 : m2);
    float M2j = (j == 0) ? M2s[0] : (j == 1) ? M2s[1] : (j == 2) ? M2s[2] : (j == 3) ? M2s[3] : (j == 4) ? M2s[4] : M2s[5];
    float Sgj = (j == 0) ? Sgs[0] : (j == 1) ? Sgs[1] : (j == 2) ? Sgs[2] : (j == 3) ? Sgs[3] : (j == 4) ? Sgs[4] : Sgs[5];
    float val = (Sgj + M2j) * inv - mud * mue * fac;
    if (d == e) val += 1e-6f;
    out[OUT_SGC + ((size_t)(b * K_ + k)) * 9 + lane] = val;
  }
  if (lane == 0) { sumA_ws[b * KT_ + k] = sumA; norm_ws[b * KT_ + k] = sqrtf(asq); }
}

// =====================================================================
// MFMA gram + fused collapse-loss tile partial (84 blocks).
__global__ __launch_bounds__(256) void gram_mfma_k(const unsigned short* __restrict__ At,
    const float* __restrict__ norm_ws, float* __restrict__ lossp) {
  const int bid = blockIdx.x;
  const int b = bid / 21;
  int p = bid % 21;
  int tk = 0, tl = 0;
  { int pp = p; for (int r0 = 0; r0 < 6; r0++) { int cnt = 6 - r0; if (pp < cnt) { tk = r0; tl = r0 + pp; break; } pp -= cnt; } }
  const int k0 = tk * 128, l0 = tl * 128;
  const int tid = threadIdx.x;
  const int l = tid & 63;
  const int w = tid >> 6;
  const int wr = w >> 1, wc = w & 1;

  __shared__ __align__(16) unsigned short Ak_lds[128 * 72];
  __shared__ __align__(16) unsigned short Al_lds[128 * 72];
  __shared__ float nk_s[128], nl_s[128], red_s[4];

  if (tid < 128) {
    int kk = k0 + tid;
    nk_s[tid] = (kk < K_) ? fmaxf(norm_ws[b * KT_ + kk], 1e-8f) : 1.f;
  } else {
    int ll2 = l0 + tid - 128;
    nl_s[tid - 128] = (ll2 < K_) ? fmaxf(norm_ws[b * KT_ + ll2], 1e-8f) : 1.f;
  }

  f32x4 acc[4][4];
#pragma unroll
  for (int i = 0; i < 4; i++)
#pragma unroll
    for (int j = 0; j < 4; j++) acc[i][j] = (f32x4){0.f, 0.f, 0.f, 0.f};

  const unsigned short* gk = At + ((size_t)(b * KP_ + k0)) * N_;
  const unsigned short* gl = At + ((size_t)(b * KP_ + l0)) * N_;

  for (int ch = 0; ch < 128; ch++) {
    const int n0 = ch * 64;
    __syncthreads();
#pragma unroll
    for (int q = 0; q < 4; q++) {
      int chunk = tid + 256 * q;
      int row = chunk >> 3, slot = chunk & 7;
      uint4 v = *(const uint4*)(gk + (size_t)row * N_ + n0 + slot * 8);
      *(uint4*)(Ak_lds + row * 72 + slot * 8) = v;
      uint4 v2 = *(const uint4*)(gl + (size_t)row * N_ + n0 + slot * 8);
      *(uint4*)(Al_lds + row * 72 + slot * 8) = v2;
    }
    __syncthreads();
#pragma unroll
    for (int ks = 0; ks < 2; ks++) {
      const int noff = (l >> 4) * 8 + ks * 32;
      bf16x8s af[4], bfr[4];
#pragma unroll
      for (int f = 0; f < 4; f++) {
        af[f]  = *(const bf16x8s*)(Ak_lds + (wr * 64 + f * 16 + (l & 15)) * 72 + noff);
        bfr[f] = *(const bf16x8s*)(Al_lds + (wc * 64 + f * 16 + (l & 15)) * 72 + noff);
      }
#pragma unroll
      for (int i = 0; i < 4; i++)
#pragma unroll
        for (int j = 0; j < 4; j++)
          acc[i][j] = __builtin_amdgcn_mfma_f32_16x16x32_bf16(af[i], bfr[j], acc[i][j], 0, 0, 0);
    }
  }

  float local = 0.f;
  const float wgt = (tk == tl) ? 1.f : 2.f;
#pragma unroll
  for (int i = 0; i < 4; i++) {
#pragma unroll
    for (int j = 0; j < 4; j++) {
#pragma unroll
      for (int r = 0; r < 4; r++) {
        int ki = wr * 64 + i * 16 + (l >> 4) * 4 + r;
        int li = wc * 64 + j * 16 + (l & 15);
        int gkk = k0 + ki, gll = l0 + li;
        if (gkk < K_ && gll < K_ && gkk != gll) {
          float g = acc[i][j][r];
          float x = g / (nk_s[ki] * nl_s[li]);
          local = fmaf(wgt * x, x, local);
        }
      }
    }
  }
  for (int off = 32; off; off >>= 1) local += __shfl_xor(local, off);
  if ((tid & 63) == 0) red_s[w] = local;
  __syncthreads();
  if (tid == 0) lossp[bid] = red_s[0] + red_s[1] + red_s[2] + red_s[3];
}

// final for the MFMA path: 84 tile partials
__global__ __launch_bounds__(256) void final2_k(const float* __restrict__ sumA_ws,
    const float* __restrict__ lossp, float* __restrict__ out) {
  const int lane = threadIdx.x & 63;
  const int wv = threadIdx.x >> 6;
  __shared__ float occ_s[4];
  __shared__ float col_s[4];
  float sb = 0.f;
  for (int k = lane; k < K_; k += 64) sb += sumA_ws[wv * KT_ + k];
  for (int off = 32; off; off >>= 1) sb += __shfl_xor(sb, off);
  float Sb = fmaxf(sb, 1e-8f);
  float lo = 0.f;
  const float tgt = 1.f / (float)K_;
  for (int k = lane; k < K_; k += 64) {
    float o = sumA_ws[wv * KT_ + k] / Sb - tgt;
    lo = fmaf(o, o, lo);
  }
  for (int off = 32; off; off >>= 1) lo += __shfl_xor(lo, off);
  if (lane == 0) occ_s[wv] = lo;
  float c = 0.f;
  for (int i = threadIdx.x; i < 84; i += 256) c += lossp[i];
  for (int off = 32; off; off >>= 1) c += __shfl_xor(c, off);
  if (lane == 0) col_s[wv] = c;
  __syncthreads();
  if (threadIdx.x == 0) {
    float loss_occ = (occ_s[0] + occ_s[1] + occ_s[2] + occ_s[3]) / (float)(B_ * K_);
    float coll = (col_s[0] + col_s[1] + col_s[2] + col_s[3]) / ((float)B_ * K_ * K_);
    out[OUT_TOT] = loss_occ + 0.1f * coll;
  }
}

// =====================================================================
// ---- OLD fp32 fallback path ----
__global__ __launch_bounds__(256) void gemm2_k(const float* __restrict__ A,
    const float* __restrict__ s, const float* __restrict__ ext,
    float* __restrict__ part) {
  const int bid = blockIdx.x;
  const int np = bid / 44;
  const int rem = bid % 44;
  const int b = rem / 11;
  const int k0 = (rem % 11) * 64;
  const int n0 = np * 1024;
  const int tid = threadIdx.x;
  const int kt = tid & 15;
  const int ft = tid >> 4;
  __shared__ __align__(16) float A_lds[32][64];
  __shared__ __align__(16) float F_lds[32][160];
  float acc[4][10];
#pragma unroll
  for (int c = 0; c < 4; c++)
#pragma unroll
    for (int f = 0; f < 10; f++) acc[c][f] = 0.f;
  float asq[4] = {0.f, 0.f, 0.f, 0.f};
  for (int ch = 0; ch < 32; ch++) {
    int nb = n0 + ch * 32;
    __syncthreads();
#pragma unroll
    for (int p = 0; p < 8; p++) {
      int q = tid + 256 * p; int r = q >> 6; int c = q & 63; int k = k0 + c;
      A_lds[r][c] = (k < K_) ? A[((size_t)(b * N_ + nb + r)) * K_ + k] : 0.f;
    }
#pragma unroll
    for (int p = 0; p < 16; p++) {
      int q = tid + 256 * p; int r = q >> 7; int c = q & 127;
      F_lds[r][c] = s[((size_t)(b * N_ + nb + r)) * C_ + c];
    }
#pragma unroll
    for (int p = 0; p < 2; p++) {
      int q = tid + 256 * p; int r = q >> 4; int e = q & 15;
      F_lds[r][128 + e] = ext[((size_t)(b * N_ + nb + r)) * 16 + e];
      F_lds[r][144 + e] = 0.f;
    }
    __syncthreads();
#pragma unroll
    for (int i = 0; i < 32; i++) {
      float a0 = A_lds[i][kt * 4 + 0];
      float a1 = A_lds[i][kt * 4 + 1];
      float a2 = A_lds[i][kt * 4 + 2];
      float a3 = A_lds[i][kt * 4 + 3];
      if (ft == 0) {
        asq[0] = fmaf(a0, a0, asq[0]); asq[1] = fmaf(a1, a1, asq[1]);
        asq[2] = fmaf(a2, a2, asq[2]); asq[3] = fmaf(a3, a3, asq[3]);
      }
#pragma unroll
      for (int f = 0; f < 10; f++) {
        float fv = F_lds[i][ft * 10 + f];
        acc[0][f] = fmaf(a0, fv, acc[0][f]);
        acc[1][f] = fmaf(a1, fv, acc[1][f]);
        acc[2][f] = fmaf(a2, fv, acc[2][f]);
        acc[3][f] = fmaf(a3, fv, acc[3][f]);
      }
    }
  }
#pragma unroll
  for (int c = 0; c < 4; c++) {
    size_t base = ((size_t)((np * 4 + b) * KT_ + k0 + kt * 4 + c)) * 168;
#pragma unroll
    for (int f = 0; f < 10; f++) part[base + ft * 10 + f] = acc[c][f];
    if (ft == 0) part[base + 160] = asq[c];
  }
}

__global__ __launch_bounds__(256) void postproc_k(const float* __restrict__ part,
    float* __restrict__ out, float* __restrict__ sumA_ws, float* __restrict__ norm_ws) {
  const int gw = blockIdx.x * 4 + (threadIdx.x >> 6);
  const int lane = threadIdx.x & 63;
  const int b = gw / K_;
  const int k = gw % K_;
  float v0 = 0.f, v1 = 0.f, v2 = 0.f, v3 = 0.f;
  for (int np = 0; np < 8; np++) {
    const float* r = part + ((size_t)((np * 4 + b) * KT_ + k)) * 168;
    v0 += r[lane];
    v1 += r[64 + lane];
    if (lane < 16) v2 += r[128 + lane];
    if (lane == 0) v3 += r[160];
  }
  float sumA = __shfl(v2, 15);
  float asq = __shfl(v3, 0);
  float denom = fmaxf(sumA, 1e-8f);
  float inv = 1.f / denom;
  out[OUT_SC + ((size_t)(b * K_ + k)) * C_ + lane] = v0 * inv;
  out[OUT_SC + ((size_t)(b * K_ + k)) * C_ + 64 + lane] = v1 * inv;
  float m0 = __shfl(v2, 0) * inv;
  float m1 = __shfl(v2, 1) * inv;
  float m2 = __shfl(v2, 2) * inv;
  if (lane < 3) out[OUT_MUC + ((size_t)(b * K_ + k)) * 3 + lane] = (lane == 0) ? m0 : ((lane == 1) ? m1 : m2);
  float W = sumA * inv;
  float fac = 2.f - W;
  float M2s[6], Sgs[6];
#pragma unroll
  for (int j = 0; j < 6; j++) { M2s[j] = __shfl(v2, 3 + j); Sgs[j] = __shfl(v2, 9 + j); }
  if (lane < 9) {
    int d = lane / 3, e = lane % 3;
    int lo = min(d, e), hi = max(d, e);
    int j = hi + 2 * lo - ((lo * (lo - 1)) >> 1);
    float mud = (d == 0) ? m0 : ((d == 1) ? m1 : m2);
    float mue = (e == 0) ? m0 : ((e == 1) ? m1 : m2);
    float M2j = (j == 0) ? M2s[0] : (j == 1) ? M2s[1] : (j == 2) ? M2s[2] : (j == 3) ? M2s[3] : (j == 4) ? M2s[4] : M2s[5];
    float Sgj = (j == 0) ? Sgs[0] : (j == 1) ? Sgs[1] : (j == 2) ? Sgs[2] : (j == 3) ? Sgs[3] : (j == 4) ? Sgs[4] : Sgs[5];
    float val = (Sgj + M2j) * inv - mud * mue * fac;
    if (d == e) val += 1e-6f;
    out[OUT_SGC + ((size_t)(b * K_ + k)) * 9 + lane] = val;
  }
  if (lane == 0) { sumA_ws[b * KT_ + k] = sumA; norm_ws[b * KT_ + k] = sqrtf(asq); }
}

__device__ __forceinline__ int swz(int f) { return f ^ (((f >> 5) & 3) << 3); }

__global__ __launch_bounds__(256) void gram_k(const float* __restrict__ A,
                                              float* __restrict__ Gpart) {
  const int bid = blockIdx.x;
  const int np = bid & 1;
  int q = bid >> 1;
  const int b = q / 21;
  int p = q % 21;
  int tk = 0, tl = 0;
  { int pp = p; for (int r0 = 0; r0 < 6; r0++) { int cnt = 6 - r0; if (pp < cnt) { tk = r0; tl = r0 + pp; break; } pp -= cnt; } }
  const int k0 = tk * 128, l0 = tl * 128;
  const int n0 = np * 4096;
  const int tid = threadIdx.x;
  const int ktid = tid & 15, ltid = tid >> 4;
  const bool diag = (tk == tl);
  __shared__ __align__(16) float Ak[32][128];
  __shared__ __align__(16) float Al[32][128];
  float acc[8][8];
#pragma unroll
  for (int i = 0; i < 8; i++)
#pragma unroll
    for (int j = 0; j < 8; j++) acc[i][j] = 0.f;
  const int kb = swz(ktid * 8);
  const int lb = swz(ltid * 8);
  for (int ch = 0; ch < 128; ch++) {
    int nb = n0 + ch * 32;
    __syncthreads();
#pragma unroll
    for (int pq = 0; pq < 16; pq++) {
      int qq = tid + 256 * pq; int r = qq >> 7; int c = qq & 127;
      int kk = k0 + c;
      Ak[r][swz(c)] = (kk < K_) ? A[((size_t)(b * N_ + nb + r)) * K_ + kk] : 0.f;
      if (!diag) {
        int ll = l0 + c;
        Al[r][swz(c)] = (ll < K_) ? A[((size_t)(b * N_ + nb + r)) * K_ + ll] : 0.f;
      }
    }
    __syncthreads();
    const float (*Alp)[128] = diag ? Ak : Al;
#pragma unroll
    for (int i = 0; i < 32; i++) {
      float4 ka = *(const float4*)(&Ak[i][kb]);
      float4 kb4 = *(const float4*)(&Ak[i][kb + 4]);
      float4 la = *(const float4*)(&Alp[i][lb]);
      float4 lb4 = *(const float4*)(&Alp[i][lb + 4]);
      float av[8] = {ka.x, ka.y, ka.z, ka.w, kb4.x, kb4.y, kb4.z, kb4.w};
      float lv[8] = {la.x, la.y, la.z, la.w, lb4.x, lb4.y, lb4.z, lb4.w};
#pragma unroll
      for (int ii = 0; ii < 8; ii++)
#pragma unroll
        for (int jj = 0; jj < 8; jj++)
          acc[ii][jj] = fmaf(av[ii], lv[jj], acc[ii][jj]);
    }
  }
#pragma unroll
  for (int ii = 0; ii < 8; ii++) {
    int kk = k0 + ktid * 8 + ii;
    float* gp = Gpart + ((size_t)((np * 4 + b) * KP_ + kk)) * KP_ + l0 + ltid * 8;
#pragma unroll
    for (int jj = 0; jj < 8; jj++) gp[jj] = acc[ii][jj];
  }
}

__global__ __launch_bounds__(256) void loss_part_k(const float* __restrict__ Gpart,
    const float* __restrict__ norm_ws, float* __restrict__ lossp) {
  const long long total = (long long)B_ * 21 * 16384;
  float local = 0.f;
  for (long long idx = (long long)blockIdx.x * 256 + threadIdx.x; idx < total; idx += (long long)512 * 256) {
    int e = (int)(idx & 16383);
    int rest = (int)(idx >> 14);
    int p = rest % 21;
    int b = rest / 21;
    int tk = 0, tl = 0;
    { int pp = p; for (int r0 = 0; r0 < 6; r0++) { int cnt = 6 - r0; if (pp < cnt) { tk = r0; tl = r0 + pp; break; } pp -= cnt; } }
    int i = e >> 7, j = e & 127;
    int k = tk * 128 + i, l = tl * 128 + j;
    if (k < K_ && l < K_ && k != l) {
      size_t i0 = ((size_t)((0 * 4 + b) * KP_ + k)) * KP_ + l;
      size_t i1 = ((size_t)((1 * 4 + b) * KP_ + k)) * KP_ + l;
      float g = Gpart[i0] + Gpart[i1];
      float nk = fmaxf(norm_ws[b * KT_ + k], 1e-8f);
      float nl2 = fmaxf(norm_ws[b * KT_ + l], 1e-8f);
      float x = g / (nk * nl2);
      float wgt = (tk == tl) ? 1.f : 2.f;
      local = fmaf(wgt * x, x, local);
    }
  }
  __shared__ float red[4];
  for (int off = 32; off; off >>= 1) local += __shfl_xor(local, off);
  if ((threadIdx.x & 63) == 0) red[threadIdx.x >> 6] = local;
  __syncthreads();
  if (threadIdx.x == 0) lossp[blockIdx.x] = red[0] + red[1] + red[2] + red[3];
}

__global__ __launch_bounds__(256) void final_k(const float* __restrict__ sumA_ws,
    const float* __restrict__ lossp, float* __restrict__ out) {
  const int lane = threadIdx.x & 63;
  const int wv = threadIdx.x >> 6;
  __shared__ float occ_s[4];
  __shared__ float col_s[4];
  float sb = 0.f;
  for (int k = lane; k < K_; k += 64) sb += sumA_ws[wv * KT_ + k];
  for (int off = 32; off; off >>= 1) sb += __shfl_xor(sb, off);
  float Sb = fmaxf(sb, 1e-8f);
  float lo = 0.f;
  const float tgt = 1.f / (float)K_;
  for (int k = lane; k < K_; k += 64) {
    float o = sumA_ws[wv * KT_ + k] / Sb - tgt;
    lo = fmaf(o, o, lo);
  }
  for (int off = 32; off; off >>= 1) lo += __shfl_xor(lo, off);
  if (lane == 0) occ_s[wv] = lo;
  float c = lossp[threadIdx.x] + lossp[threadIdx.x + 256];
  for (int off = 32; off; off >>= 1) c += __shfl_xor(c, off);
  if (lane == 0) col_s[wv] = c;
  __syncthreads();
  if (threadIdx.x == 0) {
    float loss_occ = (occ_s[0] + occ_s[1] + occ_s[2] + occ_s[3]) / (float)(B_ * K_);
    float coll = (col_s[0] + col_s[1] + col_s[2] + col_s[3]) / ((float)B_ * K_ * K_);
    out[OUT_TOT] = loss_occ + 0.1f * coll;
  }
}

// =====================================================================
extern "C" void kernel_launch(void* const* d_in, const int* in_sizes, int n_in,
                              void* d_out, int out_size, void* d_ws, size_t ws_size,
                              hipStream_t stream) {
  const float* s = (const float*)d_in[0];
  const float* mu = (const float*)d_in[1];
  const float* Sigma = (const float*)d_in[2];
  const float* mask = (const float*)d_in[3];
  const float* Wp = (const float*)d_in[4];
  const float* se = (const float*)d_in[5];
  const float* lsm = (const float*)d_in[6];
  const float* wsem = (const float*)d_in[7];
  const float* wmu = (const float*)d_in[8];
  float* out = (float*)d_out;
  float* ws = (float*)d_ws;

  float* ET = ws + WS_ET;
  float* anch = ws + WS_ANCH;
  float* ext = ws + WS_EXT;

  const bool use_mfma = ws_size >= (size_t)WS_NEW_END * 4;

  if (use_mfma) {
    float* epart = ws + WS_EPART;
    float* mpart = ws + WS_MPART;
    float* sumA = ws + WS_SUMA;
    float* nrm = ws + WS_NORM;
    float* lossp2 = ws + WS_LOSSP2;
    unsigned short* sT = (unsigned short*)(ws + WS_ST);
    unsigned short* At = (unsigned short*)(ws + WS_AT);

    hipLaunchKernelGGL(build_ET_k, dim3(384), dim3(256), 0, stream, Wp, se, ET);
    hipLaunchKernelGGL(fused_k, dim3(1348), dim3(512), 0, stream, s, mu, Sigma, mask, ET, anch, ext, out, sT);
    hipLaunchKernelGGL(postA_k, dim3(1024), dim3(256), 0, stream, mu, mask, anch, lsm, wsem, wmu, out, At);
    hipLaunchKernelGGL(gemm2_mfma_k, dim3(48), dim3(256), 0, stream, At, sT, mpart);
    hipLaunchKernelGGL(gemm2_ext_k, dim3(352), dim3(256), 0, stream, out, ext, epart);
    hipLaunchKernelGGL(postproc2_k, dim3(683), dim3(256), 0, stream, mpart, epart, out, sumA, nrm);
    hipLaunchKernelGGL(gram_mfma_k, dim3(84), dim3(256), 0, stream, At, nrm, lossp2);
    hipLaunchKernelGGL(final2_k, dim3(1), dim3(256), 0, stream, sumA, lossp2, out);
  } else {
    float* part = ws + OLD_PART;
    float* sumA = ws + OLD_SUMA;
    float* nrm = ws + OLD_NORM;
    float* Gpart = ws + OLD_GPART;
    float* lossp = ws + OLD_LOSSP;
    unsigned short* sT = (unsigned short*)(ws + WS_ST);

    hipLaunchKernelGGL(build_ET_k, dim3(384), dim3(256), 0, stream, Wp, se, ET);
    hipLaunchKernelGGL(fused_k, dim3(1348), dim3(512), 0, stream, s, mu, Sigma, mask, ET, anch, ext, out, sT);
    hipLaunchKernelGGL(spatial_softmax_k, dim3(8192), dim3(256), 0, stream, mu, mask, anch, lsm, wsem, wmu, out);
    hipLaunchKernelGGL(gemm2_k, dim3(352), dim3(256), 0, stream, out, s, ext, part);
    hipLaunchKernelGGL(postproc_k, dim3(683), dim3(256), 0, stream, part, out, sumA, nrm);
    hipLaunchKernelGGL(gram_k, dim3(168), dim3(256), 0, stream, out, Gpart);
    hipLaunchKernelGGL(loss_part_k, dim3(512), dim3(256), 0, stream, Gpart, nrm, lossp);
    hipLaunchKernelGGL(final_k, dim3(1), dim3(256), 0, stream, sumA, lossp, out);
  }
}

// Round 11
// 1123.606 us; speedup vs baseline: 1.4012x; 1.1148x over previous
//
#include <hip/hip_runtime.h>
#include <hip/hip_bf16.h>
#include <math.h>

#define B_ 4
#define N_ 8192
#define C_ 128
#define K_ 683
#define KP_ 768
#define KT_ 704   // 11*64 padded K

// ---- workspace layout, MFMA path (float offsets) ----
#define WS_ET      0          // 128*768            = 98304
#define WS_ANCH    98304      // 4*768*4            = 12288
#define WS_EXT     110592     // 4*8192*16          = 524288
#define WS_EPART   634880     // 8*4*704*32         = 720896
#define WS_MPART   1355776    // 2*4*768*128        = 786432
#define WS_SUMA    2142208    // 4*704              = 2816
#define WS_ASQ     2145024    // 4*704              = 2816
#define WS_LOSSP2  2147840    // 128
#define WS_ST      2147968    // bf16 4*128*8192    = 2097152 floats worth
#define WS_AT      4245120    // bf16 4*768*8192    = 12582912 floats worth
#define WS_NEW_END 16828032   // floats -> 67,312,128 bytes
// ---- old fallback offsets ----
#define OLD_PART   634880
#define OLD_SUMA   4419584
#define OLD_NORM   4422400
#define OLD_GPART  4425216
#define OLD_LOSSP  9143808

// ---- output layout (float offsets) ----
#define OUT_A      0
#define OUT_SC     22380544ULL
#define OUT_MUC    22730240ULL
#define OUT_SGC    22738436ULL
#define OUT_TOT    22763024ULL

typedef __attribute__((ext_vector_type(8))) short bf16x8s;
typedef __attribute__((ext_vector_type(4))) float f32x4;

static __device__ __forceinline__ unsigned short f2bf_rne(float f) {
  unsigned int u = __builtin_bit_cast(unsigned int, f);
  unsigned int r = (u + 0x7fffu + ((u >> 16) & 1u)) >> 16;
  return (unsigned short)r;
}

static __device__ __forceinline__ unsigned int f2ord(float f) {
  unsigned int u = __builtin_bit_cast(unsigned int, f);
  return (u & 0x80000000u) ? ~u : (u | 0x80000000u);
}

static __device__ __forceinline__ unsigned long long umax64(unsigned long long a,
                                                           unsigned long long b) {
  return a > b ? a : b;
}

// Pairwise distance^2; contract(off) makes plain ops IEEE RN without FMA
// contraction == the reference's per-op semantics. Paired layout invites
// v_pk_{mul,add}_f32 dual-issue packing.
static __device__ __forceinline__ void d2pair(const float2 x2, const float2 y2,
                                              const float2 z2, const float ax,
                                              const float ay, const float az,
                                              float& dl, float& dh) {
#pragma clang fp contract(off)
  float dxl = x2.x - ax, dxh = x2.y - ax;
  float dyl = y2.x - ay, dyh = y2.y - ay;
  float dzl = z2.x - az, dzh = z2.y - az;
  float al = dxl * dxl, ah = dxh * dxh;
  float bl = dyl * dyl, bh = dyh * dyh;
  float cl = dzl * dzl, ch = dzh * dzh;
  dl = (al + bl) + cl;
  dh = (ah + bh) + ch;
}

// =====================================================================
// E[k,c] builder + (blocks >= 384) zero asq accumulator
__global__ __launch_bounds__(256) void build_ET_k(const float* __restrict__ Wp,
                                                  const float* __restrict__ se,
                                                  float* __restrict__ ET,
                                                  float* __restrict__ asq) {
  if (blockIdx.x >= 384) {
    int z = (blockIdx.x - 384) * 256 + threadIdx.x;
    if (z < B_ * KT_) asq[z] = 0.f;
    return;
  }
  int idx = blockIdx.x * 256 + threadIdx.x;
  if (idx >= C_ * KP_) return;
  int c = idx / KP_;
  int k = idx % KP_;
  float acc = 0.f;
  if (k < K_) {
    for (int d = 0; d < C_; d++) acc = fmaf(se[k * C_ + d], Wp[d * C_ + c], acc);
  }
  ET[idx] = acc;
}

// =====================================================================
// FUSED kernel, 512 threads/block:
//   blocks 0..3      : FPS (one per batch) -> anchors
//   blocks 4..1027   : semantic GEMM -> Lsem into A region
//   blocks 1028..1091: ext features
//   blocks 1092..1347: sT bf16 builder
__global__ __launch_bounds__(512, 1) void fused_k(const float* __restrict__ s,
    const float* __restrict__ mu, const float* __restrict__ Sigma,
    const float* __restrict__ mask, const float* __restrict__ ET,
    float* __restrict__ anchors, float* __restrict__ ext,
    float* __restrict__ A, unsigned short* __restrict__ sT) {
  const int bid = blockIdx.x;
  const int tid = threadIdx.x;

  __shared__ __align__(16) float s_lds[32][132];
  __shared__ __align__(16) float et_lds[8][KP_];
  __shared__ __align__(16) float muL[N_ * 3];
  __shared__ __align__(16) float Tt[64][72];
  __shared__ double redd[8][4];
  __shared__ unsigned long long redk[2][8];
  __shared__ float an_s[4];

  if (bid >= 1092) {
    const int sb = bid - 1092;
    const int b = sb >> 6;
    const int rest = sb & 63;
    const int chalf = rest >> 5;
    const int ns = rest & 31;
    const int c0 = chalf * 64, n0 = ns * 256;
#pragma unroll
    for (int t2 = 0; t2 < 4; t2++) {
      const int nb = n0 + t2 * 64;
      {
        int n_loc = tid >> 3;
        int cb = (tid & 7) * 8;
        const float* sp = s + ((size_t)(b * N_ + nb + n_loc)) * C_ + c0 + cb;
        float4 v0 = *(const float4*)(sp);
        float4 v1 = *(const float4*)(sp + 4);
        Tt[cb + 0][n_loc] = v0.x; Tt[cb + 1][n_loc] = v0.y;
        Tt[cb + 2][n_loc] = v0.z; Tt[cb + 3][n_loc] = v0.w;
        Tt[cb + 4][n_loc] = v1.x; Tt[cb + 5][n_loc] = v1.y;
        Tt[cb + 6][n_loc] = v1.z; Tt[cb + 7][n_loc] = v1.w;
      }
      __syncthreads();
      {
        int row = tid >> 3;
        int qo = tid & 7;
        float4 f0 = *(const float4*)(&Tt[row][qo * 8]);
        float4 f1 = *(const float4*)(&Tt[row][qo * 8 + 4]);
        unsigned short o[8];
        o[0] = f2bf_rne(f0.x); o[1] = f2bf_rne(f0.y); o[2] = f2bf_rne(f0.z); o[3] = f2bf_rne(f0.w);
        o[4] = f2bf_rne(f1.x); o[5] = f2bf_rne(f1.y); o[6] = f2bf_rne(f1.z); o[7] = f2bf_rne(f1.w);
        unsigned short* dst = sT + ((size_t)(b * C_ + c0 + row)) * N_ + nb + qo * 8;
        *(uint4*)dst = *(uint4*)o;
      }
      __syncthreads();
    }
    return;
  }

  if (bid >= 1028) {
    int idx = (bid - 1028) * 512 + tid;
    if (idx < B_ * N_) {
      float x = mu[(size_t)idx * 3 + 0];
      float y = mu[(size_t)idx * 3 + 1];
      float z = mu[(size_t)idx * 3 + 2];
      const float* S = Sigma + (size_t)idx * 9;
      float* e = ext + (size_t)idx * 16;
      e[0] = x; e[1] = y; e[2] = z;
      e[3] = x * x; e[4] = x * y; e[5] = x * z;
      e[6] = y * y; e[7] = y * z; e[8] = z * z;
      e[9] = S[0]; e[10] = S[1]; e[11] = S[2]; e[12] = S[4]; e[13] = S[5]; e[14] = S[8];
      e[15] = 1.f;
    }
    return;
  }

  if (bid >= 4) {
    const int gb = bid - 4;
    const int b = gb >> 8;
    const int n0 = (gb & 255) * 32;
    const int nt = tid >> 6;
    const int kt = tid & 63;
    {
      const float* sb = s + ((size_t)(b * N_ + n0)) * C_;
      int r = tid >> 4;
      int cb = (tid & 15) * 8;
#pragma unroll
      for (int q = 0; q < 2; q++) {
        float4 v = *(const float4*)(sb + (size_t)r * C_ + cb + q * 4);
        *(float4*)(&s_lds[r][cb + q * 4]) = v;
      }
    }
    float acc[4][12];
#pragma unroll
    for (int i = 0; i < 4; i++)
#pragma unroll
      for (int j = 0; j < 12; j++) acc[i][j] = 0.f;

    for (int cc = 0; cc < 16; cc++) {
      __syncthreads();
#pragma unroll
      for (int q = 0; q < 3; q++) {
        int fid = q * 512 + tid;
        int cl = fid / 192;
        int o4 = fid % 192;
        *(float4*)(&et_lds[cl][o4 * 4]) = *(const float4*)(ET + (size_t)(cc * 8 + cl) * KP_ + o4 * 4);
      }
      __syncthreads();
#pragma unroll
      for (int c8 = 0; c8 < 8; c8++) {
        int c = cc * 8 + c8;
        float sv0 = s_lds[nt * 4 + 0][c];
        float sv1 = s_lds[nt * 4 + 1][c];
        float sv2 = s_lds[nt * 4 + 2][c];
        float sv3 = s_lds[nt * 4 + 3][c];
#pragma unroll
        for (int j = 0; j < 12; j++) {
          float ev = et_lds[c8][kt + 64 * j];
          acc[0][j] = fmaf(sv0, ev, acc[0][j]);
          acc[1][j] = fmaf(sv1, ev, acc[1][j]);
          acc[2][j] = fmaf(sv2, ev, acc[2][j]);
          acc[3][j] = fmaf(sv3, ev, acc[3][j]);
        }
      }
    }
#pragma unroll
    for (int i = 0; i < 4; i++) {
      float* Arow = A + ((size_t)(b * N_ + n0 + nt * 4 + i)) * K_;
#pragma unroll
      for (int j = 0; j < 12; j++) {
        int k = kt + 64 * j;
        if (k < K_) Arow[k] = acc[i][j];
      }
    }
    return;
  }

  // ---------------- FPS (R7 semantics, packed-pair update) ----------------
  const int b = bid;
  const int t = tid;
  const int wv = t >> 6;
  const float* mub = mu + (size_t)b * N_ * 3;
  const float* mkb = mask + (size_t)b * N_;
  float2 px2[8], py2[8], pz2[8], md2[8];
  float* px_f = (float*)px2;
  float* py_f = (float*)py2;
  float* pz_f = (float*)pz2;
  float* md_f = (float*)md2;

  double sx = 0, sy = 0, sz = 0, sc = 0;
#pragma unroll
  for (int i = 0; i < 16; i++) {
    int p = i * 512 + t;
    float x = mub[p * 3 + 0], y = mub[p * 3 + 1], z = mub[p * 3 + 2];
    px_f[i] = x; py_f[i] = y; pz_f[i] = z;
    muL[p * 3 + 0] = x; muL[p * 3 + 1] = y; muL[p * 3 + 2] = z;
    float mk = mkb[p];
    bool valid = (mk > 0.5f);
    md_f[i] = valid ? 3.4e38f : -1.f;
    if (valid) { sx += x; sy += y; sz += z; sc += 1.0; }
  }
  for (int off = 32; off; off >>= 1) {
    sx += __shfl_xor(sx, off);
    sy += __shfl_xor(sy, off);
    sz += __shfl_xor(sz, off);
    sc += __shfl_xor(sc, off);
  }
  if ((t & 63) == 0) { redd[wv][0] = sx; redd[wv][1] = sy; redd[wv][2] = sz; redd[wv][3] = sc; }
  __syncthreads();
  if (t == 0) {
    double ax0 = 0, ay0 = 0, az0 = 0, ac = 0;
    for (int w = 0; w < 8; w++) { ax0 += redd[w][0]; ay0 += redd[w][1]; az0 += redd[w][2]; ac += redd[w][3]; }
    if (ac < 1.0) ac = 1.0;
    an_s[0] = (float)(ax0 / ac); an_s[1] = (float)(ay0 / ac); an_s[2] = (float)(az0 / ac);
  }
  __syncthreads();

  float ax, ay, az;
  // -------- first anchor: argmax of masked d2-from-mean --------
  {
    float cx = an_s[0], cy = an_s[1], cz = an_s[2];
    float bv = -2.f, bv2 = -2.f;
    int bi = 0, bi2 = 0;
#pragma unroll
    for (int j = 0; j < 8; j++) {
      float dl, dh;
      d2pair(px2[j], py2[j], pz2[j], cx, cy, cz, dl, dh);
      float vl = (md2[j].x < 0.f) ? -1.f : dl;
      float vh = (md2[j].y < 0.f) ? -1.f : dh;
      int pl = (2 * j) * 512 + t;
      int ph = (2 * j + 1) * 512 + t;
      if (vl > bv)  { bv = vl;  bi = pl; }
      if (vh > bv2) { bv2 = vh; bi2 = ph; }
    }
    if (bv2 > bv || (bv2 == bv && bi2 < bi)) { bv = bv2; bi = bi2; }
    unsigned long long k0 = ((unsigned long long)f2ord(bv) << 32) | (unsigned int)(~bi);
    for (int off = 32; off; off >>= 1) {
      unsigned long long ok = __shfl_xor(k0, off);
      if (ok > k0) k0 = ok;
    }
    if ((t & 63) == 0) redk[0][wv] = k0;
    __syncthreads();
    unsigned long long a0 = redk[0][0], a1 = redk[0][1], a2 = redk[0][2], a3 = redk[0][3];
    unsigned long long a4 = redk[0][4], a5 = redk[0][5], a6 = redk[0][6], a7 = redk[0][7];
    unsigned long long bk = umax64(umax64(umax64(a0, a1), umax64(a2, a3)),
                                  umax64(umax64(a4, a5), umax64(a6, a7)));
    int besti = (int)(~(unsigned int)bk);
    ax = muL[besti * 3 + 0]; ay = muL[besti * 3 + 1]; az = muL[besti * 3 + 2];
    if (t == 0) {
      float aa = ax * ax + ay * ay + az * az;
      float4 st = {ax, ay, az, aa};
      *(float4*)(anchors + ((size_t)b * KP_ + 0) * 4) = st;
    }
  }

  // -------- main loop: one barrier per iteration --------
  for (int k = 1; k < K_; k++) {
    const int par = k & 1;
    float bv = -2.f, bv2 = -2.f;
    int bi = 0, bi2 = 0;
#pragma unroll
    for (int j = 0; j < 8; j++) {
      float dl, dh;
      d2pair(px2[j], py2[j], pz2[j], ax, ay, az, dl, dh);
      float ml = fminf(md2[j].x, dl);
      float mh = fminf(md2[j].y, dh);
      md2[j].x = ml; md2[j].y = mh;
      int pl = (2 * j) * 512 + t;
      int ph = (2 * j + 1) * 512 + t;
      if (ml > bv)  { bv = ml;  bi = pl; }
      if (mh > bv2) { bv2 = mh; bi2 = ph; }
    }
    if (bv2 > bv || (bv2 == bv && bi2 < bi)) { bv = bv2; bi = bi2; }
    unsigned long long kk = ((unsigned long long)f2ord(bv) << 32) | (unsigned int)(~bi);
    for (int off = 32; off; off >>= 1) {
      unsigned long long ok = __shfl_xor(kk, off);
      if (ok > kk) kk = ok;
    }
    if ((t & 63) == 0) redk[par][wv] = kk;
    __syncthreads();
    unsigned long long a0 = redk[par][0], a1 = redk[par][1], a2 = redk[par][2], a3 = redk[par][3];
    unsigned long long a4 = redk[par][4], a5 = redk[par][5], a6 = redk[par][6], a7 = redk[par][7];
    unsigned long long bk = umax64(umax64(umax64(a0, a1), umax64(a2, a3)),
                                  umax64(umax64(a4, a5), umax64(a6, a7)));
    int besti = (int)(~(unsigned int)bk);
    ax = muL[besti * 3 + 0]; ay = muL[besti * 3 + 1]; az = muL[besti * 3 + 2];
    if (t == 0) {
      float aa = ax * ax + ay * ay + az * az;
      float4 st = {ax, ay, az, aa};
      *(float4*)(anchors + ((size_t)b * KP_ + k) * 4) = st;
    }
  }
  for (int k = K_ + t; k < KP_; k += 512) {
    float4 z4 = {0.f, 0.f, 0.f, 0.f};
    *(float4*)(anchors + ((size_t)b * KP_ + k) * 4) = z4;
  }
}

// =====================================================================
// FUSED postA: softmax (bit-identical) + bf16 transpose to At + per-k
// sum(A^2) block partials -> atomicAdd into asq_ws.
__global__ __launch_bounds__(256) void postA_k(
    const float* __restrict__ mu, const float* __restrict__ mask,
    const float* __restrict__ anchors, const float* __restrict__ lsm_p,
    const float* __restrict__ wsem_p, const float* __restrict__ wmu_p,
    float* __restrict__ A, unsigned short* __restrict__ At,
    float* __restrict__ asq_ws) {
  const int bid = blockIdx.x;
  const int b = bid >> 8;
  const int n0 = (bid & 255) * 32;
  const int tid = threadIdx.x;
  const int wv = tid >> 6;
  const int lane = tid & 63;
  __shared__ __align__(16) float anch_lds[KP_][4];   // reused as asq red buffer
  __shared__ __align__(16) unsigned short T[KP_][40];

  for (int q = tid; q < KP_; q += 256)
    *(float4*)(&anch_lds[q][0]) = *(const float4*)(anchors + ((size_t)b * KP_ + q) * 4);
  __syncthreads();

  const float sg = fmaxf(expf(lsm_p[0]), 1e-4f);
  const float inv2s2 = 0.5f / (sg * sg);
  const float wsem = wsem_p[0];
  const float wmu = wmu_p[0];

  float pq[11];
#pragma unroll
  for (int j = 0; j < 11; j++) pq[j] = 0.f;

#pragma unroll
  for (int g = 0; g < 2; g++) {
    const int r0 = wv * 8 + g * 4;
    unsigned short tpack[12][4];
#pragma unroll
    for (int rr = 0; rr < 4; rr++) {
      const size_t gr = (size_t)b * N_ + n0 + r0 + rr;
      const float* mp = mu + gr * 3;
      float x = mp[0], y = mp[1], z = mp[2];
      float mq = x * x + y * y + z * z;
      float mk = mask[gr];
      float* Arow = A + gr * K_;

      float v[11];
      float m = -3e38f;
#pragma unroll
      for (int j = 0; j < 11; j++) {
        int k = lane + 64 * j;
        if (k < K_) {
          float lsem = Arow[k];
          float4 a4 = *(const float4*)(&anch_lds[k][0]);
          float tdot = x * a4.x + y * a4.y + z * a4.z;
          float d2 = mq - 2.f * tdot + a4.w;
          float l = wsem * lsem - wmu * d2 * inv2s2;
          if (mk < 0.5f) l = -1e9f;
          v[j] = l;
        } else v[j] = -1e30f;
        m = fmaxf(m, v[j]);
      }
      for (int off = 32; off; off >>= 1) m = fmaxf(m, __shfl_xor(m, off));
      float sum = 0.f;
#pragma unroll
      for (int j = 0; j < 11; j++) { float e = expf(v[j] - m); v[j] = e; sum += e; }
      for (int off = 32; off; off >>= 1) sum += __shfl_xor(sum, off);
      float r = mk / sum;
#pragma unroll
      for (int j = 0; j < 11; j++) {
        int k = lane + 64 * j;
        float av = v[j] * r;
        if (k < K_) {
          Arow[k] = av;
          tpack[j][rr] = f2bf_rne(av);
          pq[j] = fmaf(av, av, pq[j]);
        } else tpack[j][rr] = 0;
      }
      tpack[11][rr] = 0;
    }
#pragma unroll
    for (int j = 0; j < 12; j++) {
      int k = lane + 64 * j;
      *(unsigned long long*)(&T[k][r0]) = *(const unsigned long long*)(&tpack[j][0]);
    }
  }
  __syncthreads();
  // reuse anch_lds as red[4][704]
  float* redp = &anch_lds[0][0];
#pragma unroll
  for (int j = 0; j < 11; j++) redp[wv * 704 + lane + 64 * j] = pq[j];
  // At readout: 3 k-rows per thread, 64B each
#pragma unroll
  for (int kq = 0; kq < 3; kq++) {
    int k = tid + 256 * kq;
    const uint4* src = (const uint4*)(&T[k][0]);
    unsigned short* dst = At + ((size_t)(b * KP_ + k)) * N_ + n0;
#pragma unroll
    for (int q = 0; q < 4; q++) *(uint4*)(dst + q * 8) = src[q];
  }
  __syncthreads();
  for (int k2 = tid; k2 < K_; k2 += 256) {
    float tot = redp[k2] + redp[704 + k2] + redp[1408 + k2] + redp[2112 + k2];
    atomicAdd(&asq_ws[b * KT_ + k2], tot);
  }
}

// =====================================================================
// COMBINED tail: blocks 0..83 gram+loss, 84..131 s-moment MFMA, 132..483 ext.
__global__ __launch_bounds__(256) void tail_k(const unsigned short* __restrict__ At,
    const unsigned short* __restrict__ sT, const float* __restrict__ A,
    const float* __restrict__ ext, const float* __restrict__ asq_ws,
    float* __restrict__ mpart, float* __restrict__ epart, float* __restrict__ lossp) {
  __shared__ __align__(16) char arena[38912];
  const int bid = blockIdx.x;
  const int tid = threadIdx.x;

  if (bid < 84) {
    // ---------------- gram + fused loss ----------------
    const int b = bid / 21;
    int p = bid % 21;
    int tk = 0, tl = 0;
    { int pp = p; for (int r0 = 0; r0 < 6; r0++) { int cnt = 6 - r0; if (pp < cnt) { tk = r0; tl = r0 + pp; break; } pp -= cnt; } }
    const int k0 = tk * 128, l0 = tl * 128;
    const int l = tid & 63;
    const int w = tid >> 6;
    const int wr = w >> 1, wc = w & 1;

    unsigned short* Ak_lds = (unsigned short*)arena;
    unsigned short* Al_lds = (unsigned short*)(arena + 18432);
    float* nk_s = (float*)(arena + 36864);
    float* nl_s = (float*)(arena + 37376);
    float* red_s = (float*)(arena + 37888);

    if (tid < 128) {
      int kk = k0 + tid;
      nk_s[tid] = (kk < K_) ? fmaxf(sqrtf(asq_ws[b * KT_ + kk]), 1e-8f) : 1.f;
    } else {
      int ll2 = l0 + tid - 128;
      nl_s[tid - 128] = (ll2 < K_) ? fmaxf(sqrtf(asq_ws[b * KT_ + ll2]), 1e-8f) : 1.f;
    }

    f32x4 acc[4][4];
#pragma unroll
    for (int i = 0; i < 4; i++)
#pragma unroll
      for (int j = 0; j < 4; j++) acc[i][j] = (f32x4){0.f, 0.f, 0.f, 0.f};

    const unsigned short* gk = At + ((size_t)(b * KP_ + k0)) * N_;
    const unsigned short* gl = At + ((size_t)(b * KP_ + l0)) * N_;

    for (int ch = 0; ch < 128; ch++) {
      const int n0 = ch * 64;
      __syncthreads();
#pragma unroll
      for (int q = 0; q < 4; q++) {
        int chunk = tid + 256 * q;
        int row = chunk >> 3, slot = chunk & 7;
        uint4 v = *(const uint4*)(gk + (size_t)row * N_ + n0 + slot * 8);
        *(uint4*)(Ak_lds + row * 72 + slot * 8) = v;
        uint4 v2 = *(const uint4*)(gl + (size_t)row * N_ + n0 + slot * 8);
        *(uint4*)(Al_lds + row * 72 + slot * 8) = v2;
      }
      __syncthreads();
#pragma unroll
      for (int ks = 0; ks < 2; ks++) {
        const int noff = (l >> 4) * 8 + ks * 32;
        bf16x8s af[4], bfr[4];
#pragma unroll
        for (int f = 0; f < 4; f++) {
          af[f]  = *(const bf16x8s*)(Ak_lds + (wr * 64 + f * 16 + (l & 15)) * 72 + noff);
          bfr[f] = *(const bf16x8s*)(Al_lds + (wc * 64 + f * 16 + (l & 15)) * 72 + noff);
        }
#pragma unroll
        for (int i = 0; i < 4; i++)
#pragma unroll
          for (int j = 0; j < 4; j++)
            acc[i][j] = __builtin_amdgcn_mfma_f32_16x16x32_bf16(af[i], bfr[j], acc[i][j], 0, 0, 0);
      }
    }

    float local = 0.f;
    const float wgt = (tk == tl) ? 1.f : 2.f;
#pragma unroll
    for (int i = 0; i < 4; i++) {
#pragma unroll
      for (int j = 0; j < 4; j++) {
#pragma unroll
        for (int r = 0; r < 4; r++) {
          int ki = wr * 64 + i * 16 + (l >> 4) * 4 + r;
          int li = wc * 64 + j * 16 + (l & 15);
          int gkk = k0 + ki, gll = l0 + li;
          if (gkk < K_ && gll < K_ && gkk != gll) {
            float g = acc[i][j][r];
            float x = g / (nk_s[ki] * nl_s[li]);
            local = fmaf(wgt * x, x, local);
          }
        }
      }
    }
    for (int off = 32; off; off >>= 1) local += __shfl_xor(local, off);
    if ((tid & 63) == 0) red_s[w] = local;
    __syncthreads();
    if (tid == 0) lossp[bid] = red_s[0] + red_s[1] + red_s[2] + red_s[3];
    return;
  }

  if (bid < 132) {
    // ---------------- s-moment MFMA ----------------
    const int bid2 = bid - 84;
    const int np = bid2 / 24;
    const int rem = bid2 % 24;
    const int b = rem / 6;
    const int kt2 = rem % 6;
    const int k0 = kt2 * 128;
    const int l = tid & 63;
    const int w = tid >> 6;
    const int wr = w >> 1, wc = w & 1;

    unsigned short* Ak_lds = (unsigned short*)arena;
    unsigned short* Bc_lds = (unsigned short*)(arena + 18432);

    f32x4 acc[4][4];
#pragma unroll
    for (int i = 0; i < 4; i++)
#pragma unroll
      for (int j = 0; j < 4; j++) acc[i][j] = (f32x4){0.f, 0.f, 0.f, 0.f};

    const unsigned short* gk = At + ((size_t)(b * KP_ + k0)) * N_;
    const unsigned short* gc = sT + ((size_t)(b * C_)) * N_;
    const int nbase = np * 4096;

    for (int ch = 0; ch < 64; ch++) {
      const int n0 = nbase + ch * 64;
      __syncthreads();
#pragma unroll
      for (int q = 0; q < 4; q++) {
        int chunk = tid + 256 * q;
        int row = chunk >> 3, slot = chunk & 7;
        uint4 v = *(const uint4*)(gk + (size_t)row * N_ + n0 + slot * 8);
        *(uint4*)(Ak_lds + row * 72 + slot * 8) = v;
        uint4 v2 = *(const uint4*)(gc + (size_t)row * N_ + n0 + slot * 8);
        *(uint4*)(Bc_lds + row * 72 + slot * 8) = v2;
      }
      __syncthreads();
#pragma unroll
      for (int ks = 0; ks < 2; ks++) {
        const int noff = (l >> 4) * 8 + ks * 32;
        bf16x8s af[4], bfr[4];
#pragma unroll
        for (int f = 0; f < 4; f++) {
          af[f]  = *(const bf16x8s*)(Ak_lds + (wr * 64 + f * 16 + (l & 15)) * 72 + noff);
          bfr[f] = *(const bf16x8s*)(Bc_lds + (wc * 64 + f * 16 + (l & 15)) * 72 + noff);
        }
#pragma unroll
        for (int i = 0; i < 4; i++)
#pragma unroll
          for (int j = 0; j < 4; j++)
            acc[i][j] = __builtin_amdgcn_mfma_f32_16x16x32_bf16(af[i], bfr[j], acc[i][j], 0, 0, 0);
      }
    }
    float* mp = mpart + ((size_t)((np * 4 + b) * KP_ + k0)) * C_;
#pragma unroll
    for (int i = 0; i < 4; i++) {
#pragma unroll
      for (int j = 0; j < 4; j++) {
#pragma unroll
        for (int r = 0; r < 4; r++) {
          int ki = wr * 64 + i * 16 + (l >> 4) * 4 + r;
          int ci = wc * 64 + j * 16 + (l & 15);
          mp[(size_t)ki * C_ + ci] = acc[i][j][r];
        }
      }
    }
    return;
  }

  // ---------------- fp32 ext moments ----------------
  {
    const int bid3 = bid - 132;
    const int np = bid3 / 44;
    const int rem = bid3 % 44;
    const int b = rem / 11;
    const int k0 = (rem % 11) * 64;
    const int n0 = np * 1024;
    const int kt = tid & 15;
    const int ft = tid >> 4;
    float (*A_lds)[64] = (float (*)[64])arena;
    float (*F_lds)[32] = (float (*)[32])(arena + 8192);
    float acc[4][2];
#pragma unroll
    for (int c = 0; c < 4; c++) { acc[c][0] = 0.f; acc[c][1] = 0.f; }

    for (int ch = 0; ch < 32; ch++) {
      int nb = n0 + ch * 32;
      __syncthreads();
#pragma unroll
      for (int p = 0; p < 8; p++) {
        int q = tid + 256 * p; int r = q >> 6; int c = q & 63; int k = k0 + c;
        A_lds[r][c] = (k < K_) ? A[((size_t)(b * N_ + nb + r)) * K_ + k] : 0.f;
      }
#pragma unroll
      for (int p = 0; p < 2; p++) {
        int q = tid + 256 * p; int r = q >> 4; int e = q & 15;
        F_lds[r][e] = ext[((size_t)(b * N_ + nb + r)) * 16 + e];
        F_lds[r][16 + e] = 0.f;
      }
      __syncthreads();
#pragma unroll
      for (int i = 0; i < 32; i++) {
        float a0 = A_lds[i][kt * 4 + 0];
        float a1 = A_lds[i][kt * 4 + 1];
        float a2 = A_lds[i][kt * 4 + 2];
        float a3 = A_lds[i][kt * 4 + 3];
#pragma unroll
        for (int f = 0; f < 2; f++) {
          float fv = F_lds[i][ft * 2 + f];
          acc[0][f] = fmaf(a0, fv, acc[0][f]);
          acc[1][f] = fmaf(a1, fv, acc[1][f]);
          acc[2][f] = fmaf(a2, fv, acc[2][f]);
          acc[3][f] = fmaf(a3, fv, acc[3][f]);
        }
      }
    }
#pragma unroll
    for (int c = 0; c < 4; c++) {
      size_t base = ((size_t)((np * 4 + b) * KT_ + k0 + kt * 4 + c)) * 32;
#pragma unroll
      for (int f = 0; f < 2; f++) {
        int fidx = ft * 2 + f;
        if (fidx < 16) epart[base + fidx] = acc[c][f];
      }
    }
  }
}

// =====================================================================
// Postprocess (MFMA path): one wave per (b,k). sumA from ext ones-column.
__global__ __launch_bounds__(256) void postproc2_k(const float* __restrict__ mpart,
    const float* __restrict__ epart, float* __restrict__ out,
    float* __restrict__ sumA_ws) {
  const int gw = blockIdx.x * 4 + (threadIdx.x >> 6);
  const int lane = threadIdx.x & 63;
  const int b = gw / K_;
  const int k = gw % K_;
  float v0 = 0.f, v1 = 0.f, v2 = 0.f;
#pragma unroll
  for (int np = 0; np < 2; np++) {
    const float* r = mpart + ((size_t)((np * 4 + b) * KP_ + k)) * C_;
    v0 += r[lane];
    v1 += r[64 + lane];
  }
#pragma unroll
  for (int np = 0; np < 8; np++) {
    const float* e = epart + ((size_t)((np * 4 + b) * KT_ + k)) * 32;
    if (lane < 16) v2 += e[lane];
  }
  float sumA = __shfl(v2, 15);
  float denom = fmaxf(sumA, 1e-8f);
  float inv = 1.f / denom;
  out[OUT_SC + ((size_t)(b * K_ + k)) * C_ + lane] = v0 * inv;
  out[OUT_SC + ((size_t)(b * K_ + k)) * C_ + 64 + lane] = v1 * inv;
  float m0 = __shfl(v2, 0) * inv;
  float m1 = __shfl(v2, 1) * inv;
  float m2 = __shfl(v2, 2) * inv;
  if (lane < 3) out[OUT_MUC + ((size_t)(b * K_ + k)) * 3 + lane] = (lane == 0) ? m0 : ((lane == 1) ? m1 : m2);
  float W = sumA * inv;
  float fac = 2.f - W;
  float M2s[6], Sgs[6];
#pragma unroll
  for (int j = 0; j < 6; j++) { M2s[j] = __shfl(v2, 3 + j); Sgs[j] = __shfl(v2, 9 + j); }
  if (lane < 9) {
    int d = lane / 3, e = lane % 3;
    int lo = min(d, e), hi = max(d, e);
    int j = hi + 2 * lo - ((lo * (lo - 1)) >> 1);
    float mud = (d == 0) ? m0 : ((d == 1) ? m1 : m2);
    float mue = (e == 0) ? m0 : ((e == 1) ? m1 : m2);
    float M2j = (j == 0) ? M2s[0] : (j == 1) ? M2s[1] : (j == 2) ? M2s[2] : (j == 3) ? M2s[3] : (j == 4) ? M2s[4] : M2s[5];
    float Sgj = (j == 0) ? Sgs[0] : (j == 1) ? Sgs[1] : (j == 2) ? Sgs[2] : (j == 3) ? Sgs[3] : (j == 4) ? Sgs[4] : Sgs[5];
    float val = (Sgj + M2j) * inv - mud * mue * fac;
    if (d == e) val += 1e-6f;
    out[OUT_SGC + ((size_t)(b * K_ + k)) * 9 + lane] = val;
  }
  if (lane == 0) sumA_ws[b * KT_ + k] = sumA;
}

// final for the MFMA path: 84 tile partials
__global__ __launch_bounds__(256) void final2_k(const float* __restrict__ sumA_ws,
    const float* __restrict__ lossp, float* __restrict__ out) {
  const int lane = threadIdx.x & 63;
  const int wv = threadIdx.x >> 6;
  __shared__ float occ_s[4];
  __shared__ float col_s[4];
  float sb = 0.f;
  for (int k = lane; k < K_; k += 64) sb += sumA_ws[wv * KT_ + k];
  for (int off = 32; off; off >>= 1) sb += __shfl_xor(sb, off);
  float Sb = fmaxf(sb, 1e-8f);
  float lo = 0.f;
  const float tgt = 1.f / (float)K_;
  for (int k = lane; k < K_; k += 64) {
    float o = sumA_ws[wv * KT_ + k] / Sb - tgt;
    lo = fmaf(o, o, lo);
  }
  for (int off = 32; off; off >>= 1) lo += __shfl_xor(lo, off);
  if (lane == 0) occ_s[wv] = lo;
  float c = 0.f;
  for (int i = threadIdx.x; i < 84; i += 256) c += lossp[i];
  for (int off = 32; off; off >>= 1) c += __shfl_xor(c, off);
  if (lane == 0) col_s[wv] = c;
  __syncthreads();
  if (threadIdx.x == 0) {
    float loss_occ = (occ_s[0] + occ_s[1] + occ_s[2] + occ_s[3]) / (float)(B_ * K_);
    float coll = (col_s[0] + col_s[1] + col_s[2] + col_s[3]) / ((float)B_ * K_ * K_);
    out[OUT_TOT] = loss_occ + 0.1f * coll;
  }
}

// =====================================================================
// ---- fallback path kernels (ws too small) ----
__global__ __launch_bounds__(256) void spatial_softmax_k(
    const float* __restrict__ mu, const float* __restrict__ mask,
    const float* __restrict__ anchors, const float* __restrict__ lsm_p,
    const float* __restrict__ wsem_p, const float* __restrict__ wmu_p,
    float* __restrict__ A) {
  const int bid = blockIdx.x;
  const int b = bid >> 11;
  const int n0 = (bid & 2047) * 4;
  const int tid = threadIdx.x;
  const int wv = tid >> 6;
  const int lane = tid & 63;
  __shared__ __align__(16) float anch_lds[KP_][4];
  for (int q = tid; q < KP_; q += 256)
    *(float4*)(&anch_lds[q][0]) = *(const float4*)(anchors + ((size_t)b * KP_ + q) * 4);
  __syncthreads();
  const float sg = fmaxf(expf(lsm_p[0]), 1e-4f);
  const float inv2s2 = 0.5f / (sg * sg);
  const float wsem = wsem_p[0];
  const float wmu = wmu_p[0];
  const size_t gr = (size_t)b * N_ + n0 + wv;
  const float* mp = mu + gr * 3;
  float x = mp[0], y = mp[1], z = mp[2];
  float mq = x * x + y * y + z * z;
  float mk = mask[gr];
  float* Arow = A + gr * K_;
  float v[11];
  float m = -3e38f;
#pragma unroll
  for (int j = 0; j < 11; j++) {
    int k = lane + 64 * j;
    if (k < K_) {
      float lsem = Arow[k];
      float4 a4 = *(const float4*)(&anch_lds[k][0]);
      float tdot = x * a4.x + y * a4.y + z * a4.z;
      float d2 = mq - 2.f * tdot + a4.w;
      float l = wsem * lsem - wmu * d2 * inv2s2;
      if (mk < 0.5f) l = -1e9f;
      v[j] = l;
    } else v[j] = -1e30f;
    m = fmaxf(m, v[j]);
  }
  for (int off = 32; off; off >>= 1) m = fmaxf(m, __shfl_xor(m, off));
  float sum = 0.f;
#pragma unroll
  for (int j = 0; j < 11; j++) { float e = expf(v[j] - m); v[j] = e; sum += e; }
  for (int off = 32; off; off >>= 1) sum += __shfl_xor(sum, off);
  float r = mk / sum;
#pragma unroll
  for (int j = 0; j < 11; j++) {
    int k = lane + 64 * j;
    if (k < K_) Arow[k] = v[j] * r;
  }
}

__global__ __launch_bounds__(256) void gemm2_k(const float* __restrict__ A,
    const float* __restrict__ s, const float* __restrict__ ext,
    float* __restrict__ part) {
  const int bid = blockIdx.x;
  const int np = bid / 44;
  const int rem = bid % 44;
  const int b = rem / 11;
  const int k0 = (rem % 11) * 64;
  const int n0 = np * 1024;
  const int tid = threadIdx.x;
  const int kt = tid & 15;
  const int ft = tid >> 4;
  __shared__ __align__(16) float A_lds[32][64];
  __shared__ __align__(16) float F_lds[32][160];
  float acc[4][10];
#pragma unroll
  for (int c = 0; c < 4; c++)
#pragma unroll
    for (int f = 0; f < 10; f++) acc[c][f] = 0.f;
  float asq[4] = {0.f, 0.f, 0.f, 0.f};
  for (int ch = 0; ch < 32; ch++) {
    int nb = n0 + ch * 32;
    __syncthreads();
#pragma unroll
    for (int p = 0; p < 8; p++) {
      int q = tid + 256 * p; int r = q >> 6; int c = q & 63; int k = k0 + c;
      A_lds[r][c] = (k < K_) ? A[((size_t)(b * N_ + nb + r)) * K_ + k] : 0.f;
    }
#pragma unroll
    for (int p = 0; p < 16; p++) {
      int q = tid + 256 * p; int r = q >> 7; int c = q & 127;
      F_lds[r][c] = s[((size_t)(b * N_ + nb + r)) * C_ + c];
    }
#pragma unroll
    for (int p = 0; p < 2; p++) {
      int q = tid + 256 * p; int r = q >> 4; int e = q & 15;
      F_lds[r][128 + e] = ext[((size_t)(b * N_ + nb + r)) * 16 + e];
      F_lds[r][144 + e] = 0.f;
    }
    __syncthreads();
#pragma unroll
    for (int i = 0; i < 32; i++) {
      float a0 = A_lds[i][kt * 4 + 0];
      float a1 = A_lds[i][kt * 4 + 1];
      float a2 = A_lds[i][kt * 4 + 2];
      float a3 = A_lds[i][kt * 4 + 3];
      if (ft == 0) {
        asq[0] = fmaf(a0, a0, asq[0]); asq[1] = fmaf(a1, a1, asq[1]);
        asq[2] = fmaf(a2, a2, asq[2]); asq[3] = fmaf(a3, a3, asq[3]);
      }
#pragma unroll
      for (int f = 0; f < 10; f++) {
        float fv = F_lds[i][ft * 10 + f];
        acc[0][f] = fmaf(a0, fv, acc[0][f]);
        acc[1][f] = fmaf(a1, fv, acc[1][f]);
        acc[2][f] = fmaf(a2, fv, acc[2][f]);
        acc[3][f] = fmaf(a3, fv, acc[3][f]);
      }
    }
  }
#pragma unroll
  for (int c = 0; c < 4; c++) {
    size_t base = ((size_t)((np * 4 + b) * KT_ + k0 + kt * 4 + c)) * 168;
#pragma unroll
    for (int f = 0; f < 10; f++) part[base + ft * 10 + f] = acc[c][f];
    if (ft == 0) part[base + 160] = asq[c];
  }
}

__global__ __launch_bounds__(256) void postproc_k(const float* __restrict__ part,
    float* __restrict__ out, float* __restrict__ sumA_ws, float* __restrict__ norm_ws) {
  const int gw = blockIdx.x * 4 + (threadIdx.x >> 6);
  const int lane = threadIdx.x & 63;
  const int b = gw / K_;
  const int k = gw % K_;
  float v0 = 0.f, v1 = 0.f, v2 = 0.f, v3 = 0.f;
  for (int np = 0; np < 8; np++) {
    const float* r = part + ((size_t)((np * 4 + b) * KT_ + k)) * 168;
    v0 += r[lane];
    v1 += r[64 + lane];
    if (lane < 16) v2 += r[128 + lane];
    if (lane == 0) v3 += r[160];
  }
  float sumA = __shfl(v2, 15);
  float asq = __shfl(v3, 0);
  float denom = fmaxf(sumA, 1e-8f);
  float inv = 1.f / denom;
  out[OUT_SC + ((size_t)(b * K_ + k)) * C_ + lane] = v0 * inv;
  out[OUT_SC + ((size_t)(b * K_ + k)) * C_ + 64 + lane] = v1 * inv;
  float m0 = __shfl(v2, 0) * inv;
  float m1 = __shfl(v2, 1) * inv;
  float m2 = __shfl(v2, 2) * inv;
  if (lane < 3) out[OUT_MUC + ((size_t)(b * K_ + k)) * 3 + lane] = (lane == 0) ? m0 : ((lane == 1) ? m1 : m2);
  float W = sumA * inv;
  float fac = 2.f - W;
  float M2s[6], Sgs[6];
#pragma unroll
  for (int j = 0; j < 6; j++) { M2s[j] = __shfl(v2, 3 + j); Sgs[j] = __shfl(v2, 9 + j); }
  if (lane < 9) {
    int d = lane / 3, e = lane % 3;
    int lo = min(d, e), hi = max(d, e);
    int j = hi + 2 * lo - ((lo * (lo - 1)) >> 1);
    float mud = (d == 0) ? m0 : ((d == 1) ? m1 : m2);
    float mue = (e == 0) ? m0 : ((e == 1) ? m1 : m2);
    float M2j = (j == 0) ? M2s[0] : (j == 1) ? M2s[1] : (j == 2) ? M2s[2] : (j == 3) ? M2s[3] : (j == 4) ? M2s[4] : M2s[5];
    float Sgj = (j == 0) ? Sgs[0] : (j == 1) ? Sgs[1] : (j == 2) ? Sgs[2] : (j == 3) ? Sgs[3] : (j == 4) ? Sgs[4] : Sgs[5];
    float val = (Sgj + M2j) * inv - mud * mue * fac;
    if (d == e) val += 1e-6f;
    out[OUT_SGC + ((size_t)(b * K_ + k)) * 9 + lane] = val;
  }
  if (lane == 0) { sumA_ws[b * KT_ + k] = sumA; norm_ws[b * KT_ + k] = sqrtf(asq); }
}

__device__ __forceinline__ int swz(int f) { return f ^ (((f >> 5) & 3) << 3); }

__global__ __launch_bounds__(256) void gram_k(const float* __restrict__ A,
                                              float* __restrict__ Gpart) {
  const int bid = blockIdx.x;
  const int np = bid & 1;
  int q = bid >> 1;
  const int b = q / 21;
  int p = q % 21;
  int tk = 0, tl = 0;
  { int pp = p; for (int r0 = 0; r0 < 6; r0++) { int cnt = 6 - r0; if (pp < cnt) { tk = r0; tl = r0 + pp; break; } pp -= cnt; } }
  const int k0 = tk * 128, l0 = tl * 128;
  const int n0 = np * 4096;
  const int tid = threadIdx.x;
  const int ktid = tid & 15, ltid = tid >> 4;
  const bool diag = (tk == tl);
  __shared__ __align__(16) float Ak[32][128];
  __shared__ __align__(16) float Al[32][128];
  float acc[8][8];
#pragma unroll
  for (int i = 0; i < 8; i++)
#pragma unroll
    for (int j = 0; j < 8; j++) acc[i][j] = 0.f;
  const int kb = swz(ktid * 8);
  const int lb = swz(ltid * 8);
  for (int ch = 0; ch < 128; ch++) {
    int nb = n0 + ch * 32;
    __syncthreads();
#pragma unroll
    for (int pq = 0; pq < 16; pq++) {
      int qq = tid + 256 * pq; int r = qq >> 7; int c = qq & 127;
      int kk = k0 + c;
      Ak[r][swz(c)] = (kk < K_) ? A[((size_t)(b * N_ + nb + r)) * K_ + kk] : 0.f;
      if (!diag) {
        int ll = l0 + c;
        Al[r][swz(c)] = (ll < K_) ? A[((size_t)(b * N_ + nb + r)) * K_ + ll] : 0.f;
      }
    }
    __syncthreads();
    const float (*Alp)[128] = diag ? Ak : Al;
#pragma unroll
    for (int i = 0; i < 32; i++) {
      float4 ka = *(const float4*)(&Ak[i][kb]);
      float4 kb4 = *(const float4*)(&Ak[i][kb + 4]);
      float4 la = *(const float4*)(&Alp[i][lb]);
      float4 lb4 = *(const float4*)(&Alp[i][lb + 4]);
      float av[8] = {ka.x, ka.y, ka.z, ka.w, kb4.x, kb4.y, kb4.z, kb4.w};
      float lv[8] = {la.x, la.y, la.z, la.w, lb4.x, lb4.y, lb4.z, lb4.w};
#pragma unroll
      for (int ii = 0; ii < 8; ii++)
#pragma unroll
        for (int jj = 0; jj < 8; jj++)
          acc[ii][jj] = fmaf(av[ii], lv[jj], acc[ii][jj]);
    }
  }
#pragma unroll
  for (int ii = 0; ii < 8; ii++) {
    int kk = k0 + ktid * 8 + ii;
    float* gp = Gpart + ((size_t)((np * 4 + b) * KP_ + kk)) * KP_ + l0 + ltid * 8;
#pragma unroll
    for (int jj = 0; jj < 8; jj++) gp[jj] = acc[ii][jj];
  }
}

__global__ __launch_bounds__(256) void loss_part_k(const float* __restrict__ Gpart,
    const float* __restrict__ norm_ws, float* __restrict__ lossp) {
  const long long total = (long long)B_ * 21 * 16384;
  float local = 0.f;
  for (long long idx = (long long)blockIdx.x * 256 + threadIdx.x; idx < total; idx += (long long)512 * 256) {
    int e = (int)(idx & 16383);
    int rest = (int)(idx >> 14);
    int p = rest % 21;
    int b = rest / 21;
    int tk = 0, tl = 0;
    { int pp = p; for (int r0 = 0; r0 < 6; r0++) { int cnt = 6 - r0; if (pp < cnt) { tk = r0; tl = r0 + pp; break; } pp -= cnt; } }
    int i = e >> 7, j = e & 127;
    int k = tk * 128 + i, l = tl * 128 + j;
    if (k < K_ && l < K_ && k != l) {
      size_t i0 = ((size_t)((0 * 4 + b) * KP_ + k)) * KP_ + l;
      size_t i1 = ((size_t)((1 * 4 + b) * KP_ + k)) * KP_ + l;
      float g = Gpart[i0] + Gpart[i1];
      float nk = fmaxf(norm_ws[b * KT_ + k], 1e-8f);
      float nl2 = fmaxf(norm_ws[b * KT_ + l], 1e-8f);
      float x = g / (nk * nl2);
      float wgt = (tk == tl) ? 1.f : 2.f;
      local = fmaf(wgt * x, x, local);
    }
  }
  __shared__ float red[4];
  for (int off = 32; off; off >>= 1) local += __shfl_xor(local, off);
  if ((threadIdx.x & 63) == 0) red[threadIdx.x >> 6] = local;
  __syncthreads();
  if (threadIdx.x == 0) lossp[blockIdx.x] = red[0] + red[1] + red[2] + red[3];
}

__global__ __launch_bounds__(256) void final_k(const float* __restrict__ sumA_ws,
    const float* __restrict__ lossp, float* __restrict__ out) {
  const int lane = threadIdx.x & 63;
  const int wv = threadIdx.x >> 6;
  __shared__ float occ_s[4];
  __shared__ float col_s[4];
  float sb = 0.f;
  for (int k = lane; k < K_; k += 64) sb += sumA_ws[wv * KT_ + k];
  for (int off = 32; off; off >>= 1) sb += __shfl_xor(sb, off);
  float Sb = fmaxf(sb, 1e-8f);
  float lo = 0.f;
  const float tgt = 1.f / (float)K_;
  for (int k = lane; k < K_; k += 64) {
    float o = sumA_ws[wv * KT_ + k] / Sb - tgt;
    lo = fmaf(o, o, lo);
  }
  for (int off = 32; off; off >>= 1) lo += __shfl_xor(lo, off);
  if (lane == 0) occ_s[wv] = lo;
  float c = lossp[threadIdx.x] + lossp[threadIdx.x + 256];
  for (int off = 32; off; off >>= 1) c += __shfl_xor(c, off);
  if (lane == 0) col_s[wv] = c;
  __syncthreads();
  if (threadIdx.x == 0) {
    float loss_occ = (occ_s[0] + occ_s[1] + occ_s[2] + occ_s[3]) / (float)(B_ * K_);
    float coll = (col_s[0] + col_s[1] + col_s[2] + col_s[3]) / ((float)B_ * K_ * K_);
    out[OUT_TOT] = loss_occ + 0.1f * coll;
  }
}

// =====================================================================
extern "C" void kernel_launch(void* const* d_in, const int* in_sizes, int n_in,
                              void* d_out, int out_size, void* d_ws, size_t ws_size,
                              hipStream_t stream) {
  const float* s = (const float*)d_in[0];
  const float* mu = (const float*)d_in[1];
  const float* Sigma = (const float*)d_in[2];
  const float* mask = (const float*)d_in[3];
  const float* Wp = (const float*)d_in[4];
  const float* se = (const float*)d_in[5];
  const float* lsm = (const float*)d_in[6];
  const float* wsem = (const float*)d_in[7];
  const float* wmu = (const float*)d_in[8];
  float* out = (float*)d_out;
  float* ws = (float*)d_ws;

  float* ET = ws + WS_ET;
  float* anch = ws + WS_ANCH;
  float* ext = ws + WS_EXT;

  const bool use_mfma = ws_size >= (size_t)WS_NEW_END * 4;

  if (use_mfma) {
    float* epart = ws + WS_EPART;
    float* mpart = ws + WS_MPART;
    float* sumA = ws + WS_SUMA;
    float* asq = ws + WS_ASQ;
    float* lossp2 = ws + WS_LOSSP2;
    unsigned short* sT = (unsigned short*)(ws + WS_ST);
    unsigned short* At = (unsigned short*)(ws + WS_AT);

    hipLaunchKernelGGL(build_ET_k, dim3(395), dim3(256), 0, stream, Wp, se, ET, asq);
    hipLaunchKernelGGL(fused_k, dim3(1348), dim3(512), 0, stream, s, mu, Sigma, mask, ET, anch, ext, out, sT);
    hipLaunchKernelGGL(postA_k, dim3(1024), dim3(256), 0, stream, mu, mask, anch, lsm, wsem, wmu, out, At, asq);
    hipLaunchKernelGGL(tail_k, dim3(484), dim3(256), 0, stream, At, sT, out, ext, asq, mpart, epart, lossp2);
    hipLaunchKernelGGL(postproc2_k, dim3(683), dim3(256), 0, stream, mpart, epart, out, sumA);
    hipLaunchKernelGGL(final2_k, dim3(1), dim3(256), 0, stream, sumA, lossp2, out);
  } else {
    float* part = ws + OLD_PART;
    float* sumA = ws + OLD_SUMA;
    float* nrm = ws + OLD_NORM;
    float* Gpart = ws + OLD_GPART;
    float* lossp = ws + OLD_LOSSP;
    unsigned short* sT = (unsigned short*)(ws + WS_ST);

    hipLaunchKernelGGL(build_ET_k, dim3(395), dim3(256), 0, stream, Wp, se, ET, nrm);
    hipLaunchKernelGGL(fused_k, dim3(1348), dim3(512), 0, stream, s, mu, Sigma, mask, ET, anch, ext, out, sT);
    hipLaunchKernelGGL(spatial_softmax_k, dim3(8192), dim3(256), 0, stream, mu, mask, anch, lsm, wsem, wmu, out);
    hipLaunchKernelGGL(gemm2_k, dim3(352), dim3(256), 0, stream, out, s, ext, part);
    hipLaunchKernelGGL(postproc_k, dim3(683), dim3(256), 0, stream, part, out, sumA, nrm);
    hipLaunchKernelGGL(gram_k, dim3(168), dim3(256), 0, stream, out, Gpart);
    hipLaunchKernelGGL(loss_part_k, dim3(512), dim3(256), 0, stream, Gpart, nrm, lossp);
    hipLaunchKernelGGL(final_k, dim3(1), dim3(256), 0, stream, sumA, lossp, out);
  }
}

// Round 12
// 1085.190 us; speedup vs baseline: 1.4508x; 1.0354x over previous
//
#include <hip/hip_runtime.h>
#include <hip/hip_bf16.h>
#include <math.h>

#define B_ 4
#define N_ 8192
#define C_ 128
#define K_ 683
#define KP_ 768
#define KT_ 704   // 11*64 padded K

// ---- workspace layout, MFMA path (float offsets) ----
#define WS_ET      0          // 128*768            = 98304
#define WS_ANCH    98304      // 4*768*4            = 12288
#define WS_EXT     110592     // 4*8192*16          = 524288
#define WS_EPART   634880     // 8*4*704*32         = 720896
#define WS_MPART   1355776    // 2*4*768*128        = 786432
#define WS_SUMA    2142208    // 4*704              = 2816
#define WS_ASQ     2145024    // 4*704              = 2816
#define WS_LOSSP2  2147840    // 128
#define WS_ST      2147968    // bf16 4*128*8192    = 2097152 floats worth
#define WS_AT      4245120    // bf16 4*768*8192    = 12582912 floats worth
#define WS_NEW_END 16828032   // floats -> 67,312,128 bytes
// ---- old fallback offsets ----
#define OLD_PART   634880
#define OLD_SUMA   4419584
#define OLD_NORM   4422400
#define OLD_GPART  4425216
#define OLD_LOSSP  9143808

// ---- output layout (float offsets) ----
#define OUT_A      0
#define OUT_SC     22380544ULL
#define OUT_MUC    22730240ULL
#define OUT_SGC    22738436ULL
#define OUT_TOT    22763024ULL

typedef __attribute__((ext_vector_type(8))) short bf16x8s;
typedef __attribute__((ext_vector_type(4))) float f32x4;

static __device__ __forceinline__ unsigned short f2bf_rne(float f) {
  unsigned int u = __builtin_bit_cast(unsigned int, f);
  unsigned int r = (u + 0x7fffu + ((u >> 16) & 1u)) >> 16;
  return (unsigned short)r;
}

static __device__ __forceinline__ unsigned int f2ord(float f) {
  unsigned int u = __builtin_bit_cast(unsigned int, f);
  return (u & 0x80000000u) ? ~u : (u | 0x80000000u);
}

static __device__ __forceinline__ unsigned long long umax64(unsigned long long a,
                                                           unsigned long long b) {
  return a > b ? a : b;
}

// =====================================================================
// E[k,c] builder + (blocks >= 384) zero asq accumulator
__global__ __launch_bounds__(256) void build_ET_k(const float* __restrict__ Wp,
                                                  const float* __restrict__ se,
                                                  float* __restrict__ ET,
                                                  float* __restrict__ asq) {
  if (blockIdx.x >= 384) {
    int z = (blockIdx.x - 384) * 256 + threadIdx.x;
    if (z < B_ * KT_) asq[z] = 0.f;
    return;
  }
  int idx = blockIdx.x * 256 + threadIdx.x;
  if (idx >= C_ * KP_) return;
  int c = idx / KP_;
  int k = idx % KP_;
  float acc = 0.f;
  if (k < K_) {
    for (int d = 0; d < C_; d++) acc = fmaf(se[k * C_ + d], Wp[d * C_ + c], acc);
  }
  ET[idx] = acc;
}

// =====================================================================
// FUSED kernel, 512 threads/block:
//   blocks 0..3      : FPS (one per batch) -> anchors  [R7 scalar structure]
//   blocks 4..1027   : semantic GEMM -> Lsem into A region
//   blocks 1028..1091: ext features
//   blocks 1092..1347: sT bf16 builder
__global__ __launch_bounds__(512, 1) void fused_k(const float* __restrict__ s,
    const float* __restrict__ mu, const float* __restrict__ Sigma,
    const float* __restrict__ mask, const float* __restrict__ ET,
    float* __restrict__ anchors, float* __restrict__ ext,
    float* __restrict__ A, unsigned short* __restrict__ sT) {
  const int bid = blockIdx.x;
  const int tid = threadIdx.x;

  __shared__ __align__(16) float s_lds[32][132];
  __shared__ __align__(16) float et_lds[8][KP_];
  __shared__ __align__(16) float muL[N_ * 3];
  __shared__ __align__(16) float Tt[64][72];
  __shared__ double redd[8][4];
  __shared__ unsigned long long redk[2][8];
  __shared__ float an_s[4];

  if (bid >= 1092) {
    const int sb = bid - 1092;
    const int b = sb >> 6;
    const int rest = sb & 63;
    const int chalf = rest >> 5;
    const int ns = rest & 31;
    const int c0 = chalf * 64, n0 = ns * 256;
#pragma unroll
    for (int t2 = 0; t2 < 4; t2++) {
      const int nb = n0 + t2 * 64;
      {
        int n_loc = tid >> 3;
        int cb = (tid & 7) * 8;
        const float* sp = s + ((size_t)(b * N_ + nb + n_loc)) * C_ + c0 + cb;
        float4 v0 = *(const float4*)(sp);
        float4 v1 = *(const float4*)(sp + 4);
        Tt[cb + 0][n_loc] = v0.x; Tt[cb + 1][n_loc] = v0.y;
        Tt[cb + 2][n_loc] = v0.z; Tt[cb + 3][n_loc] = v0.w;
        Tt[cb + 4][n_loc] = v1.x; Tt[cb + 5][n_loc] = v1.y;
        Tt[cb + 6][n_loc] = v1.z; Tt[cb + 7][n_loc] = v1.w;
      }
      __syncthreads();
      {
        int row = tid >> 3;
        int qo = tid & 7;
        float4 f0 = *(const float4*)(&Tt[row][qo * 8]);
        float4 f1 = *(const float4*)(&Tt[row][qo * 8 + 4]);
        unsigned short o[8];
        o[0] = f2bf_rne(f0.x); o[1] = f2bf_rne(f0.y); o[2] = f2bf_rne(f0.z); o[3] = f2bf_rne(f0.w);
        o[4] = f2bf_rne(f1.x); o[5] = f2bf_rne(f1.y); o[6] = f2bf_rne(f1.z); o[7] = f2bf_rne(f1.w);
        unsigned short* dst = sT + ((size_t)(b * C_ + c0 + row)) * N_ + nb + qo * 8;
        *(uint4*)dst = *(uint4*)o;
      }
      __syncthreads();
    }
    return;
  }

  if (bid >= 1028) {
    int idx = (bid - 1028) * 512 + tid;
    if (idx < B_ * N_) {
      float x = mu[(size_t)idx * 3 + 0];
      float y = mu[(size_t)idx * 3 + 1];
      float z = mu[(size_t)idx * 3 + 2];
      const float* S = Sigma + (size_t)idx * 9;
      float* e = ext + (size_t)idx * 16;
      e[0] = x; e[1] = y; e[2] = z;
      e[3] = x * x; e[4] = x * y; e[5] = x * z;
      e[6] = y * y; e[7] = y * z; e[8] = z * z;
      e[9] = S[0]; e[10] = S[1]; e[11] = S[2]; e[12] = S[4]; e[13] = S[5]; e[14] = S[8];
      e[15] = 1.f;
    }
    return;
  }

  if (bid >= 4) {
    const int gb = bid - 4;
    const int b = gb >> 8;
    const int n0 = (gb & 255) * 32;
    const int nt = tid >> 6;
    const int kt = tid & 63;
    {
      const float* sb = s + ((size_t)(b * N_ + n0)) * C_;
      int r = tid >> 4;
      int cb = (tid & 15) * 8;
#pragma unroll
      for (int q = 0; q < 2; q++) {
        float4 v = *(const float4*)(sb + (size_t)r * C_ + cb + q * 4);
        *(float4*)(&s_lds[r][cb + q * 4]) = v;
      }
    }
    float acc[4][12];
#pragma unroll
    for (int i = 0; i < 4; i++)
#pragma unroll
      for (int j = 0; j < 12; j++) acc[i][j] = 0.f;

    for (int cc = 0; cc < 16; cc++) {
      __syncthreads();
#pragma unroll
      for (int q = 0; q < 3; q++) {
        int fid = q * 512 + tid;
        int cl = fid / 192;
        int o4 = fid % 192;
        *(float4*)(&et_lds[cl][o4 * 4]) = *(const float4*)(ET + (size_t)(cc * 8 + cl) * KP_ + o4 * 4);
      }
      __syncthreads();
#pragma unroll
      for (int c8 = 0; c8 < 8; c8++) {
        int c = cc * 8 + c8;
        float sv0 = s_lds[nt * 4 + 0][c];
        float sv1 = s_lds[nt * 4 + 1][c];
        float sv2 = s_lds[nt * 4 + 2][c];
        float sv3 = s_lds[nt * 4 + 3][c];
#pragma unroll
        for (int j = 0; j < 12; j++) {
          float ev = et_lds[c8][kt + 64 * j];
          acc[0][j] = fmaf(sv0, ev, acc[0][j]);
          acc[1][j] = fmaf(sv1, ev, acc[1][j]);
          acc[2][j] = fmaf(sv2, ev, acc[2][j]);
          acc[3][j] = fmaf(sv3, ev, acc[3][j]);
        }
      }
    }
#pragma unroll
    for (int i = 0; i < 4; i++) {
      float* Arow = A + ((size_t)(b * N_ + n0 + nt * 4 + i)) * K_;
#pragma unroll
      for (int j = 0; j < 12; j++) {
        int k = kt + 64 * j;
        if (k < K_) Arow[k] = acc[i][j];
      }
    }
    return;
  }

  // ---------------- FPS (R7 scalar structure, verbatim) ----------------
  const int b = bid;
  const int t = tid;
  const int wv = t >> 6;
  const float* mub = mu + (size_t)b * N_ * 3;
  const float* mkb = mask + (size_t)b * N_;
  float px[16], py[16], pz[16], md[16];

  double sx = 0, sy = 0, sz = 0, sc = 0;
#pragma unroll
  for (int i = 0; i < 16; i++) {
    int p = i * 512 + t;
    px[i] = mub[p * 3 + 0];
    py[i] = mub[p * 3 + 1];
    pz[i] = mub[p * 3 + 2];
    muL[p * 3 + 0] = px[i];
    muL[p * 3 + 1] = py[i];
    muL[p * 3 + 2] = pz[i];
    float mk = mkb[p];
    bool valid = (mk > 0.5f);
    md[i] = valid ? 3.4e38f : -1.f;
    if (valid) { sx += px[i]; sy += py[i]; sz += pz[i]; sc += 1.0; }
  }
  for (int off = 32; off; off >>= 1) {
    sx += __shfl_xor(sx, off);
    sy += __shfl_xor(sy, off);
    sz += __shfl_xor(sz, off);
    sc += __shfl_xor(sc, off);
  }
  if ((t & 63) == 0) { redd[wv][0] = sx; redd[wv][1] = sy; redd[wv][2] = sz; redd[wv][3] = sc; }
  __syncthreads();
  if (t == 0) {
    double ax0 = 0, ay0 = 0, az0 = 0, ac = 0;
    for (int w = 0; w < 8; w++) { ax0 += redd[w][0]; ay0 += redd[w][1]; az0 += redd[w][2]; ac += redd[w][3]; }
    if (ac < 1.0) ac = 1.0;
    an_s[0] = (float)(ax0 / ac); an_s[1] = (float)(ay0 / ac); an_s[2] = (float)(az0 / ac);
  }
  __syncthreads();

  float ax, ay, az;
  {
    float cx = an_s[0], cy = an_s[1], cz = an_s[2];
    float bv = -2.f, bv2 = -2.f;
    int bi = 0, bi2 = 0;
#pragma unroll
    for (int i = 0; i < 16; i++) {
      float dx = px[i] - cx, dy = py[i] - cy, dz = pz[i] - cz;
      float d2 = __fadd_rn(__fadd_rn(__fmul_rn(dx, dx), __fmul_rn(dy, dy)), __fmul_rn(dz, dz));
      float v = (md[i] < 0.f) ? -1.f : d2;
      int p = i * 512 + t;
      if (i & 1) { if (v > bv2) { bv2 = v; bi2 = p; } }
      else       { if (v > bv)  { bv = v;  bi = p; } }
    }
    if (bv2 > bv || (bv2 == bv && bi2 < bi)) { bv = bv2; bi = bi2; }
    unsigned long long k0 = ((unsigned long long)f2ord(bv) << 32) | (unsigned int)(~bi);
    for (int off = 32; off; off >>= 1) {
      unsigned long long ok = __shfl_xor(k0, off);
      if (ok > k0) k0 = ok;
    }
    if ((t & 63) == 0) redk[0][wv] = k0;
    __syncthreads();
    unsigned long long a0 = redk[0][0], a1 = redk[0][1], a2 = redk[0][2], a3 = redk[0][3];
    unsigned long long a4 = redk[0][4], a5 = redk[0][5], a6 = redk[0][6], a7 = redk[0][7];
    unsigned long long bk = umax64(umax64(umax64(a0, a1), umax64(a2, a3)),
                                  umax64(umax64(a4, a5), umax64(a6, a7)));
    int besti = (int)(~(unsigned int)bk);
    ax = muL[besti * 3 + 0]; ay = muL[besti * 3 + 1]; az = muL[besti * 3 + 2];
    if (t == 0) {
      float aa = ax * ax + ay * ay + az * az;
      float4 st = {ax, ay, az, aa};
      *(float4*)(anchors + ((size_t)b * KP_ + 0) * 4) = st;
    }
  }

  for (int k = 1; k < K_; k++) {
    const int par = k & 1;
    float bv = -2.f, bv2 = -2.f;
    int bi = 0, bi2 = 0;
#pragma unroll
    for (int i = 0; i < 16; i++) {
      float dx = px[i] - ax, dy = py[i] - ay, dz = pz[i] - az;
      float d2 = __fadd_rn(__fadd_rn(__fmul_rn(dx, dx), __fmul_rn(dy, dy)), __fmul_rn(dz, dz));
      float m = fminf(md[i], d2);
      md[i] = m;
      int p = i * 512 + t;
      if (i & 1) { if (m > bv2) { bv2 = m; bi2 = p; } }
      else       { if (m > bv)  { bv = m;  bi = p; } }
    }
    if (bv2 > bv || (bv2 == bv && bi2 < bi)) { bv = bv2; bi = bi2; }
    unsigned long long kk = ((unsigned long long)f2ord(bv) << 32) | (unsigned int)(~bi);
    for (int off = 32; off; off >>= 1) {
      unsigned long long ok = __shfl_xor(kk, off);
      if (ok > kk) kk = ok;
    }
    if ((t & 63) == 0) redk[par][wv] = kk;
    __syncthreads();
    unsigned long long a0 = redk[par][0], a1 = redk[par][1], a2 = redk[par][2], a3 = redk[par][3];
    unsigned long long a4 = redk[par][4], a5 = redk[par][5], a6 = redk[par][6], a7 = redk[par][7];
    unsigned long long bk = umax64(umax64(umax64(a0, a1), umax64(a2, a3)),
                                  umax64(umax64(a4, a5), umax64(a6, a7)));
    int besti = (int)(~(unsigned int)bk);
    ax = muL[besti * 3 + 0]; ay = muL[besti * 3 + 1]; az = muL[besti * 3 + 2];
    if (t == 0) {
      float aa = ax * ax + ay * ay + az * az;
      float4 st = {ax, ay, az, aa};
      *(float4*)(anchors + ((size_t)b * KP_ + k) * 4) = st;
    }
  }
  for (int k = K_ + t; k < KP_; k += 512) {
    float4 z4 = {0.f, 0.f, 0.f, 0.f};
    *(float4*)(anchors + ((size_t)b * KP_ + k) * 4) = z4;
  }
}

// =====================================================================
// FUSED postA: softmax (bit-identical) + bf16 transpose to At + per-k
// sum(A^2) block partials -> atomicAdd into asq_ws.
__global__ __launch_bounds__(256) void postA_k(
    const float* __restrict__ mu, const float* __restrict__ mask,
    const float* __restrict__ anchors, const float* __restrict__ lsm_p,
    const float* __restrict__ wsem_p, const float* __restrict__ wmu_p,
    float* __restrict__ A, unsigned short* __restrict__ At,
    float* __restrict__ asq_ws) {
  const int bid = blockIdx.x;
  const int b = bid >> 8;
  const int n0 = (bid & 255) * 32;
  const int tid = threadIdx.x;
  const int wv = tid >> 6;
  const int lane = tid & 63;
  __shared__ __align__(16) float anch_lds[KP_][4];   // reused as asq red buffer
  __shared__ __align__(16) unsigned short T[KP_][40];

  for (int q = tid; q < KP_; q += 256)
    *(float4*)(&anch_lds[q][0]) = *(const float4*)(anchors + ((size_t)b * KP_ + q) * 4);
  __syncthreads();

  const float sg = fmaxf(expf(lsm_p[0]), 1e-4f);
  const float inv2s2 = 0.5f / (sg * sg);
  const float wsem = wsem_p[0];
  const float wmu = wmu_p[0];

  float pq[11];
#pragma unroll
  for (int j = 0; j < 11; j++) pq[j] = 0.f;

#pragma unroll
  for (int g = 0; g < 2; g++) {
    const int r0 = wv * 8 + g * 4;
    unsigned short tpack[12][4];
#pragma unroll
    for (int rr = 0; rr < 4; rr++) {
      const size_t gr = (size_t)b * N_ + n0 + r0 + rr;
      const float* mp = mu + gr * 3;
      float x = mp[0], y = mp[1], z = mp[2];
      float mq = x * x + y * y + z * z;
      float mk = mask[gr];
      float* Arow = A + gr * K_;

      float v[11];
      float m = -3e38f;
#pragma unroll
      for (int j = 0; j < 11; j++) {
        int k = lane + 64 * j;
        if (k < K_) {
          float lsem = Arow[k];
          float4 a4 = *(const float4*)(&anch_lds[k][0]);
          float tdot = x * a4.x + y * a4.y + z * a4.z;
          float d2 = mq - 2.f * tdot + a4.w;
          float l = wsem * lsem - wmu * d2 * inv2s2;
          if (mk < 0.5f) l = -1e9f;
          v[j] = l;
        } else v[j] = -1e30f;
        m = fmaxf(m, v[j]);
      }
      for (int off = 32; off; off >>= 1) m = fmaxf(m, __shfl_xor(m, off));
      float sum = 0.f;
#pragma unroll
      for (int j = 0; j < 11; j++) { float e = expf(v[j] - m); v[j] = e; sum += e; }
      for (int off = 32; off; off >>= 1) sum += __shfl_xor(sum, off);
      float r = mk / sum;
#pragma unroll
      for (int j = 0; j < 11; j++) {
        int k = lane + 64 * j;
        float av = v[j] * r;
        if (k < K_) {
          Arow[k] = av;
          tpack[j][rr] = f2bf_rne(av);
          pq[j] = fmaf(av, av, pq[j]);
        } else tpack[j][rr] = 0;
      }
      tpack[11][rr] = 0;
    }
#pragma unroll
    for (int j = 0; j < 12; j++) {
      int k = lane + 64 * j;
      *(unsigned long long*)(&T[k][r0]) = *(const unsigned long long*)(&tpack[j][0]);
    }
  }
  __syncthreads();
  // reuse anch_lds as red[4][704]
  float* redp = &anch_lds[0][0];
#pragma unroll
  for (int j = 0; j < 11; j++) redp[wv * 704 + lane + 64 * j] = pq[j];
  // At readout: 3 k-rows per thread, 64B each
#pragma unroll
  for (int kq = 0; kq < 3; kq++) {
    int k = tid + 256 * kq;
    const uint4* src = (const uint4*)(&T[k][0]);
    unsigned short* dst = At + ((size_t)(b * KP_ + k)) * N_ + n0;
#pragma unroll
    for (int q = 0; q < 4; q++) *(uint4*)(dst + q * 8) = src[q];
  }
  __syncthreads();
  for (int k2 = tid; k2 < K_; k2 += 256) {
    float tot = redp[k2] + redp[704 + k2] + redp[1408 + k2] + redp[2112 + k2];
    atomicAdd(&asq_ws[b * KT_ + k2], tot);
  }
}

// =====================================================================
// COMBINED tail: blocks 0..83 gram+loss, 84..131 s-moment MFMA, 132..483 ext.
__global__ __launch_bounds__(256) void tail_k(const unsigned short* __restrict__ At,
    const unsigned short* __restrict__ sT, const float* __restrict__ A,
    const float* __restrict__ ext, const float* __restrict__ asq_ws,
    float* __restrict__ mpart, float* __restrict__ epart, float* __restrict__ lossp) {
  __shared__ __align__(16) char arena[38912];
  const int bid = blockIdx.x;
  const int tid = threadIdx.x;

  if (bid < 84) {
    // ---------------- gram + fused loss ----------------
    const int b = bid / 21;
    int p = bid % 21;
    int tk = 0, tl = 0;
    { int pp = p; for (int r0 = 0; r0 < 6; r0++) { int cnt = 6 - r0; if (pp < cnt) { tk = r0; tl = r0 + pp; break; } pp -= cnt; } }
    const int k0 = tk * 128, l0 = tl * 128;
    const int l = tid & 63;
    const int w = tid >> 6;
    const int wr = w >> 1, wc = w & 1;

    unsigned short* Ak_lds = (unsigned short*)arena;
    unsigned short* Al_lds = (unsigned short*)(arena + 18432);
    float* nk_s = (float*)(arena + 36864);
    float* nl_s = (float*)(arena + 37376);
    float* red_s = (float*)(arena + 37888);

    if (tid < 128) {
      int kk = k0 + tid;
      nk_s[tid] = (kk < K_) ? fmaxf(sqrtf(asq_ws[b * KT_ + kk]), 1e-8f) : 1.f;
    } else {
      int ll2 = l0 + tid - 128;
      nl_s[tid - 128] = (ll2 < K_) ? fmaxf(sqrtf(asq_ws[b * KT_ + ll2]), 1e-8f) : 1.f;
    }

    f32x4 acc[4][4];
#pragma unroll
    for (int i = 0; i < 4; i++)
#pragma unroll
      for (int j = 0; j < 4; j++) acc[i][j] = (f32x4){0.f, 0.f, 0.f, 0.f};

    const unsigned short* gk = At + ((size_t)(b * KP_ + k0)) * N_;
    const unsigned short* gl = At + ((size_t)(b * KP_ + l0)) * N_;

    for (int ch = 0; ch < 128; ch++) {
      const int n0 = ch * 64;
      __syncthreads();
#pragma unroll
      for (int q = 0; q < 4; q++) {
        int chunk = tid + 256 * q;
        int row = chunk >> 3, slot = chunk & 7;
        uint4 v = *(const uint4*)(gk + (size_t)row * N_ + n0 + slot * 8);
        *(uint4*)(Ak_lds + row * 72 + slot * 8) = v;
        uint4 v2 = *(const uint4*)(gl + (size_t)row * N_ + n0 + slot * 8);
        *(uint4*)(Al_lds + row * 72 + slot * 8) = v2;
      }
      __syncthreads();
#pragma unroll
      for (int ks = 0; ks < 2; ks++) {
        const int noff = (l >> 4) * 8 + ks * 32;
        bf16x8s af[4], bfr[4];
#pragma unroll
        for (int f = 0; f < 4; f++) {
          af[f]  = *(const bf16x8s*)(Ak_lds + (wr * 64 + f * 16 + (l & 15)) * 72 + noff);
          bfr[f] = *(const bf16x8s*)(Al_lds + (wc * 64 + f * 16 + (l & 15)) * 72 + noff);
        }
#pragma unroll
        for (int i = 0; i < 4; i++)
#pragma unroll
          for (int j = 0; j < 4; j++)
            acc[i][j] = __builtin_amdgcn_mfma_f32_16x16x32_bf16(af[i], bfr[j], acc[i][j], 0, 0, 0);
      }
    }

    float local = 0.f;
    const float wgt = (tk == tl) ? 1.f : 2.f;
#pragma unroll
    for (int i = 0; i < 4; i++) {
#pragma unroll
      for (int j = 0; j < 4; j++) {
#pragma unroll
        for (int r = 0; r < 4; r++) {
          int ki = wr * 64 + i * 16 + (l >> 4) * 4 + r;
          int li = wc * 64 + j * 16 + (l & 15);
          int gkk = k0 + ki, gll = l0 + li;
          if (gkk < K_ && gll < K_ && gkk != gll) {
            float g = acc[i][j][r];
            float x = g / (nk_s[ki] * nl_s[li]);
            local = fmaf(wgt * x, x, local);
          }
        }
      }
    }
    for (int off = 32; off; off >>= 1) local += __shfl_xor(local, off);
    if ((tid & 63) == 0) red_s[w] = local;
    __syncthreads();
    if (tid == 0) lossp[bid] = red_s[0] + red_s[1] + red_s[2] + red_s[3];
    return;
  }

  if (bid < 132) {
    // ---------------- s-moment MFMA ----------------
    const int bid2 = bid - 84;
    const int np = bid2 / 24;
    const int rem = bid2 % 24;
    const int b = rem / 6;
    const int kt2 = rem % 6;
    const int k0 = kt2 * 128;
    const int l = tid & 63;
    const int w = tid >> 6;
    const int wr = w >> 1, wc = w & 1;

    unsigned short* Ak_lds = (unsigned short*)arena;
    unsigned short* Bc_lds = (unsigned short*)(arena + 18432);

    f32x4 acc[4][4];
#pragma unroll
    for (int i = 0; i < 4; i++)
#pragma unroll
      for (int j = 0; j < 4; j++) acc[i][j] = (f32x4){0.f, 0.f, 0.f, 0.f};

    const unsigned short* gk = At + ((size_t)(b * KP_ + k0)) * N_;
    const unsigned short* gc = sT + ((size_t)(b * C_)) * N_;
    const int nbase = np * 4096;

    for (int ch = 0; ch < 64; ch++) {
      const int n0 = nbase + ch * 64;
      __syncthreads();
#pragma unroll
      for (int q = 0; q < 4; q++) {
        int chunk = tid + 256 * q;
        int row = chunk >> 3, slot = chunk & 7;
        uint4 v = *(const uint4*)(gk + (size_t)row * N_ + n0 + slot * 8);
        *(uint4*)(Ak_lds + row * 72 + slot * 8) = v;
        uint4 v2 = *(const uint4*)(gc + (size_t)row * N_ + n0 + slot * 8);
        *(uint4*)(Bc_lds + row * 72 + slot * 8) = v2;
      }
      __syncthreads();
#pragma unroll
      for (int ks = 0; ks < 2; ks++) {
        const int noff = (l >> 4) * 8 + ks * 32;
        bf16x8s af[4], bfr[4];
#pragma unroll
        for (int f = 0; f < 4; f++) {
          af[f]  = *(const bf16x8s*)(Ak_lds + (wr * 64 + f * 16 + (l & 15)) * 72 + noff);
          bfr[f] = *(const bf16x8s*)(Bc_lds + (wc * 64 + f * 16 + (l & 15)) * 72 + noff);
        }
#pragma unroll
        for (int i = 0; i < 4; i++)
#pragma unroll
          for (int j = 0; j < 4; j++)
            acc[i][j] = __builtin_amdgcn_mfma_f32_16x16x32_bf16(af[i], bfr[j], acc[i][j], 0, 0, 0);
      }
    }
    float* mp = mpart + ((size_t)((np * 4 + b) * KP_ + k0)) * C_;
#pragma unroll
    for (int i = 0; i < 4; i++) {
#pragma unroll
      for (int j = 0; j < 4; j++) {
#pragma unroll
        for (int r = 0; r < 4; r++) {
          int ki = wr * 64 + i * 16 + (l >> 4) * 4 + r;
          int ci = wc * 64 + j * 16 + (l & 15);
          mp[(size_t)ki * C_ + ci] = acc[i][j][r];
        }
      }
    }
    return;
  }

  // ---------------- fp32 ext moments ----------------
  {
    const int bid3 = bid - 132;
    const int np = bid3 / 44;
    const int rem = bid3 % 44;
    const int b = rem / 11;
    const int k0 = (rem % 11) * 64;
    const int n0 = np * 1024;
    const int kt = tid & 15;
    const int ft = tid >> 4;
    float (*A_lds)[64] = (float (*)[64])arena;
    float (*F_lds)[32] = (float (*)[32])(arena + 8192);
    float acc[4][2];
#pragma unroll
    for (int c = 0; c < 4; c++) { acc[c][0] = 0.f; acc[c][1] = 0.f; }

    for (int ch = 0; ch < 32; ch++) {
      int nb = n0 + ch * 32;
      __syncthreads();
#pragma unroll
      for (int p = 0; p < 8; p++) {
        int q = tid + 256 * p; int r = q >> 6; int c = q & 63; int k = k0 + c;
        A_lds[r][c] = (k < K_) ? A[((size_t)(b * N_ + nb + r)) * K_ + k] : 0.f;
      }
#pragma unroll
      for (int p = 0; p < 2; p++) {
        int q = tid + 256 * p; int r = q >> 4; int e = q & 15;
        F_lds[r][e] = ext[((size_t)(b * N_ + nb + r)) * 16 + e];
        F_lds[r][16 + e] = 0.f;
      }
      __syncthreads();
#pragma unroll
      for (int i = 0; i < 32; i++) {
        float a0 = A_lds[i][kt * 4 + 0];
        float a1 = A_lds[i][kt * 4 + 1];
        float a2 = A_lds[i][kt * 4 + 2];
        float a3 = A_lds[i][kt * 4 + 3];
#pragma unroll
        for (int f = 0; f < 2; f++) {
          float fv = F_lds[i][ft * 2 + f];
          acc[0][f] = fmaf(a0, fv, acc[0][f]);
          acc[1][f] = fmaf(a1, fv, acc[1][f]);
          acc[2][f] = fmaf(a2, fv, acc[2][f]);
          acc[3][f] = fmaf(a3, fv, acc[3][f]);
        }
      }
    }
#pragma unroll
    for (int c = 0; c < 4; c++) {
      size_t base = ((size_t)((np * 4 + b) * KT_ + k0 + kt * 4 + c)) * 32;
#pragma unroll
      for (int f = 0; f < 2; f++) {
        int fidx = ft * 2 + f;
        if (fidx < 16) epart[base + fidx] = acc[c][f];
      }
    }
  }
}

// =====================================================================
// Postprocess (MFMA path): one wave per (b,k). sumA from ext ones-column.
__global__ __launch_bounds__(256) void postproc2_k(const float* __restrict__ mpart,
    const float* __restrict__ epart, float* __restrict__ out,
    float* __restrict__ sumA_ws) {
  const int gw = blockIdx.x * 4 + (threadIdx.x >> 6);
  const int lane = threadIdx.x & 63;
  const int b = gw / K_;
  const int k = gw % K_;
  float v0 = 0.f, v1 = 0.f, v2 = 0.f;
#pragma unroll
  for (int np = 0; np < 2; np++) {
    const float* r = mpart + ((size_t)((np * 4 + b) * KP_ + k)) * C_;
    v0 += r[lane];
    v1 += r[64 + lane];
  }
#pragma unroll
  for (int np = 0; np < 8; np++) {
    const float* e = epart + ((size_t)((np * 4 + b) * KT_ + k)) * 32;
    if (lane < 16) v2 += e[lane];
  }
  float sumA = __shfl(v2, 15);
  float denom = fmaxf(sumA, 1e-8f);
  float inv = 1.f / denom;
  out[OUT_SC + ((size_t)(b * K_ + k)) * C_ + lane] = v0 * inv;
  out[OUT_SC + ((size_t)(b * K_ + k)) * C_ + 64 + lane] = v1 * inv;
  float m0 = __shfl(v2, 0) * inv;
  float m1 = __shfl(v2, 1) * inv;
  float m2 = __shfl(v2, 2) * inv;
  if (lane < 3) out[OUT_MUC + ((size_t)(b * K_ + k)) * 3 + lane] = (lane == 0) ? m0 : ((lane == 1) ? m1 : m2);
  float W = sumA * inv;
  float fac = 2.f - W;
  float M2s[6], Sgs[6];
#pragma unroll
  for (int j = 0; j < 6; j++) { M2s[j] = __shfl(v2, 3 + j); Sgs[j] = __shfl(v2, 9 + j); }
  if (lane < 9) {
    int d = lane / 3, e = lane % 3;
    int lo = min(d, e), hi = max(d, e);
    int j = hi + 2 * lo - ((lo * (lo - 1)) >> 1);
    float mud = (d == 0) ? m0 : ((d == 1) ? m1 : m2);
    float mue = (e == 0) ? m0 : ((e == 1) ? m1 : m2);
    float M2j = (j == 0) ? M2s[0] : (j == 1) ? M2s[1] : (j == 2) ? M2s[2] : (j == 3) ? M2s[3] : (j == 4) ? M2s[4] : M2s[5];
    float Sgj = (j == 0) ? Sgs[0] : (j == 1) ? Sgs[1] : (j == 2) ? Sgs[2] : (j == 3) ? Sgs[3] : (j == 4) ? Sgs[4] : Sgs[5];
    float val = (Sgj + M2j) * inv - mud * mue * fac;
    if (d == e) val += 1e-6f;
    out[OUT_SGC + ((size_t)(b * K_ + k)) * 9 + lane] = val;
  }
  if (lane == 0) sumA_ws[b * KT_ + k] = sumA;
}

// final for the MFMA path: 84 tile partials
__global__ __launch_bounds__(256) void final2_k(const float* __restrict__ sumA_ws,
    const float* __restrict__ lossp, float* __restrict__ out) {
  const int lane = threadIdx.x & 63;
  const int wv = threadIdx.x >> 6;
  __shared__ float occ_s[4];
  __shared__ float col_s[4];
  float sb = 0.f;
  for (int k = lane; k < K_; k += 64) sb += sumA_ws[wv * KT_ + k];
  for (int off = 32; off; off >>= 1) sb += __shfl_xor(sb, off);
  float Sb = fmaxf(sb, 1e-8f);
  float lo = 0.f;
  const float tgt = 1.f / (float)K_;
  for (int k = lane; k < K_; k += 64) {
    float o = sumA_ws[wv * KT_ + k] / Sb - tgt;
    lo = fmaf(o, o, lo);
  }
  for (int off = 32; off; off >>= 1) lo += __shfl_xor(lo, off);
  if (lane == 0) occ_s[wv] = lo;
  float c = 0.f;
  for (int i = threadIdx.x; i < 84; i += 256) c += lossp[i];
  for (int off = 32; off; off >>= 1) c += __shfl_xor(c, off);
  if (lane == 0) col_s[wv] = c;
  __syncthreads();
  if (threadIdx.x == 0) {
    float loss_occ = (occ_s[0] + occ_s[1] + occ_s[2] + occ_s[3]) / (float)(B_ * K_);
    float coll = (col_s[0] + col_s[1] + col_s[2] + col_s[3]) / ((float)B_ * K_ * K_);
    out[OUT_TOT] = loss_occ + 0.1f * coll;
  }
}

// =====================================================================
// ---- fallback path kernels (ws too small) ----
__global__ __launch_bounds__(256) void spatial_softmax_k(
    const float* __restrict__ mu, const float* __restrict__ mask,
    const float* __restrict__ anchors, const float* __restrict__ lsm_p,
    const float* __restrict__ wsem_p, const float* __restrict__ wmu_p,
    float* __restrict__ A) {
  const int bid = blockIdx.x;
  const int b = bid >> 11;
  const int n0 = (bid & 2047) * 4;
  const int tid = threadIdx.x;
  const int wv = tid >> 6;
  const int lane = tid & 63;
  __shared__ __align__(16) float anch_lds[KP_][4];
  for (int q = tid; q < KP_; q += 256)
    *(float4*)(&anch_lds[q][0]) = *(const float4*)(anchors + ((size_t)b * KP_ + q) * 4);
  __syncthreads();
  const float sg = fmaxf(expf(lsm_p[0]), 1e-4f);
  const float inv2s2 = 0.5f / (sg * sg);
  const float wsem = wsem_p[0];
  const float wmu = wmu_p[0];
  const size_t gr = (size_t)b * N_ + n0 + wv;
  const float* mp = mu + gr * 3;
  float x = mp[0], y = mp[1], z = mp[2];
  float mq = x * x + y * y + z * z;
  float mk = mask[gr];
  float* Arow = A + gr * K_;
  float v[11];
  float m = -3e38f;
#pragma unroll
  for (int j = 0; j < 11; j++) {
    int k = lane + 64 * j;
    if (k < K_) {
      float lsem = Arow[k];
      float4 a4 = *(const float4*)(&anch_lds[k][0]);
      float tdot = x * a4.x + y * a4.y + z * a4.z;
      float d2 = mq - 2.f * tdot + a4.w;
      float l = wsem * lsem - wmu * d2 * inv2s2;
      if (mk < 0.5f) l = -1e9f;
      v[j] = l;
    } else v[j] = -1e30f;
    m = fmaxf(m, v[j]);
  }
  for (int off = 32; off; off >>= 1) m = fmaxf(m, __shfl_xor(m, off));
  float sum = 0.f;
#pragma unroll
  for (int j = 0; j < 11; j++) { float e = expf(v[j] - m); v[j] = e; sum += e; }
  for (int off = 32; off; off >>= 1) sum += __shfl_xor(sum, off);
  float r = mk / sum;
#pragma unroll
  for (int j = 0; j < 11; j++) {
    int k = lane + 64 * j;
    if (k < K_) Arow[k] = v[j] * r;
  }
}

__global__ __launch_bounds__(256) void gemm2_k(const float* __restrict__ A,
    const float* __restrict__ s, const float* __restrict__ ext,
    float* __restrict__ part) {
  const int bid = blockIdx.x;
  const int np = bid / 44;
  const int rem = bid % 44;
  const int b = rem / 11;
  const int k0 = (rem % 11) * 64;
  const int n0 = np * 1024;
  const int tid = threadIdx.x;
  const int kt = tid & 15;
  const int ft = tid >> 4;
  __shared__ __align__(16) float A_lds[32][64];
  __shared__ __align__(16) float F_lds[32][160];
  float acc[4][10];
#pragma unroll
  for (int c = 0; c < 4; c++)
#pragma unroll
    for (int f = 0; f < 10; f++) acc[c][f] = 0.f;
  float asq[4] = {0.f, 0.f, 0.f, 0.f};
  for (int ch = 0; ch < 32; ch++) {
    int nb = n0 + ch * 32;
    __syncthreads();
#pragma unroll
    for (int p = 0; p < 8; p++) {
      int q = tid + 256 * p; int r = q >> 6; int c = q & 63; int k = k0 + c;
      A_lds[r][c] = (k < K_) ? A[((size_t)(b * N_ + nb + r)) * K_ + k] : 0.f;
    }
#pragma unroll
    for (int p = 0; p < 16; p++) {
      int q = tid + 256 * p; int r = q >> 7; int c = q & 127;
      F_lds[r][c] = s[((size_t)(b * N_ + nb + r)) * C_ + c];
    }
#pragma unroll
    for (int p = 0; p < 2; p++) {
      int q = tid + 256 * p; int r = q >> 4; int e = q & 15;
      F_lds[r][128 + e] = ext[((size_t)(b * N_ + nb + r)) * 16 + e];
      F_lds[r][144 + e] = 0.f;
    }
    __syncthreads();
#pragma unroll
    for (int i = 0; i < 32; i++) {
      float a0 = A_lds[i][kt * 4 + 0];
      float a1 = A_lds[i][kt * 4 + 1];
      float a2 = A_lds[i][kt * 4 + 2];
      float a3 = A_lds[i][kt * 4 + 3];
      if (ft == 0) {
        asq[0] = fmaf(a0, a0, asq[0]); asq[1] = fmaf(a1, a1, asq[1]);
        asq[2] = fmaf(a2, a2, asq[2]); asq[3] = fmaf(a3, a3, asq[3]);
      }
#pragma unroll
      for (int f = 0; f < 10; f++) {
        float fv = F_lds[i][ft * 10 + f];
        acc[0][f] = fmaf(a0, fv, acc[0][f]);
        acc[1][f] = fmaf(a1, fv, acc[1][f]);
        acc[2][f] = fmaf(a2, fv, acc[2][f]);
        acc[3][f] = fmaf(a3, fv, acc[3][f]);
      }
    }
  }
#pragma unroll
  for (int c = 0; c < 4; c++) {
    size_t base = ((size_t)((np * 4 + b) * KT_ + k0 + kt * 4 + c)) * 168;
#pragma unroll
    for (int f = 0; f < 10; f++) part[base + ft * 10 + f] = acc[c][f];
    if (ft == 0) part[base + 160] = asq[c];
  }
}

__global__ __launch_bounds__(256) void postproc_k(const float* __restrict__ part,
    float* __restrict__ out, float* __restrict__ sumA_ws, float* __restrict__ norm_ws) {
  const int gw = blockIdx.x * 4 + (threadIdx.x >> 6);
  const int lane = threadIdx.x & 63;
  const int b = gw / K_;
  const int k = gw % K_;
  float v0 = 0.f, v1 = 0.f, v2 = 0.f, v3 = 0.f;
  for (int np = 0; np < 8; np++) {
    const float* r = part + ((size_t)((np * 4 + b) * KT_ + k)) * 168;
    v0 += r[lane];
    v1 += r[64 + lane];
    if (lane < 16) v2 += r[128 + lane];
    if (lane == 0) v3 += r[160];
  }
  float sumA = __shfl(v2, 15);
  float asq = __shfl(v3, 0);
  float denom = fmaxf(sumA, 1e-8f);
  float inv = 1.f / denom;
  out[OUT_SC + ((size_t)(b * K_ + k)) * C_ + lane] = v0 * inv;
  out[OUT_SC + ((size_t)(b * K_ + k)) * C_ + 64 + lane] = v1 * inv;
  float m0 = __shfl(v2, 0) * inv;
  float m1 = __shfl(v2, 1) * inv;
  float m2 = __shfl(v2, 2) * inv;
  if (lane < 3) out[OUT_MUC + ((size_t)(b * K_ + k)) * 3 + lane] = (lane == 0) ? m0 : ((lane == 1) ? m1 : m2);
  float W = sumA * inv;
  float fac = 2.f - W;
  float M2s[6], Sgs[6];
#pragma unroll
  for (int j = 0; j < 6; j++) { M2s[j] = __shfl(v2, 3 + j); Sgs[j] = __shfl(v2, 9 + j); }
  if (lane < 9) {
    int d = lane / 3, e = lane % 3;
    int lo = min(d, e), hi = max(d, e);
    int j = hi + 2 * lo - ((lo * (lo - 1)) >> 1);
    float mud = (d == 0) ? m0 : ((d == 1) ? m1 : m2);
    float mue = (e == 0) ? m0 : ((e == 1) ? m1 : m2);
    float M2j = (j == 0) ? M2s[0] : (j == 1) ? M2s[1] : (j == 2) ? M2s[2] : (j == 3) ? M2s[3] : (j == 4) ? M2s[4] : M2s[5];
    float Sgj = (j == 0) ? Sgs[0] : (j == 1) ? Sgs[1] : (j == 2) ? Sgs[2] : (j == 3) ? Sgs[3] : (j == 4) ? Sgs[4] : Sgs[5];
    float val = (Sgj + M2j) * inv - mud * mue * fac;
    if (d == e) val += 1e-6f;
    out[OUT_SGC + ((size_t)(b * K_ + k)) * 9 + lane] = val;
  }
  if (lane == 0) { sumA_ws[b * KT_ + k] = sumA; norm_ws[b * KT_ + k] = sqrtf(asq); }
}

__device__ __forceinline__ int swz(int f) { return f ^ (((f >> 5) & 3) << 3); }

__global__ __launch_bounds__(256) void gram_k(const float* __restrict__ A,
                                              float* __restrict__ Gpart) {
  const int bid = blockIdx.x;
  const int np = bid & 1;
  int q = bid >> 1;
  const int b = q / 21;
  int p = q % 21;
  int tk = 0, tl = 0;
  { int pp = p; for (int r0 = 0; r0 < 6; r0++) { int cnt = 6 - r0; if (pp < cnt) { tk = r0; tl = r0 + pp; break; } pp -= cnt; } }
  const int k0 = tk * 128, l0 = tl * 128;
  const int n0 = np * 4096;
  const int tid = threadIdx.x;
  const int ktid = tid & 15, ltid = tid >> 4;
  const bool diag = (tk == tl);
  __shared__ __align__(16) float Ak[32][128];
  __shared__ __align__(16) float Al[32][128];
  float acc[8][8];
#pragma unroll
  for (int i = 0; i < 8; i++)
#pragma unroll
    for (int j = 0; j < 8; j++) acc[i][j] = 0.f;
  const int kb = swz(ktid * 8);
  const int lb = swz(ltid * 8);
  for (int ch = 0; ch < 128; ch++) {
    int nb = n0 + ch * 32;
    __syncthreads();
#pragma unroll
    for (int pq = 0; pq < 16; pq++) {
      int qq = tid + 256 * pq; int r = qq >> 7; int c = qq & 127;
      int kk = k0 + c;
      Ak[r][swz(c)] = (kk < K_) ? A[((size_t)(b * N_ + nb + r)) * K_ + kk] : 0.f;
      if (!diag) {
        int ll = l0 + c;
        Al[r][swz(c)] = (ll < K_) ? A[((size_t)(b * N_ + nb + r)) * K_ + ll] : 0.f;
      }
    }
    __syncthreads();
    const float (*Alp)[128] = diag ? Ak : Al;
#pragma unroll
    for (int i = 0; i < 32; i++) {
      float4 ka = *(const float4*)(&Ak[i][kb]);
      float4 kb4 = *(const float4*)(&Ak[i][kb + 4]);
      float4 la = *(const float4*)(&Alp[i][lb]);
      float4 lb4 = *(const float4*)(&Alp[i][lb + 4]);
      float av[8] = {ka.x, ka.y, ka.z, ka.w, kb4.x, kb4.y, kb4.z, kb4.w};
      float lv[8] = {la.x, la.y, la.z, la.w, lb4.x, lb4.y, lb4.z, lb4.w};
#pragma unroll
      for (int ii = 0; ii < 8; ii++)
#pragma unroll
        for (int jj = 0; jj < 8; jj++)
          acc[ii][jj] = fmaf(av[ii], lv[jj], acc[ii][jj]);
    }
  }
#pragma unroll
  for (int ii = 0; ii < 8; ii++) {
    int kk = k0 + ktid * 8 + ii;
    float* gp = Gpart + ((size_t)((np * 4 + b) * KP_ + kk)) * KP_ + l0 + ltid * 8;
#pragma unroll
    for (int jj = 0; jj < 8; jj++) gp[jj] = acc[ii][jj];
  }
}

__global__ __launch_bounds__(256) void loss_part_k(const float* __restrict__ Gpart,
    const float* __restrict__ norm_ws, float* __restrict__ lossp) {
  const long long total = (long long)B_ * 21 * 16384;
  float local = 0.f;
  for (long long idx = (long long)blockIdx.x * 256 + threadIdx.x; idx < total; idx += (long long)512 * 256) {
    int e = (int)(idx & 16383);
    int rest = (int)(idx >> 14);
    int p = rest % 21;
    int b = rest / 21;
    int tk = 0, tl = 0;
    { int pp = p; for (int r0 = 0; r0 < 6; r0++) { int cnt = 6 - r0; if (pp < cnt) { tk = r0; tl = r0 + pp; break; } pp -= cnt; } }
    int i = e >> 7, j = e & 127;
    int k = tk * 128 + i, l = tl * 128 + j;
    if (k < K_ && l < K_ && k != l) {
      size_t i0 = ((size_t)((0 * 4 + b) * KP_ + k)) * KP_ + l;
      size_t i1 = ((size_t)((1 * 4 + b) * KP_ + k)) * KP_ + l;
      float g = Gpart[i0] + Gpart[i1];
      float nk = fmaxf(norm_ws[b * KT_ + k], 1e-8f);
      float nl2 = fmaxf(norm_ws[b * KT_ + l], 1e-8f);
      float x = g / (nk * nl2);
      float wgt = (tk == tl) ? 1.f : 2.f;
      local = fmaf(wgt * x, x, local);
    }
  }
  __shared__ float red[4];
  for (int off = 32; off; off >>= 1) local += __shfl_xor(local, off);
  if ((threadIdx.x & 63) == 0) red[threadIdx.x >> 6] = local;
  __syncthreads();
  if (threadIdx.x == 0) lossp[blockIdx.x] = red[0] + red[1] + red[2] + red[3];
}

__global__ __launch_bounds__(256) void final_k(const float* __restrict__ sumA_ws,
    const float* __restrict__ lossp, float* __restrict__ out) {
  const int lane = threadIdx.x & 63;
  const int wv = threadIdx.x >> 6;
  __shared__ float occ_s[4];
  __shared__ float col_s[4];
  float sb = 0.f;
  for (int k = lane; k < K_; k += 64) sb += sumA_ws[wv * KT_ + k];
  for (int off = 32; off; off >>= 1) sb += __shfl_xor(sb, off);
  float Sb = fmaxf(sb, 1e-8f);
  float lo = 0.f;
  const float tgt = 1.f / (float)K_;
  for (int k = lane; k < K_; k += 64) {
    float o = sumA_ws[wv * KT_ + k] / Sb - tgt;
    lo = fmaf(o, o, lo);
  }
  for (int off = 32; off; off >>= 1) lo += __shfl_xor(lo, off);
  if (lane == 0) occ_s[wv] = lo;
  float c = lossp[threadIdx.x] + lossp[threadIdx.x + 256];
  for (int off = 32; off; off >>= 1) c += __shfl_xor(c, off);
  if (lane == 0) col_s[wv] = c;
  __syncthreads();
  if (threadIdx.x == 0) {
    float loss_occ = (occ_s[0] + occ_s[1] + occ_s[2] + occ_s[3]) / (float)(B_ * K_);
    float coll = (col_s[0] + col_s[1] + col_s[2] + col_s[3]) / ((float)B_ * K_ * K_);
    out[OUT_TOT] = loss_occ + 0.1f * coll;
  }
}

// =====================================================================
extern "C" void kernel_launch(void* const* d_in, const int* in_sizes, int n_in,
                              void* d_out, int out_size, void* d_ws, size_t ws_size,
                              hipStream_t stream) {
  const float* s = (const float*)d_in[0];
  const float* mu = (const float*)d_in[1];
  const float* Sigma = (const float*)d_in[2];
  const float* mask = (const float*)d_in[3];
  const float* Wp = (const float*)d_in[4];
  const float* se = (const float*)d_in[5];
  const float* lsm = (const float*)d_in[6];
  const float* wsem = (const float*)d_in[7];
  const float* wmu = (const float*)d_in[8];
  float* out = (float*)d_out;
  float* ws = (float*)d_ws;

  float* ET = ws + WS_ET;
  float* anch = ws + WS_ANCH;
  float* ext = ws + WS_EXT;

  const bool use_mfma = ws_size >= (size_t)WS_NEW_END * 4;

  if (use_mfma) {
    float* epart = ws + WS_EPART;
    float* mpart = ws + WS_MPART;
    float* sumA = ws + WS_SUMA;
    float* asq = ws + WS_ASQ;
    float* lossp2 = ws + WS_LOSSP2;
    unsigned short* sT = (unsigned short*)(ws + WS_ST);
    unsigned short* At = (unsigned short*)(ws + WS_AT);

    hipLaunchKernelGGL(build_ET_k, dim3(395), dim3(256), 0, stream, Wp, se, ET, asq);
    hipLaunchKernelGGL(fused_k, dim3(1348), dim3(512), 0, stream, s, mu, Sigma, mask, ET, anch, ext, out, sT);
    hipLaunchKernelGGL(postA_k, dim3(1024), dim3(256), 0, stream, mu, mask, anch, lsm, wsem, wmu, out, At, asq);
    hipLaunchKernelGGL(tail_k, dim3(484), dim3(256), 0, stream, At, sT, out, ext, asq, mpart, epart, lossp2);
    hipLaunchKernelGGL(postproc2_k, dim3(683), dim3(256), 0, stream, mpart, epart, out, sumA);
    hipLaunchKernelGGL(final2_k, dim3(1), dim3(256), 0, stream, sumA, lossp2, out);
  } else {
    float* part = ws + OLD_PART;
    float* sumA = ws + OLD_SUMA;
    float* nrm = ws + OLD_NORM;
    float* Gpart = ws + OLD_GPART;
    float* lossp = ws + OLD_LOSSP;
    unsigned short* sT = (unsigned short*)(ws + WS_ST);

    hipLaunchKernelGGL(build_ET_k, dim3(395), dim3(256), 0, stream, Wp, se, ET, nrm);
    hipLaunchKernelGGL(fused_k, dim3(1348), dim3(512), 0, stream, s, mu, Sigma, mask, ET, anch, ext, out, sT);
    hipLaunchKernelGGL(spatial_softmax_k, dim3(8192), dim3(256), 0, stream, mu, mask, anch, lsm, wsem, wmu, out);
    hipLaunchKernelGGL(gemm2_k, dim3(352), dim3(256), 0, stream, out, s, ext, part);
    hipLaunchKernelGGL(postproc_k, dim3(683), dim3(256), 0, stream, part, out, sumA, nrm);
    hipLaunchKernelGGL(gram_k, dim3(168), dim3(256), 0, stream, out, Gpart);
    hipLaunchKernelGGL(loss_part_k, dim3(512), dim3(256), 0, stream, Gpart, nrm, lossp);
    hipLaunchKernelGGL(final_k, dim3(1), dim3(256), 0, stream, sumA, lossp, out);
  }
}